// Round 1
// baseline (15708.760 us; speedup 1.0000x reference)
//
#include <hip/hip_runtime.h>
#include <math.h>

#define S_LEN  4096
#define DMODEL 1024
#define NHEAD  16
#define DHEAD  64
#define DFF    4096
#define NLAYER 4
#define VOCAB  50257

// ---------------------------------------------------------------------------
// embedding + sinusoidal positional encoding (double-precision trig, one-time)
// ---------------------------------------------------------------------------
__global__ __launch_bounds__(256) void embed_kernel(
    const int* __restrict__ tokens, const float* __restrict__ emb,
    float* __restrict__ x)
{
  int s = blockIdx.x;
  int tok = tokens[s];
  const double lf = 0.01798894603901598653; // log(10000)/512
  #pragma unroll
  for (int j = 0; j < 4; ++j) {
    int d = threadIdx.x + j * 256;
    int i = (d < 512) ? d : d - 512;
    double ang = (double)s * exp(-lf * (double)i);
    float pe = (d < 512) ? (float)sin(ang) : (float)cos(ang);
    x[(size_t)s * DMODEL + d] = emb[(size_t)tok * DMODEL + d] + pe;
  }
}

// ---------------------------------------------------------------------------
// block reduction helpers (256 threads = 4 waves)
// ---------------------------------------------------------------------------
__device__ __forceinline__ float block_sum256(float v, float* sm)
{
  #pragma unroll
  for (int off = 32; off >= 1; off >>= 1) v += __shfl_xor(v, off);
  int w = threadIdx.x >> 6;
  if ((threadIdx.x & 63) == 0) sm[w] = v;
  __syncthreads();
  v = sm[0] + sm[1] + sm[2] + sm[3];
  __syncthreads();
  return v;
}

__device__ __forceinline__ float block_max256(float v, float* sm)
{
  #pragma unroll
  for (int off = 32; off >= 1; off >>= 1) v = fmaxf(v, __shfl_xor(v, off));
  int w = threadIdx.x >> 6;
  if ((threadIdx.x & 63) == 0) sm[w] = v;
  __syncthreads();
  v = fmaxf(fmaxf(sm[0], sm[1]), fmaxf(sm[2], sm[3]));
  __syncthreads();
  return v;
}

// ---------------------------------------------------------------------------
// generic fp32 GEMM:  C[z] = A @ B[z] + bias[z]  (optional ReLU, opt N-bounds)
// tile 128x64, BK=32, 256 threads, 8x4 microtile
// ---------------------------------------------------------------------------
#define BM 128
#define BN 64
#define BKK 32

template<bool RELU, bool NB>
__global__ __launch_bounds__(256)
void gemm_f32(const float* __restrict__ A, const float* __restrict__ Bmat,
              const float* __restrict__ bias, float* __restrict__ C,
              int M, int N, int K, long sB, long sC, long sBias)
{
  __shared__ __align__(16) float At[BKK][BM + 4];  // transposed A tile [k][m]
  __shared__ __align__(16) float Bs[BKK][BN + 4];  // [k][n]

  const float* Bp    = Bmat + (long)blockIdx.z * sB;
  float*       Cp    = C    + (long)blockIdx.z * sC;
  const float* biasp = bias + (long)blockIdx.z * sBias;

  int tid = threadIdx.x;
  int m0 = blockIdx.x * BM;
  int n0 = blockIdx.y * BN;
  int ty = tid >> 4;   // 0..15 -> rows ty*8 .. +7
  int tx = tid & 15;   // 0..15 -> cols tx*4 .. +3

  float acc[8][4] = {};

  for (int k0 = 0; k0 < K; k0 += BKK) {
    // ---- load A tile (128x32) transposed ----
    #pragma unroll
    for (int i = 0; i < 4; ++i) {
      int idx = tid + i * 256;          // float4 index 0..1023
      int row = idx >> 3;               // 8 f4 per row of 32
      int kq  = idx & 7;
      float4 av = *(const float4*)(A + (size_t)(m0 + row) * K + k0 + kq * 4);
      At[kq*4+0][row] = av.x;
      At[kq*4+1][row] = av.y;
      At[kq*4+2][row] = av.z;
      At[kq*4+3][row] = av.w;
    }
    // ---- load B tile (32x64) ----
    #pragma unroll
    for (int i = 0; i < 2; ++i) {
      int idx = tid + i * 256;          // 0..511
      int row = idx >> 4;               // 16 f4 per row of 64
      int cq  = idx & 15;
      if (!NB) {
        *(float4*)&Bs[row][cq*4] =
            *(const float4*)(Bp + (size_t)(k0 + row) * N + n0 + cq * 4);
      } else {
        int n = n0 + cq * 4;
        float4 bv;
        bv.x = (n + 0 < N) ? Bp[(size_t)(k0 + row) * N + n + 0] : 0.f;
        bv.y = (n + 1 < N) ? Bp[(size_t)(k0 + row) * N + n + 1] : 0.f;
        bv.z = (n + 2 < N) ? Bp[(size_t)(k0 + row) * N + n + 2] : 0.f;
        bv.w = (n + 3 < N) ? Bp[(size_t)(k0 + row) * N + n + 3] : 0.f;
        *(float4*)&Bs[row][cq*4] = bv;
      }
    }
    __syncthreads();

    #pragma unroll 8
    for (int kk = 0; kk < BKK; ++kk) {
      float4 a0 = *(const float4*)&At[kk][ty * 8];
      float4 a1 = *(const float4*)&At[kk][ty * 8 + 4];
      float4 b  = *(const float4*)&Bs[kk][tx * 4];
      float ar[8] = {a0.x, a0.y, a0.z, a0.w, a1.x, a1.y, a1.z, a1.w};
      float br[4] = {b.x, b.y, b.z, b.w};
      #pragma unroll
      for (int r = 0; r < 8; ++r)
        #pragma unroll
        for (int c = 0; c < 4; ++c)
          acc[r][c] = fmaf(ar[r], br[c], acc[r][c]);
    }
    __syncthreads();
  }

  // ---- epilogue ----
  float bv[4];
  #pragma unroll
  for (int c = 0; c < 4; ++c) {
    int n = n0 + tx * 4 + c;
    bv[c] = (!NB || n < N) ? biasp[n] : 0.f;
  }
  #pragma unroll
  for (int r = 0; r < 8; ++r) {
    int row = m0 + ty * 8 + r;
    float* crow = Cp + (size_t)row * N + n0 + tx * 4;
    if (!NB) {
      float4 o;
      o.x = acc[r][0] + bv[0];
      o.y = acc[r][1] + bv[1];
      o.z = acc[r][2] + bv[2];
      o.w = acc[r][3] + bv[3];
      if (RELU) {
        o.x = fmaxf(o.x, 0.f); o.y = fmaxf(o.y, 0.f);
        o.z = fmaxf(o.z, 0.f); o.w = fmaxf(o.w, 0.f);
      }
      *(float4*)crow = o;
    } else {
      #pragma unroll
      for (int c = 0; c < 4; ++c) {
        int n = n0 + tx * 4 + c;
        if (n < N) {
          float v = acc[r][c] + bv[c];
          if (RELU) v = fmaxf(v, 0.f);
          crow[c] = v;
        }
      }
    }
  }
}

// ---------------------------------------------------------------------------
// flash attention, fp32.  q,k,v: [H][S][64] ; y: [S][1024] (heads concat)
// block: 64 queries x one head; 256 threads; online softmax
// ---------------------------------------------------------------------------
__global__ __launch_bounds__(256)
void attn_f32(const float* __restrict__ q, const float* __restrict__ k,
              const float* __restrict__ v, float* __restrict__ y)
{
  __shared__ __align__(16) float Qt[64][68];   // [e][r]
  __shared__ __align__(16) float KPt[64][68];  // K: [e][c] then P: [kk][r]
  __shared__ __align__(16) float Vs[64][68];   // [kk][e]

  int h  = blockIdx.y;
  int q0 = blockIdx.x * 64;
  int tid = threadIdx.x;
  int ty = tid >> 4;   // rows ty*4..+3
  int tx = tid & 15;   // cols tx*4..+3
  const size_t hS = (size_t)h * S_LEN * DHEAD;

  // load Q block transposed
  #pragma unroll
  for (int i = 0; i < 4; ++i) {
    int idx = tid + i * 256;       // f4 idx 0..1023
    int row = idx >> 4;
    int e4  = idx & 15;
    float4 t = *(const float4*)(q + hS + (size_t)(q0 + row) * DHEAD + e4 * 4);
    Qt[e4*4+0][row] = t.x; Qt[e4*4+1][row] = t.y;
    Qt[e4*4+2][row] = t.z; Qt[e4*4+3][row] = t.w;
  }

  float O[4][4] = {};
  float mrow[4], lrow[4];
  #pragma unroll
  for (int i = 0; i < 4; ++i) { mrow[i] = -1e30f; lrow[i] = 0.f; }
  __syncthreads();

  const float sc = 0.125f;  // 1/sqrt(64)

  for (int kb = 0; kb < S_LEN / 64; ++kb) {
    int k0 = kb * 64;
    // load K (transposed) and V (natural)
    #pragma unroll
    for (int i = 0; i < 4; ++i) {
      int idx = tid + i * 256;
      int row = idx >> 4;
      int e4  = idx & 15;
      float4 t = *(const float4*)(k + hS + (size_t)(k0 + row) * DHEAD + e4 * 4);
      KPt[e4*4+0][row] = t.x; KPt[e4*4+1][row] = t.y;
      KPt[e4*4+2][row] = t.z; KPt[e4*4+3][row] = t.w;
      float4 u = *(const float4*)(v + hS + (size_t)(k0 + row) * DHEAD + e4 * 4);
      *(float4*)&Vs[row][e4*4] = u;
    }
    __syncthreads();

    // scores: s[i][j] = sum_e Q[r][e]*K[c][e]
    float s[4][4] = {};
    #pragma unroll 8
    for (int e = 0; e < 64; ++e) {
      float4 qa = *(const float4*)&Qt[e][ty * 4];
      float4 kbv = *(const float4*)&KPt[e][tx * 4];
      float qr[4] = {qa.x, qa.y, qa.z, qa.w};
      float kr[4] = {kbv.x, kbv.y, kbv.z, kbv.w};
      #pragma unroll
      for (int i = 0; i < 4; ++i)
        #pragma unroll
        for (int j = 0; j < 4; ++j)
          s[i][j] = fmaf(qr[i], kr[j], s[i][j]);
    }

    // online softmax (row reduce across the 16 tx lanes)
    float alpha[4];
    #pragma unroll
    for (int i = 0; i < 4; ++i) {
      float tm = fmaxf(fmaxf(s[i][0], s[i][1]), fmaxf(s[i][2], s[i][3])) * sc;
      #pragma unroll
      for (int off = 1; off < 16; off <<= 1) tm = fmaxf(tm, __shfl_xor(tm, off));
      float mn = fmaxf(mrow[i], tm);
      alpha[i] = expf(mrow[i] - mn);
      mrow[i] = mn;
    }
    #pragma unroll
    for (int i = 0; i < 4; ++i) {
      float rs = 0.f;
      #pragma unroll
      for (int j = 0; j < 4; ++j) {
        float p = expf(s[i][j] * sc - mrow[i]);
        s[i][j] = p;
        rs += p;
      }
      #pragma unroll
      for (int off = 1; off < 16; off <<= 1) rs += __shfl_xor(rs, off);
      lrow[i] = lrow[i] * alpha[i] + rs;
      #pragma unroll
      for (int j = 0; j < 4; ++j) O[i][j] *= alpha[i];
    }
    __syncthreads();   // everyone done reading KPt as K

    // write P transposed: Pt[kcol][row]
    #pragma unroll
    for (int i = 0; i < 4; ++i)
      #pragma unroll
      for (int j = 0; j < 4; ++j)
        KPt[tx * 4 + j][ty * 4 + i] = s[i][j];
    __syncthreads();

    // O += P @ V
    #pragma unroll 8
    for (int kk = 0; kk < 64; ++kk) {
      float4 pa = *(const float4*)&KPt[kk][ty * 4];
      float4 vb = *(const float4*)&Vs[kk][tx * 4];
      float pr[4] = {pa.x, pa.y, pa.z, pa.w};
      float vr[4] = {vb.x, vb.y, vb.z, vb.w};
      #pragma unroll
      for (int i = 0; i < 4; ++i)
        #pragma unroll
        for (int j = 0; j < 4; ++j)
          O[i][j] = fmaf(pr[i], vr[j], O[i][j]);
    }
    __syncthreads();   // done with KPt/Vs before next load
  }

  // normalize + write y[s, h*64 + c]
  #pragma unroll
  for (int i = 0; i < 4; ++i) {
    float inv = 1.0f / lrow[i];
    float4 o;
    o.x = O[i][0] * inv; o.y = O[i][1] * inv;
    o.z = O[i][2] * inv; o.w = O[i][3] * inv;
    *(float4*)(y + (size_t)(q0 + ty * 4 + i) * DMODEL + h * DHEAD + tx * 4) = o;
  }
}

// ---------------------------------------------------------------------------
// x = layernorm(x + y) * g + b   (one row per block)
// ---------------------------------------------------------------------------
__global__ __launch_bounds__(256)
void resid_ln_kernel(float* __restrict__ x, const float* __restrict__ y,
                     const float* __restrict__ g, const float* __restrict__ b)
{
  __shared__ float sm[4];
  int row = blockIdx.x, t = threadIdx.x;
  float4 xv = *(const float4*)(x + (size_t)row * DMODEL + t * 4);
  float4 yv = *(const float4*)(y + (size_t)row * DMODEL + t * 4);
  float a0 = xv.x + yv.x, a1 = xv.y + yv.y, a2 = xv.z + yv.z, a3 = xv.w + yv.w;
  float s = block_sum256(a0 + a1 + a2 + a3, sm);
  float mean = s * (1.0f / DMODEL);
  float d0 = a0 - mean, d1 = a1 - mean, d2 = a2 - mean, d3 = a3 - mean;
  float vs = block_sum256(d0*d0 + d1*d1 + d2*d2 + d3*d3, sm);
  float inv = rsqrtf(vs * (1.0f / DMODEL) + 1e-5f);
  float4 gv = *(const float4*)(g + t * 4);
  float4 bv = *(const float4*)(b + t * 4);
  float4 o;
  o.x = d0 * inv * gv.x + bv.x;
  o.y = d1 * inv * gv.y + bv.y;
  o.z = d2 * inv * gv.z + bv.z;
  o.w = d3 * inv * gv.w + bv.w;
  *(float4*)(x + (size_t)row * DMODEL + t * 4) = o;
}

// ---------------------------------------------------------------------------
// in-place row softmax over VOCAB (one row per block)
// ---------------------------------------------------------------------------
__global__ __launch_bounds__(256)
void softmax_v_kernel(float* __restrict__ out)
{
  __shared__ float sm[4];
  int row = blockIdx.x, t = threadIdx.x;
  float* p = out + (size_t)row * VOCAB;
  float mx = -1e30f;
  for (int i = t; i < VOCAB; i += 256) mx = fmaxf(mx, p[i]);
  mx = block_max256(mx, sm);
  float s = 0.f;
  for (int i = t; i < VOCAB; i += 256) s += expf(p[i] - mx);
  s = block_sum256(s, sm);
  float inv = 1.0f / s;
  for (int i = t; i < VOCAB; i += 256) p[i] = expf(p[i] - mx) * inv;
}

// ---------------------------------------------------------------------------
extern "C" void kernel_launch(void* const* d_in, const int* in_sizes, int n_in,
                              void* d_out, int out_size, void* d_ws, size_t ws_size,
                              hipStream_t stream)
{
  const int*   tokens = (const int*)  d_in[0];
  const float* emb    = (const float*)d_in[1];
  const float* Wq     = (const float*)d_in[2];
  const float* bq     = (const float*)d_in[3];
  const float* Wk     = (const float*)d_in[4];
  const float* bk     = (const float*)d_in[5];
  const float* Wv     = (const float*)d_in[6];
  const float* bv     = (const float*)d_in[7];
  const float* ln1g   = (const float*)d_in[8];
  const float* ln1b   = (const float*)d_in[9];
  const float* W1     = (const float*)d_in[10];
  const float* b1     = (const float*)d_in[11];
  const float* W2     = (const float*)d_in[12];
  const float* b2     = (const float*)d_in[13];
  const float* ln2g   = (const float*)d_in[14];
  const float* ln2b   = (const float*)d_in[15];
  const float* Wout   = (const float*)d_in[16];
  const float* bout   = (const float*)d_in[17];

  float* out = (float*)d_out;
  float* x   = (float*)d_ws;                 // [S, D]   16 MB in workspace
  // scratch inside d_out (dead before logits GEMM overwrites everything):
  float* qb  = out;                          // [H,S,64]  4M floats
  float* kb  = out + 4194304;                // [H,S,64]
  float* vb  = out + 8388608;                // [H,S,64]
  float* yb  = out + 12582912;               // [S,D]     4M floats
  float* h1  = out + 16777216;               // [S,DFF]  16M floats

  const long sWqkv = (long)DMODEL * DHEAD;       // per-head weight stride
  const long sQ    = (long)S_LEN * DHEAD;        // per-head output stride

  embed_kernel<<<S_LEN, 256, 0, stream>>>(tokens, emb, x);

  for (int l = 0; l < NLAYER; ++l) {
    const float* Wql = Wq + (size_t)l * NHEAD * DMODEL * DHEAD;
    const float* Wkl = Wk + (size_t)l * NHEAD * DMODEL * DHEAD;
    const float* Wvl = Wv + (size_t)l * NHEAD * DMODEL * DHEAD;
    const float* bql = bq + (size_t)l * NHEAD * DHEAD;
    const float* bkl = bk + (size_t)l * NHEAD * DHEAD;
    const float* bvl = bv + (size_t)l * NHEAD * DHEAD;

    dim3 gqkv(S_LEN / BM, 1, NHEAD);
    gemm_f32<false,false><<<gqkv, 256, 0, stream>>>(x, Wql, bql, qb,
        S_LEN, DHEAD, DMODEL, sWqkv, sQ, DHEAD);
    gemm_f32<false,false><<<gqkv, 256, 0, stream>>>(x, Wkl, bkl, kb,
        S_LEN, DHEAD, DMODEL, sWqkv, sQ, DHEAD);
    gemm_f32<false,false><<<gqkv, 256, 0, stream>>>(x, Wvl, bvl, vb,
        S_LEN, DHEAD, DMODEL, sWqkv, sQ, DHEAD);

    attn_f32<<<dim3(S_LEN / 64, NHEAD), 256, 0, stream>>>(qb, kb, vb, yb);

    resid_ln_kernel<<<S_LEN, 256, 0, stream>>>(x, yb,
        ln1g + (size_t)l * DMODEL, ln1b + (size_t)l * DMODEL);

    gemm_f32<true,false><<<dim3(S_LEN / BM, DFF / BN), 256, 0, stream>>>(
        x, W1 + (size_t)l * DMODEL * DFF, b1 + (size_t)l * DFF, h1,
        S_LEN, DFF, DMODEL, 0, 0, 0);
    gemm_f32<false,false><<<dim3(S_LEN / BM, DMODEL / BN), 256, 0, stream>>>(
        h1, W2 + (size_t)l * DFF * DMODEL, b2 + (size_t)l * DMODEL, yb,
        S_LEN, DMODEL, DFF, 0, 0, 0);

    resid_ln_kernel<<<S_LEN, 256, 0, stream>>>(x, yb,
        ln2g + (size_t)l * DMODEL, ln2b + (size_t)l * DMODEL);
  }

  // logits into d_out (overwrites scratch), then in-place softmax
  gemm_f32<false,true><<<dim3(S_LEN / BM, (VOCAB + BN - 1) / BN), 256, 0, stream>>>(
      x, Wout, bout, out, S_LEN, VOCAB, DMODEL, 0, 0, 0);
  softmax_v_kernel<<<S_LEN, 256, 0, stream>>>(out);
}

// Round 2
// 9095.142 us; speedup vs baseline: 1.7272x; 1.7272x over previous
//
#include <hip/hip_runtime.h>
#include <math.h>

#define S_LEN  4096
#define DMODEL 1024
#define NHEAD  16
#define DHEAD  64
#define DFF    4096
#define NLAYER 4
#define VOCAB  50257

typedef unsigned short ushort_t;
typedef __attribute__((ext_vector_type(8))) __bf16 bf16x8;
typedef __attribute__((ext_vector_type(4))) float f32x4;

static __device__ __forceinline__ ushort_t f2bf(float f) {
  union { float f; unsigned u; } x; x.f = f;
  unsigned r = x.u + 0x7fffu + ((x.u >> 16) & 1u);
  return (ushort_t)(r >> 16);
}
static __device__ __forceinline__ float bf2f(ushort_t h) {
  union { unsigned u; float f; } x; x.u = ((unsigned)h) << 16;
  return x.f;
}

#define GLOAD_LDS16(gp, lp) \
  __builtin_amdgcn_global_load_lds((const __attribute__((address_space(1))) void*)(gp), \
                                   (__attribute__((address_space(3))) void*)(lp), 16, 0, 0)

// ---------------------------------------------------------------------------
// embedding + sinusoidal positional encoding, fused bf16 hi/lo split
// ---------------------------------------------------------------------------
__global__ __launch_bounds__(256) void embed_kernel(
    const int* __restrict__ tokens, const float* __restrict__ emb,
    float* __restrict__ x, ushort_t* __restrict__ xh, ushort_t* __restrict__ xl)
{
  int s = blockIdx.x;
  int tok = tokens[s];
  int d0 = threadIdx.x * 4;
  const double lf = 0.01798894603901598653; // log(10000)/512
  float4 ev = *(const float4*)(emb + (size_t)tok * DMODEL + d0);
  float o[4]; float evr[4] = {ev.x, ev.y, ev.z, ev.w};
  #pragma unroll
  for (int j = 0; j < 4; ++j) {
    int d = d0 + j;
    int i = (d < 512) ? d : d - 512;
    double ang = (double)s * exp(-lf * (double)i);
    float pe = (d < 512) ? (float)sin(ang) : (float)cos(ang);
    o[j] = evr[j] + pe;
  }
  *(float4*)(x + (size_t)s * DMODEL + d0) = make_float4(o[0], o[1], o[2], o[3]);
  ushort_t hv[4], lv[4];
  #pragma unroll
  for (int j = 0; j < 4; ++j) {
    hv[j] = f2bf(o[j]);
    lv[j] = f2bf(o[j] - bf2f(hv[j]));
  }
  *(ushort4*)(xh + (size_t)s * DMODEL + d0) = make_ushort4(hv[0], hv[1], hv[2], hv[3]);
  *(ushort4*)(xl + (size_t)s * DMODEL + d0) = make_ushort4(lv[0], lv[1], lv[2], lv[3]);
}

// ---------------------------------------------------------------------------
// transpose + split: in f32 [K][N] (row stride in_rstride) -> out bf16 hi/lo
// [N][Kout] K-contiguous. Zero-fills columns >= Nvalid. blockIdx.z batches.
// ---------------------------------------------------------------------------
__global__ __launch_bounds__(256)
void transpose_split(const float* __restrict__ in, ushort_t* __restrict__ oh,
                     ushort_t* __restrict__ ol, long in_zstr, long out_zoff,
                     int in_rstride, int Kout, int Nvalid)
{
  __shared__ float tile[64][65];
  const float* inz = in + (long)blockIdx.z * in_zstr;
  ushort_t* ohz = oh + (long)blockIdx.z * out_zoff;
  ushort_t* olz = ol + (long)blockIdx.z * out_zoff;
  int k0 = blockIdx.x * 64, n0 = blockIdx.y * 64;
  int t = threadIdx.x;
  #pragma unroll
  for (int i = 0; i < 4; ++i) {
    int idx = t + i * 256;            // 0..1023
    int kk = idx >> 4, c4 = idx & 15;
    #pragma unroll
    for (int j = 0; j < 4; ++j) {
      int n = n0 + c4 * 4 + j;
      float v = (n < Nvalid) ? inz[(long)(k0 + kk) * in_rstride + n] : 0.f;
      tile[c4 * 4 + j][kk] = v;       // transposed into LDS
    }
  }
  __syncthreads();
  #pragma unroll
  for (int i = 0; i < 4; ++i) {
    int idx = t + i * 256;
    int nn = idx >> 4, k4 = idx & 15;
    ushort_t hv[4], lv[4];
    #pragma unroll
    for (int j = 0; j < 4; ++j) {
      float v = tile[nn][k4 * 4 + j];
      hv[j] = f2bf(v);
      lv[j] = f2bf(v - bf2f(hv[j]));
    }
    long ob = (long)(n0 + nn) * Kout + k0 + k4 * 4;
    *(ushort4*)(ohz + ob) = make_ushort4(hv[0], hv[1], hv[2], hv[3]);
    *(ushort4*)(olz + ob) = make_ushort4(lv[0], lv[1], lv[2], lv[3]);
  }
}

// ---------------------------------------------------------------------------
// concat 3 bias vectors of length n into one [3n]
// ---------------------------------------------------------------------------
__global__ __launch_bounds__(256)
void concat3_kernel(const float* __restrict__ a, const float* __restrict__ b,
                    const float* __restrict__ c, float* __restrict__ o, int n)
{
  int i = blockIdx.x * 256 + threadIdx.x;
  if (i < n) { o[i] = a[i]; o[n + i] = b[i]; o[2 * n + i] = c[i]; }
}

// ---------------------------------------------------------------------------
// split-bf16 MFMA GEMM: C = A @ B^T(+bias), A hi/lo [M][K], B hi/lo [N][K],
// both bf16 K-contiguous. 128x128 tile, BK=32, 4 waves, 16x16x32 MFMA,
// 3-product split accumulation (AhBh + AhBl + AlBh) in fp32.
// m97 structure: fragment-contiguous LDS + global_load_lds(16B) + 2 barriers.
// ---------------------------------------------------------------------------
template<bool RELU, bool SPLIT, bool BOUND>
__global__ __launch_bounds__(256)
void gemm3(const ushort_t* __restrict__ Ah, const ushort_t* __restrict__ Al,
           const ushort_t* __restrict__ Bh, const ushort_t* __restrict__ Bl,
           const float* __restrict__ bias, float* __restrict__ C,
           ushort_t* __restrict__ Ch, ushort_t* __restrict__ Cl,
           int K, long ldc, int Nlimit)
{
  __shared__ ushort_t lds[4 * 4096];  // Ah | Al | Bh | Bl, each 128x32 bf16

  const int t = threadIdx.x;
  const int l = t & 63;
  const int w = t >> 6;
  const int wr = w >> 1, wc = w & 1;
  const long m0 = (long)blockIdx.x * 128;
  const long n0 = (long)blockIdx.y * 128;
  const int lrow = l & 15;
  const int lk   = (l >> 4) * 8;

  f32x4 acc[4][4];
  #pragma unroll
  for (int m = 0; m < 4; ++m)
    #pragma unroll
    for (int n = 0; n < 4; ++n) acc[m][n] = (f32x4)0.f;

  // staging source pointers: issue i covers subtile s = i*4 + w
  const ushort_t* ag[2]; const ushort_t* alg[2];
  const ushort_t* bg[2]; const ushort_t* blg[2];
  #pragma unroll
  for (int i = 0; i < 2; ++i) {
    int s = i * 4 + w;
    long ar = m0 + s * 16 + lrow;
    long br = n0 + s * 16 + lrow;
    ag[i]  = Ah + ar * (long)K + lk;
    alg[i] = Al + ar * (long)K + lk;
    bg[i]  = Bh + br * (long)K + lk;
    blg[i] = Bl + br * (long)K + lk;
  }

  for (int k0 = 0; k0 < K; k0 += 32) {
    __syncthreads();
    #pragma unroll
    for (int i = 0; i < 2; ++i) {
      int s = i * 4 + w;
      GLOAD_LDS16(ag[i]  + k0, &lds[        s * 512 + l * 8]);
      GLOAD_LDS16(alg[i] + k0, &lds[ 4096 + s * 512 + l * 8]);
      GLOAD_LDS16(bg[i]  + k0, &lds[ 8192 + s * 512 + l * 8]);
      GLOAD_LDS16(blg[i] + k0, &lds[12288 + s * 512 + l * 8]);
    }
    __syncthreads();

    bf16x8 bh_[4], bl_[4];
    #pragma unroll
    for (int n = 0; n < 4; ++n) {
      bh_[n] = *(const bf16x8*)&lds[ 8192 + (wc * 4 + n) * 512 + l * 8];
      bl_[n] = *(const bf16x8*)&lds[12288 + (wc * 4 + n) * 512 + l * 8];
    }
    #pragma unroll
    for (int m = 0; m < 4; ++m) {
      bf16x8 ah_ = *(const bf16x8*)&lds[       (wr * 4 + m) * 512 + l * 8];
      bf16x8 al_ = *(const bf16x8*)&lds[4096 + (wr * 4 + m) * 512 + l * 8];
      #pragma unroll
      for (int n = 0; n < 4; ++n) {
        acc[m][n] = __builtin_amdgcn_mfma_f32_16x16x32_bf16(ah_, bh_[n], acc[m][n], 0, 0, 0);
        acc[m][n] = __builtin_amdgcn_mfma_f32_16x16x32_bf16(ah_, bl_[n], acc[m][n], 0, 0, 0);
        acc[m][n] = __builtin_amdgcn_mfma_f32_16x16x32_bf16(al_, bh_[n], acc[m][n], 0, 0, 0);
      }
    }
  }

  // epilogue: C[m0+wr*64+m*16+(l>>4)*4+r][n0+wc*64+n*16+(l&15)] = acc[m][n][r]
  #pragma unroll
  for (int n = 0; n < 4; ++n) {
    long col = n0 + wc * 64 + n * 16 + lrow;
    bool cok = (!BOUND) || (col < (long)Nlimit);
    float bv = cok ? bias[col] : 0.f;
    #pragma unroll
    for (int m = 0; m < 4; ++m) {
      #pragma unroll
      for (int r = 0; r < 4; ++r) {
        long row = m0 + wr * 64 + m * 16 + (l >> 4) * 4 + r;
        float v = acc[m][n][r] + bv;
        if (RELU) v = fmaxf(v, 0.f);
        if (cok) {
          if (SPLIT) {
            ushort_t h = f2bf(v);
            Ch[row * ldc + col] = h;
            Cl[row * ldc + col] = f2bf(v - bf2f(h));
          } else {
            C[row * ldc + col] = v;
          }
        }
      }
    }
  }
}

// ---------------------------------------------------------------------------
// flash attention, fp32. qkv: [S][3072] (q|k|v, heads concat within each),
// y: [S][1024]. block: 64 queries x one head; 256 threads; online softmax
// ---------------------------------------------------------------------------
__global__ __launch_bounds__(256)
void attn_f32(const float* __restrict__ qkv, float* __restrict__ y)
{
  __shared__ __align__(16) float Qt[64][68];   // [e][r]
  __shared__ __align__(16) float KPt[64][68];  // K: [e][c] then P: [kk][r]
  __shared__ __align__(16) float Vs[64][68];   // [kk][e]

  int h  = blockIdx.y;
  int q0 = blockIdx.x * 64;
  int tid = threadIdx.x;
  int ty = tid >> 4;
  int tx = tid & 15;
  const float* qp = qkv + h * DHEAD;
  const float* kp = qkv + 1024 + h * DHEAD;
  const float* vp = qkv + 2048 + h * DHEAD;

  #pragma unroll
  for (int i = 0; i < 4; ++i) {
    int idx = tid + i * 256;
    int row = idx >> 4;
    int e4  = idx & 15;
    float4 tq = *(const float4*)(qp + (size_t)(q0 + row) * 3072 + e4 * 4);
    Qt[e4*4+0][row] = tq.x; Qt[e4*4+1][row] = tq.y;
    Qt[e4*4+2][row] = tq.z; Qt[e4*4+3][row] = tq.w;
  }

  float O[4][4] = {};
  float mrow[4], lrow[4];
  #pragma unroll
  for (int i = 0; i < 4; ++i) { mrow[i] = -1e30f; lrow[i] = 0.f; }
  __syncthreads();

  const float sc = 0.125f;

  for (int kb = 0; kb < S_LEN / 64; ++kb) {
    int k0 = kb * 64;
    #pragma unroll
    for (int i = 0; i < 4; ++i) {
      int idx = tid + i * 256;
      int row = idx >> 4;
      int e4  = idx & 15;
      float4 tk = *(const float4*)(kp + (size_t)(k0 + row) * 3072 + e4 * 4);
      KPt[e4*4+0][row] = tk.x; KPt[e4*4+1][row] = tk.y;
      KPt[e4*4+2][row] = tk.z; KPt[e4*4+3][row] = tk.w;
      float4 u = *(const float4*)(vp + (size_t)(k0 + row) * 3072 + e4 * 4);
      *(float4*)&Vs[row][e4*4] = u;
    }
    __syncthreads();

    float s[4][4] = {};
    #pragma unroll 8
    for (int e = 0; e < 64; ++e) {
      float4 qa = *(const float4*)&Qt[e][ty * 4];
      float4 kbv = *(const float4*)&KPt[e][tx * 4];
      float qr[4] = {qa.x, qa.y, qa.z, qa.w};
      float kr[4] = {kbv.x, kbv.y, kbv.z, kbv.w};
      #pragma unroll
      for (int i = 0; i < 4; ++i)
        #pragma unroll
        for (int j = 0; j < 4; ++j)
          s[i][j] = fmaf(qr[i], kr[j], s[i][j]);
    }

    float alpha[4];
    #pragma unroll
    for (int i = 0; i < 4; ++i) {
      float tm = fmaxf(fmaxf(s[i][0], s[i][1]), fmaxf(s[i][2], s[i][3])) * sc;
      #pragma unroll
      for (int off = 1; off < 16; off <<= 1) tm = fmaxf(tm, __shfl_xor(tm, off));
      float mn = fmaxf(mrow[i], tm);
      alpha[i] = expf(mrow[i] - mn);
      mrow[i] = mn;
    }
    #pragma unroll
    for (int i = 0; i < 4; ++i) {
      float rs = 0.f;
      #pragma unroll
      for (int j = 0; j < 4; ++j) {
        float p = expf(s[i][j] * sc - mrow[i]);
        s[i][j] = p;
        rs += p;
      }
      #pragma unroll
      for (int off = 1; off < 16; off <<= 1) rs += __shfl_xor(rs, off);
      lrow[i] = lrow[i] * alpha[i] + rs;
      #pragma unroll
      for (int j = 0; j < 4; ++j) O[i][j] *= alpha[i];
    }
    __syncthreads();

    #pragma unroll
    for (int i = 0; i < 4; ++i)
      #pragma unroll
      for (int j = 0; j < 4; ++j)
        KPt[tx * 4 + j][ty * 4 + i] = s[i][j];
    __syncthreads();

    #pragma unroll 8
    for (int kk = 0; kk < 64; ++kk) {
      float4 pa = *(const float4*)&KPt[kk][ty * 4];
      float4 vb = *(const float4*)&Vs[kk][tx * 4];
      float pr[4] = {pa.x, pa.y, pa.z, pa.w};
      float vr[4] = {vb.x, vb.y, vb.z, vb.w};
      #pragma unroll
      for (int i = 0; i < 4; ++i)
        #pragma unroll
        for (int j = 0; j < 4; ++j)
          O[i][j] = fmaf(pr[i], vr[j], O[i][j]);
    }
    __syncthreads();
  }

  #pragma unroll
  for (int i = 0; i < 4; ++i) {
    float inv = 1.0f / lrow[i];
    float4 o;
    o.x = O[i][0] * inv; o.y = O[i][1] * inv;
    o.z = O[i][2] * inv; o.w = O[i][3] * inv;
    *(float4*)(y + (size_t)(q0 + ty * 4 + i) * DMODEL + h * DHEAD + tx * 4) = o;
  }
}

// ---------------------------------------------------------------------------
__device__ __forceinline__ float block_sum256(float v, float* sm)
{
  #pragma unroll
  for (int off = 32; off >= 1; off >>= 1) v += __shfl_xor(v, off);
  int w = threadIdx.x >> 6;
  if ((threadIdx.x & 63) == 0) sm[w] = v;
  __syncthreads();
  v = sm[0] + sm[1] + sm[2] + sm[3];
  __syncthreads();
  return v;
}

__device__ __forceinline__ float block_max256(float v, float* sm)
{
  #pragma unroll
  for (int off = 32; off >= 1; off >>= 1) v = fmaxf(v, __shfl_xor(v, off));
  int w = threadIdx.x >> 6;
  if ((threadIdx.x & 63) == 0) sm[w] = v;
  __syncthreads();
  v = fmaxf(fmaxf(sm[0], sm[1]), fmaxf(sm[2], sm[3]));
  __syncthreads();
  return v;
}

// x = layernorm(x + y) * g + b, fused bf16 hi/lo split of the result
__global__ __launch_bounds__(256)
void resid_ln_kernel(float* __restrict__ x, const float* __restrict__ y,
                     const float* __restrict__ g, const float* __restrict__ b,
                     ushort_t* __restrict__ xh, ushort_t* __restrict__ xl)
{
  __shared__ float sm[4];
  int row = blockIdx.x, t = threadIdx.x;
  float4 xv = *(const float4*)(x + (size_t)row * DMODEL + t * 4);
  float4 yv = *(const float4*)(y + (size_t)row * DMODEL + t * 4);
  float a0 = xv.x + yv.x, a1 = xv.y + yv.y, a2 = xv.z + yv.z, a3 = xv.w + yv.w;
  float s = block_sum256(a0 + a1 + a2 + a3, sm);
  float mean = s * (1.0f / DMODEL);
  float d0 = a0 - mean, d1 = a1 - mean, d2 = a2 - mean, d3 = a3 - mean;
  float vs = block_sum256(d0*d0 + d1*d1 + d2*d2 + d3*d3, sm);
  float inv = rsqrtf(vs * (1.0f / DMODEL) + 1e-5f);
  float4 gv = *(const float4*)(g + t * 4);
  float4 bv = *(const float4*)(b + t * 4);
  float o[4];
  o[0] = d0 * inv * gv.x + bv.x;
  o[1] = d1 * inv * gv.y + bv.y;
  o[2] = d2 * inv * gv.z + bv.z;
  o[3] = d3 * inv * gv.w + bv.w;
  *(float4*)(x + (size_t)row * DMODEL + t * 4) = make_float4(o[0], o[1], o[2], o[3]);
  ushort_t hv[4], lv[4];
  #pragma unroll
  for (int j = 0; j < 4; ++j) {
    hv[j] = f2bf(o[j]);
    lv[j] = f2bf(o[j] - bf2f(hv[j]));
  }
  *(ushort4*)(xh + (size_t)row * DMODEL + t * 4) = make_ushort4(hv[0], hv[1], hv[2], hv[3]);
  *(ushort4*)(xl + (size_t)row * DMODEL + t * 4) = make_ushort4(lv[0], lv[1], lv[2], lv[3]);
}

// in-place row softmax over VOCAB
__global__ __launch_bounds__(256)
void softmax_v_kernel(float* __restrict__ out)
{
  __shared__ float sm[4];
  int row = blockIdx.x, t = threadIdx.x;
  float* p = out + (size_t)row * VOCAB;
  float mx = -1e30f;
  for (int i = t; i < VOCAB; i += 256) mx = fmaxf(mx, p[i]);
  mx = block_max256(mx, sm);
  float s = 0.f;
  for (int i = t; i < VOCAB; i += 256) s += expf(p[i] - mx);
  s = block_sum256(s, sm);
  float inv = 1.0f / s;
  for (int i = t; i < VOCAB; i += 256) p[i] = expf(p[i] - mx) * inv;
}

// ---------------------------------------------------------------------------
extern "C" void kernel_launch(void* const* d_in, const int* in_sizes, int n_in,
                              void* d_out, int out_size, void* d_ws, size_t ws_size,
                              hipStream_t stream)
{
  const int*   tokens = (const int*)  d_in[0];
  const float* emb    = (const float*)d_in[1];
  const float* Wq     = (const float*)d_in[2];
  const float* bq     = (const float*)d_in[3];
  const float* Wk     = (const float*)d_in[4];
  const float* bk     = (const float*)d_in[5];
  const float* Wv     = (const float*)d_in[6];
  const float* bv     = (const float*)d_in[7];
  const float* ln1g   = (const float*)d_in[8];
  const float* ln1b   = (const float*)d_in[9];
  const float* W1     = (const float*)d_in[10];
  const float* b1     = (const float*)d_in[11];
  const float* W2     = (const float*)d_in[12];
  const float* b2     = (const float*)d_in[13];
  const float* ln2g   = (const float*)d_in[14];
  const float* ln2b   = (const float*)d_in[15];
  const float* Wout   = (const float*)d_in[16];
  const float* bout   = (const float*)d_in[17];

  // workspace (needs >= 32 MB): xh | xl | stripH | stripL, 8 MB each
  char* wsb = (char*)d_ws;
  ushort_t* xh     = (ushort_t*)(wsb);
  ushort_t* xl     = (ushort_t*)(wsb + ((size_t)8  << 20));
  ushort_t* stripH = (ushort_t*)(wsb + ((size_t)16 << 20));
  ushort_t* stripL = (ushort_t*)(wsb + ((size_t)24 << 20));

  // scratch carved out of d_out (823 MB; all dead before logits GEMM writes it)
  char* ob = (char*)d_out;
  float*    x    = (float*)(ob);                         // [S][D] f32, 16 MB
  float*    qkvb = (float*)(ob + ((size_t)16  << 20));   // [S][3072] f32, 48 MB
  float*    yb   = (float*)(ob + ((size_t)64  << 20));   // [S][D] f32, 16 MB
  ushort_t* h1h  = (ushort_t*)(ob + ((size_t)80  << 20)); // [S][DFF] bf16, 32 MB
  ushort_t* h1l  = (ushort_t*)(ob + ((size_t)112 << 20));
  ushort_t* wqkvh= (ushort_t*)(ob + ((size_t)144 << 20)); // [3072][1024] bf16, 6 MB
  ushort_t* wqkvl= (ushort_t*)(ob + ((size_t)150 << 20));
  ushort_t* w1h  = (ushort_t*)(ob + ((size_t)156 << 20)); // [4096][1024] bf16, 8 MB
  ushort_t* w1l  = (ushort_t*)(ob + ((size_t)164 << 20));
  ushort_t* w2h  = (ushort_t*)(ob + ((size_t)172 << 20)); // [1024][4096] bf16, 8 MB
  ushort_t* w2l  = (ushort_t*)(ob + ((size_t)180 << 20));
  float*    bqkv = (float*)(ob + ((size_t)188 << 20));    // [3072] f32
  float*    outf = (float*)d_out;

  embed_kernel<<<S_LEN, 256, 0, stream>>>(tokens, emb, x, xh, xl);

  for (int l = 0; l < NLAYER; ++l) {
    const long wofs = (long)l * NHEAD * DMODEL * DHEAD;
    // weight prep: Wq/Wk/Wv -> [3072][1024] bf16 hi/lo (per-head transpose)
    transpose_split<<<dim3(16, 1, 16), 256, 0, stream>>>(
        Wq + wofs, wqkvh, wqkvl, (long)DMODEL * DHEAD, (long)DHEAD * DMODEL,
        DHEAD, DMODEL, DHEAD);
    transpose_split<<<dim3(16, 1, 16), 256, 0, stream>>>(
        Wk + wofs, wqkvh + 1024 * 1024, wqkvl + 1024 * 1024,
        (long)DMODEL * DHEAD, (long)DHEAD * DMODEL, DHEAD, DMODEL, DHEAD);
    transpose_split<<<dim3(16, 1, 16), 256, 0, stream>>>(
        Wv + wofs, wqkvh + 2048 * 1024, wqkvl + 2048 * 1024,
        (long)DMODEL * DHEAD, (long)DHEAD * DMODEL, DHEAD, DMODEL, DHEAD);
    concat3_kernel<<<4, 256, 0, stream>>>(
        bq + (long)l * 1024, bk + (long)l * 1024, bv + (long)l * 1024, bqkv, 1024);
    transpose_split<<<dim3(16, 64, 1), 256, 0, stream>>>(
        W1 + (long)l * DMODEL * DFF, w1h, w1l, 0, 0, DFF, DMODEL, DFF);
    transpose_split<<<dim3(64, 16, 1), 256, 0, stream>>>(
        W2 + (long)l * DFF * DMODEL, w2h, w2l, 0, 0, DMODEL, DFF, DMODEL);

    // fused QKV projection: [S][1024] @ [3072][1024]^T -> [S][3072]
    gemm3<false, false, false><<<dim3(32, 24), 256, 0, stream>>>(
        xh, xl, wqkvh, wqkvl, bqkv, qkvb, nullptr, nullptr, 1024, 3072, 0);

    attn_f32<<<dim3(S_LEN / 64, NHEAD), 256, 0, stream>>>(qkvb, yb);

    resid_ln_kernel<<<S_LEN, 256, 0, stream>>>(x, yb,
        ln1g + (size_t)l * DMODEL, ln1b + (size_t)l * DMODEL, xh, xl);

    // FFN1 with fused ReLU + bf16 split output
    gemm3<true, true, false><<<dim3(32, 32), 256, 0, stream>>>(
        xh, xl, w1h, w1l, b1 + (long)l * DFF, nullptr, h1h, h1l, 1024, 4096, 0);
    // FFN2
    gemm3<false, false, false><<<dim3(32, 8), 256, 0, stream>>>(
        h1h, h1l, w2h, w2l, b2 + (long)l * DMODEL, yb, nullptr, nullptr,
        4096, 1024, 0);

    resid_ln_kernel<<<S_LEN, 256, 0, stream>>>(x, yb,
        ln2g + (size_t)l * DMODEL, ln2b + (size_t)l * DMODEL, xh, xl);
  }

  // logits: stream Wout through ws in 4096-column strips
  for (int is = 0; is < 13; ++is) {
    int n0 = is * 4096;
    int ncols = VOCAB - n0; if (ncols > 4096) ncols = 4096;
    int nt64 = (ncols + 63) / 64;
    int nb128 = (ncols + 127) / 128;
    transpose_split<<<dim3(16, nt64, 1), 256, 0, stream>>>(
        Wout + n0, stripH, stripL, 0, 0, VOCAB, DMODEL, ncols);
    gemm3<false, false, true><<<dim3(32, nb128), 256, 0, stream>>>(
        xh, xl, stripH, stripL, bout + n0, outf + n0, nullptr, nullptr,
        1024, VOCAB, ncols);
  }
  softmax_v_kernel<<<S_LEN, 256, 0, stream>>>(outf);
}

// Round 3
// 5922.513 us; speedup vs baseline: 2.6524x; 1.5357x over previous
//
#include <hip/hip_runtime.h>
#include <math.h>

#define S_LEN  4096
#define DMODEL 1024
#define NHEAD  16
#define DHEAD  64
#define DFF    4096
#define NLAYER 4
#define VOCAB  50257

typedef unsigned short ushort_t;
typedef __attribute__((ext_vector_type(8))) __bf16 bf16x8;
typedef __attribute__((ext_vector_type(4))) float f32x4;

static __device__ __forceinline__ ushort_t f2bf(float f) {
  union { float f; unsigned u; } x; x.f = f;
  unsigned r = x.u + 0x7fffu + ((x.u >> 16) & 1u);
  return (ushort_t)(r >> 16);
}
static __device__ __forceinline__ float bf2f(ushort_t h) {
  union { unsigned u; float f; } x; x.u = ((unsigned)h) << 16;
  return x.f;
}

#define GLOAD_LDS16(gp, lp) \
  __builtin_amdgcn_global_load_lds((const __attribute__((address_space(1))) void*)(gp), \
                                   (__attribute__((address_space(3))) void*)(lp), 16, 0, 0)

// ---------------------------------------------------------------------------
// embedding + sinusoidal positional encoding, fused bf16 hi/lo split
// ---------------------------------------------------------------------------
__global__ __launch_bounds__(256) void embed_kernel(
    const int* __restrict__ tokens, const float* __restrict__ emb,
    float* __restrict__ x, ushort_t* __restrict__ xh, ushort_t* __restrict__ xl)
{
  int s = blockIdx.x;
  int tok = tokens[s];
  int d0 = threadIdx.x * 4;
  const double lf = 0.01798894603901598653; // log(10000)/512
  float4 ev = *(const float4*)(emb + (size_t)tok * DMODEL + d0);
  float o[4]; float evr[4] = {ev.x, ev.y, ev.z, ev.w};
  #pragma unroll
  for (int j = 0; j < 4; ++j) {
    int d = d0 + j;
    int i = (d < 512) ? d : d - 512;
    double ang = (double)s * exp(-lf * (double)i);
    float pe = (d < 512) ? (float)sin(ang) : (float)cos(ang);
    o[j] = evr[j] + pe;
  }
  *(float4*)(x + (size_t)s * DMODEL + d0) = make_float4(o[0], o[1], o[2], o[3]);
  ushort_t hv[4], lv[4];
  #pragma unroll
  for (int j = 0; j < 4; ++j) {
    hv[j] = f2bf(o[j]);
    lv[j] = f2bf(o[j] - bf2f(hv[j]));
  }
  *(ushort4*)(xh + (size_t)s * DMODEL + d0) = make_ushort4(hv[0], hv[1], hv[2], hv[3]);
  *(ushort4*)(xl + (size_t)s * DMODEL + d0) = make_ushort4(lv[0], lv[1], lv[2], lv[3]);
}

// ---------------------------------------------------------------------------
// transpose + split: in f32 [K][N] (row stride in_rstride) -> out bf16 hi/lo
// [N][Kout] K-contiguous. Zero-fills columns >= Nvalid. blockIdx.z batches.
// ---------------------------------------------------------------------------
__global__ __launch_bounds__(256)
void transpose_split(const float* __restrict__ in, ushort_t* __restrict__ oh,
                     ushort_t* __restrict__ ol, long in_zstr, long out_zoff,
                     int in_rstride, int Kout, int Nvalid)
{
  __shared__ float tile[64][65];
  const float* inz = in + (long)blockIdx.z * in_zstr;
  ushort_t* ohz = oh + (long)blockIdx.z * out_zoff;
  ushort_t* olz = ol + (long)blockIdx.z * out_zoff;
  int k0 = blockIdx.x * 64, n0 = blockIdx.y * 64;
  int t = threadIdx.x;
  #pragma unroll
  for (int i = 0; i < 4; ++i) {
    int idx = t + i * 256;            // 0..1023
    int kk = idx >> 4, c4 = idx & 15;
    #pragma unroll
    for (int j = 0; j < 4; ++j) {
      int n = n0 + c4 * 4 + j;
      float v = (n < Nvalid) ? inz[(long)(k0 + kk) * in_rstride + n] : 0.f;
      tile[c4 * 4 + j][kk] = v;       // transposed into LDS
    }
  }
  __syncthreads();
  #pragma unroll
  for (int i = 0; i < 4; ++i) {
    int idx = t + i * 256;
    int nn = idx >> 4, k4 = idx & 15;
    ushort_t hv[4], lv[4];
    #pragma unroll
    for (int j = 0; j < 4; ++j) {
      float v = tile[nn][k4 * 4 + j];
      hv[j] = f2bf(v);
      lv[j] = f2bf(v - bf2f(hv[j]));
    }
    long ob = (long)(n0 + nn) * Kout + k0 + k4 * 4;
    *(ushort4*)(ohz + ob) = make_ushort4(hv[0], hv[1], hv[2], hv[3]);
    *(ushort4*)(olz + ob) = make_ushort4(lv[0], lv[1], lv[2], lv[3]);
  }
}

// ---------------------------------------------------------------------------
// bf16 transpose: vb [H][S][64] -> vt [H][64][S]
// ---------------------------------------------------------------------------
__global__ __launch_bounds__(256)
void transpose_v(const ushort_t* __restrict__ vb, ushort_t* __restrict__ vt)
{
  __shared__ ushort_t tile[64][72];
  int h = blockIdx.y, s0 = blockIdx.x * 64;
  int t = threadIdx.x;
  const ushort_t* src = vb + ((size_t)h * S_LEN + s0) * 64;
  #pragma unroll
  for (int i = 0; i < 4; ++i) {
    int idx = t + i * 256;            // 0..1023 ushort4 units
    int row = idx >> 4, c4 = idx & 15;
    *(ushort4*)&tile[row][c4 * 4] = *(const ushort4*)(src + (size_t)row * 64 + c4 * 4);
  }
  __syncthreads();
  ushort_t* dst = vt + (size_t)h * DHEAD * S_LEN + s0;
  #pragma unroll
  for (int i = 0; i < 4; ++i) {
    int idx = t + i * 256;
    int e = idx >> 4, s4 = idx & 15;
    ushort4 o = make_ushort4(tile[s4*4+0][e], tile[s4*4+1][e],
                             tile[s4*4+2][e], tile[s4*4+3][e]);
    *(ushort4*)(dst + (size_t)e * S_LEN + s4 * 4) = o;
  }
}

// ---------------------------------------------------------------------------
// concat 3 bias vectors of length n into one [3n]
// ---------------------------------------------------------------------------
__global__ __launch_bounds__(256)
void concat3_kernel(const float* __restrict__ a, const float* __restrict__ b,
                    const float* __restrict__ c, float* __restrict__ o, int n)
{
  int i = blockIdx.x * 256 + threadIdx.x;
  if (i < n) { o[i] = a[i]; o[n + i] = b[i]; o[2 * n + i] = c[i]; }
}

// ---------------------------------------------------------------------------
// split-bf16 MFMA GEMM: C = A @ B^T (+bias). A hi/lo [M][K], B hi/lo [N][K].
// 128x128 tile, BK=32, 4 waves, 16x16x32 MFMA, NPROD-product split accum.
// EPI: 0 = f32 C, 1 = bf16 hi/lo split C, 2 = QKV routing (q scaled+split,
//      k split, v bf16, all [H][S][64]).
// ---------------------------------------------------------------------------
template<int EPI, bool RELU, bool BOUND, int NPROD>
__global__ __launch_bounds__(256)
void gemm3(const ushort_t* __restrict__ Ah, const ushort_t* __restrict__ Al,
           const ushort_t* __restrict__ Bh, const ushort_t* __restrict__ Bl,
           const float* __restrict__ bias, float* __restrict__ C,
           ushort_t* __restrict__ O0, ushort_t* __restrict__ O1,
           ushort_t* __restrict__ O2, ushort_t* __restrict__ O3,
           ushort_t* __restrict__ O4,
           int K, long ldc, int Nlimit)
{
  __shared__ ushort_t lds[4 * 4096];  // Ah | Al | Bh | Bl, each 128x32 bf16

  const int t = threadIdx.x;
  const int l = t & 63;
  const int w = t >> 6;
  const int wr = w >> 1, wc = w & 1;
  const long m0 = (long)blockIdx.x * 128;
  const long n0 = (long)blockIdx.y * 128;
  const int lrow = l & 15;
  const int lk   = (l >> 4) * 8;

  f32x4 acc[4][4];
  #pragma unroll
  for (int m = 0; m < 4; ++m)
    #pragma unroll
    for (int n = 0; n < 4; ++n) acc[m][n] = (f32x4)0.f;

  const ushort_t* ag[2]; const ushort_t* alg[2];
  const ushort_t* bg[2]; const ushort_t* blg[2];
  #pragma unroll
  for (int i = 0; i < 2; ++i) {
    int s = i * 4 + w;
    long ar = m0 + s * 16 + lrow;
    long br = n0 + s * 16 + lrow;
    ag[i]  = Ah + ar * (long)K + lk;
    alg[i] = Al + ar * (long)K + lk;
    bg[i]  = Bh + br * (long)K + lk;
    blg[i] = Bl + br * (long)K + lk;
  }

  for (int k0 = 0; k0 < K; k0 += 32) {
    __syncthreads();
    #pragma unroll
    for (int i = 0; i < 2; ++i) {
      int s = i * 4 + w;
      GLOAD_LDS16(ag[i]  + k0, &lds[        s * 512 + l * 8]);
      if (NPROD == 3) GLOAD_LDS16(alg[i] + k0, &lds[ 4096 + s * 512 + l * 8]);
      GLOAD_LDS16(bg[i]  + k0, &lds[ 8192 + s * 512 + l * 8]);
      GLOAD_LDS16(blg[i] + k0, &lds[12288 + s * 512 + l * 8]);
    }
    __syncthreads();

    bf16x8 bh_[4], bl_[4];
    #pragma unroll
    for (int n = 0; n < 4; ++n) {
      bh_[n] = *(const bf16x8*)&lds[ 8192 + (wc * 4 + n) * 512 + l * 8];
      bl_[n] = *(const bf16x8*)&lds[12288 + (wc * 4 + n) * 512 + l * 8];
    }
    #pragma unroll
    for (int m = 0; m < 4; ++m) {
      bf16x8 ah_ = *(const bf16x8*)&lds[       (wr * 4 + m) * 512 + l * 8];
      #pragma unroll
      for (int n = 0; n < 4; ++n) {
        acc[m][n] = __builtin_amdgcn_mfma_f32_16x16x32_bf16(ah_, bh_[n], acc[m][n], 0, 0, 0);
        acc[m][n] = __builtin_amdgcn_mfma_f32_16x16x32_bf16(ah_, bl_[n], acc[m][n], 0, 0, 0);
      }
      if (NPROD == 3) {
        bf16x8 al_ = *(const bf16x8*)&lds[4096 + (wr * 4 + m) * 512 + l * 8];
        #pragma unroll
        for (int n = 0; n < 4; ++n)
          acc[m][n] = __builtin_amdgcn_mfma_f32_16x16x32_bf16(al_, bh_[n], acc[m][n], 0, 0, 0);
      }
    }
  }

  // epilogue: element (row, col) = acc[m][n][r]
  #pragma unroll
  for (int n = 0; n < 4; ++n) {
    long col = n0 + wc * 64 + n * 16 + lrow;
    bool cok = (!BOUND) || (col < (long)Nlimit);
    float bv = cok ? bias[col] : 0.f;
    #pragma unroll
    for (int m = 0; m < 4; ++m) {
      #pragma unroll
      for (int r = 0; r < 4; ++r) {
        long row = m0 + wr * 64 + m * 16 + (l >> 4) * 4 + r;
        float v = acc[m][n][r] + bv;
        if (RELU) v = fmaxf(v, 0.f);
        if (cok) {
          if (EPI == 0) {
            C[row * ldc + col] = v;
          } else if (EPI == 1) {
            ushort_t h = f2bf(v);
            O0[row * ldc + col] = h;
            O1[row * ldc + col] = f2bf(v - bf2f(h));
          } else {
            int c = (int)col;
            if (c < 1024) {
              int hh = c >> 6, e = c & 63;
              float qv = v * 0.125f;           // fold 1/sqrt(DH) exactly
              ushort_t hi = f2bf(qv);
              size_t a = ((size_t)hh * S_LEN + row) * 64 + e;
              O0[a] = hi; O1[a] = f2bf(qv - bf2f(hi));
            } else if (c < 2048) {
              int cc = c - 1024;
              int hh = cc >> 6, e = cc & 63;
              ushort_t hi = f2bf(v);
              size_t a = ((size_t)hh * S_LEN + row) * 64 + e;
              O2[a] = hi; O3[a] = f2bf(v - bf2f(hi));
            } else {
              int cc = c - 2048;
              int hh = cc >> 6, e = cc & 63;
              size_t a = ((size_t)hh * S_LEN + row) * 64 + e;
              O4[a] = f2bf(v);
            }
          }
        }
      }
    }
  }
}

// ---------------------------------------------------------------------------
// MFMA flash attention. qh/ql/kh/kl: [H][S][64] bf16 (q pre-scaled by 0.125),
// vt: [H][64][S] bf16. y out: [S][1024] f32.
// Block: 128 queries x 1 head, 4 waves (32 q-rows each), KT=64 key tiles.
// QK^T = 3-product split; PV = bf16 P (via XOR-swizzled LDS transpose) x bf16 V.
// ---------------------------------------------------------------------------
__global__ __launch_bounds__(256)
void attn_mfma(const ushort_t* __restrict__ qh, const ushort_t* __restrict__ ql,
               const ushort_t* __restrict__ kh, const ushort_t* __restrict__ kl,
               const ushort_t* __restrict__ vt, float* __restrict__ y)
{
  __shared__ ushort_t lds[20480];  // Kh[4096] Kl[4096] Vt[4096] P[4x2048]

  const int t = threadIdx.x, l = t & 63, w = t >> 6;
  const int lrow = l & 15, lhi = l >> 4;
  const int h = blockIdx.y;
  const int bw = blockIdx.x * 128 + w * 32;      // wave's first q row
  const size_t hS = (size_t)h * S_LEN * DHEAD;   // q/k base
  const size_t hV = (size_t)h * DHEAD * S_LEN;   // vt base
  const int pb = 12288 + w * 2048;               // per-wave P region (shorts)

  // Q fragments in registers (A-layout: row=lrow, k=lhi*8..+7)
  bf16x8 qhf[2][2], qlf[2][2];
  #pragma unroll
  for (int m = 0; m < 2; ++m)
    #pragma unroll
    for (int ks = 0; ks < 2; ++ks) {
      size_t a = hS + (size_t)(bw + m * 16 + lrow) * 64 + ks * 32 + lhi * 8;
      qhf[m][ks] = *(const bf16x8*)(qh + a);
      qlf[m][ks] = *(const bf16x8*)(ql + a);
    }

  f32x4 acc[2][4];
  #pragma unroll
  for (int m = 0; m < 2; ++m)
    #pragma unroll
    for (int n = 0; n < 4; ++n) acc[m][n] = (f32x4)0.f;
  float mrow[8], lsum[8];
  #pragma unroll
  for (int i = 0; i < 8; ++i) { mrow[i] = -1e30f; lsum[i] = 0.f; }

  for (int kt = 0; kt < S_LEN; kt += 64) {
    __syncthreads();
    #pragma unroll
    for (int i = 0; i < 2; ++i) {
      int s = i * 4 + w;
      size_t krow = (size_t)(kt + (s >> 1) * 16 + lrow);
      int koff = (s & 1) * 32 + lhi * 8;
      GLOAD_LDS16(kh + hS + krow * 64 + koff, &lds[       s * 512 + l * 8]);
      GLOAD_LDS16(kl + hS + krow * 64 + koff, &lds[4096 + s * 512 + l * 8]);
      size_t erow = (size_t)((s >> 1) * 16 + lrow);
      int toff = kt + (s & 1) * 32 + lhi * 8;
      GLOAD_LDS16(vt + hV + erow * S_LEN + toff, &lds[8192 + s * 512 + l * 8]);
    }
    __syncthreads();

    // ---- scores = Q K^T (pre-scaled), split 3-product ----
    f32x4 sacc[2][4];
    #pragma unroll
    for (int m = 0; m < 2; ++m)
      #pragma unroll
      for (int n = 0; n < 4; ++n) sacc[m][n] = (f32x4)0.f;
    #pragma unroll
    for (int ks = 0; ks < 2; ++ks) {
      bf16x8 bh_[4], bl_[4];
      #pragma unroll
      for (int n = 0; n < 4; ++n) {
        bh_[n] = *(const bf16x8*)&lds[       (n * 2 + ks) * 512 + l * 8];
        bl_[n] = *(const bf16x8*)&lds[4096 + (n * 2 + ks) * 512 + l * 8];
      }
      #pragma unroll
      for (int m = 0; m < 2; ++m)
        #pragma unroll
        for (int n = 0; n < 4; ++n) {
          sacc[m][n] = __builtin_amdgcn_mfma_f32_16x16x32_bf16(qhf[m][ks], bh_[n], sacc[m][n], 0, 0, 0);
          sacc[m][n] = __builtin_amdgcn_mfma_f32_16x16x32_bf16(qhf[m][ks], bl_[n], sacc[m][n], 0, 0, 0);
          sacc[m][n] = __builtin_amdgcn_mfma_f32_16x16x32_bf16(qlf[m][ks], bh_[n], sacc[m][n], 0, 0, 0);
        }
    }

    // ---- online softmax; write P (bf16) to per-wave LDS in A-frag layout ----
    #pragma unroll
    for (int m = 0; m < 2; ++m) {
      #pragma unroll
      for (int r = 0; r < 4; ++r) {
        const int idx = m * 4 + r;
        float tm = fmaxf(fmaxf(sacc[m][0][r], sacc[m][1][r]),
                         fmaxf(sacc[m][2][r], sacc[m][3][r]));
        tm = fmaxf(tm, __shfl_xor(tm, 1));
        tm = fmaxf(tm, __shfl_xor(tm, 2));
        tm = fmaxf(tm, __shfl_xor(tm, 4));
        tm = fmaxf(tm, __shfl_xor(tm, 8));
        float mn = fmaxf(mrow[idx], tm);
        float al = __expf(mrow[idx] - mn);
        mrow[idx] = mn;
        float rs = 0.f;
        #pragma unroll
        for (int n = 0; n < 4; ++n) {
          float p = __expf(sacc[m][n][r] - mn);
          rs += p;
          int pa = pb + ((m * 2 + (n >> 1)) << 9) + (((n & 1) * 2 + (lrow >> 3)) << 7)
                   + ((lhi * 4 + r) << 3) + (l & 7);
          pa ^= (lrow >> 3) << 3;          // bank swizzle
          lds[pa] = f2bf(p);
        }
        rs += __shfl_xor(rs, 1);
        rs += __shfl_xor(rs, 2);
        rs += __shfl_xor(rs, 4);
        rs += __shfl_xor(rs, 8);
        lsum[idx] = lsum[idx] * al + rs;
        #pragma unroll
        for (int n = 0; n < 4; ++n) acc[m][n][r] *= al;
      }
    }

    // ---- O += P V ----
    #pragma unroll
    for (int ks = 0; ks < 2; ++ks) {
      bf16x8 pa_[2];
      #pragma unroll
      for (int m = 0; m < 2; ++m) {
        int ra = pb + ((m * 2 + ks) << 9) + (l << 3);
        ra ^= ((l >> 4) & 1) << 3;
        pa_[m] = *(const bf16x8*)&lds[ra];
      }
      #pragma unroll
      for (int n = 0; n < 4; ++n) {
        bf16x8 vf = *(const bf16x8*)&lds[8192 + (n * 2 + ks) * 512 + l * 8];
        #pragma unroll
        for (int m = 0; m < 2; ++m)
          acc[m][n] = __builtin_amdgcn_mfma_f32_16x16x32_bf16(pa_[m], vf, acc[m][n], 0, 0, 0);
      }
    }
  }

  // ---- normalize + write y[s][h*64+e] ----
  #pragma unroll
  for (int m = 0; m < 2; ++m) {
    #pragma unroll
    for (int r = 0; r < 4; ++r) {
      float inv = 1.0f / lsum[m * 4 + r];
      int row = bw + m * 16 + lhi * 4 + r;
      #pragma unroll
      for (int n = 0; n < 4; ++n)
        y[(size_t)row * DMODEL + h * 64 + n * 16 + lrow] = acc[m][n][r] * inv;
    }
  }
}

// ---------------------------------------------------------------------------
__device__ __forceinline__ float block_sum256(float v, float* sm)
{
  #pragma unroll
  for (int off = 32; off >= 1; off >>= 1) v += __shfl_xor(v, off);
  int w = threadIdx.x >> 6;
  if ((threadIdx.x & 63) == 0) sm[w] = v;
  __syncthreads();
  v = sm[0] + sm[1] + sm[2] + sm[3];
  __syncthreads();
  return v;
}

__device__ __forceinline__ float block_max256(float v, float* sm)
{
  #pragma unroll
  for (int off = 32; off >= 1; off >>= 1) v = fmaxf(v, __shfl_xor(v, off));
  int w = threadIdx.x >> 6;
  if ((threadIdx.x & 63) == 0) sm[w] = v;
  __syncthreads();
  v = fmaxf(fmaxf(sm[0], sm[1]), fmaxf(sm[2], sm[3]));
  __syncthreads();
  return v;
}

// x = layernorm(x + y) * g + b, fused bf16 hi/lo split of the result
__global__ __launch_bounds__(256)
void resid_ln_kernel(float* __restrict__ x, const float* __restrict__ y,
                     const float* __restrict__ g, const float* __restrict__ b,
                     ushort_t* __restrict__ xh, ushort_t* __restrict__ xl)
{
  __shared__ float sm[4];
  int row = blockIdx.x, t = threadIdx.x;
  float4 xv = *(const float4*)(x + (size_t)row * DMODEL + t * 4);
  float4 yv = *(const float4*)(y + (size_t)row * DMODEL + t * 4);
  float a0 = xv.x + yv.x, a1 = xv.y + yv.y, a2 = xv.z + yv.z, a3 = xv.w + yv.w;
  float s = block_sum256(a0 + a1 + a2 + a3, sm);
  float mean = s * (1.0f / DMODEL);
  float d0 = a0 - mean, d1 = a1 - mean, d2 = a2 - mean, d3 = a3 - mean;
  float vs = block_sum256(d0*d0 + d1*d1 + d2*d2 + d3*d3, sm);
  float inv = rsqrtf(vs * (1.0f / DMODEL) + 1e-5f);
  float4 gv = *(const float4*)(g + t * 4);
  float4 bv = *(const float4*)(b + t * 4);
  float o[4];
  o[0] = d0 * inv * gv.x + bv.x;
  o[1] = d1 * inv * gv.y + bv.y;
  o[2] = d2 * inv * gv.z + bv.z;
  o[3] = d3 * inv * gv.w + bv.w;
  *(float4*)(x + (size_t)row * DMODEL + t * 4) = make_float4(o[0], o[1], o[2], o[3]);
  ushort_t hv[4], lv[4];
  #pragma unroll
  for (int j = 0; j < 4; ++j) {
    hv[j] = f2bf(o[j]);
    lv[j] = f2bf(o[j] - bf2f(hv[j]));
  }
  *(ushort4*)(xh + (size_t)row * DMODEL + t * 4) = make_ushort4(hv[0], hv[1], hv[2], hv[3]);
  *(ushort4*)(xl + (size_t)row * DMODEL + t * 4) = make_ushort4(lv[0], lv[1], lv[2], lv[3]);
}

// in-place row softmax over VOCAB
__global__ __launch_bounds__(256)
void softmax_v_kernel(float* __restrict__ out)
{
  __shared__ float sm[4];
  int row = blockIdx.x, t = threadIdx.x;
  float* p = out + (size_t)row * VOCAB;
  float mx = -1e30f;
  for (int i = t; i < VOCAB; i += 256) mx = fmaxf(mx, p[i]);
  mx = block_max256(mx, sm);
  float s = 0.f;
  for (int i = t; i < VOCAB; i += 256) s += __expf(p[i] - mx);
  s = block_sum256(s, sm);
  float inv = 1.0f / s;
  for (int i = t; i < VOCAB; i += 256) p[i] = __expf(p[i] - mx) * inv;
}

// ---------------------------------------------------------------------------
extern "C" void kernel_launch(void* const* d_in, const int* in_sizes, int n_in,
                              void* d_out, int out_size, void* d_ws, size_t ws_size,
                              hipStream_t stream)
{
  const int*   tokens = (const int*)  d_in[0];
  const float* emb    = (const float*)d_in[1];
  const float* Wq     = (const float*)d_in[2];
  const float* bq     = (const float*)d_in[3];
  const float* Wk     = (const float*)d_in[4];
  const float* bk     = (const float*)d_in[5];
  const float* Wv     = (const float*)d_in[6];
  const float* bv     = (const float*)d_in[7];
  const float* ln1g   = (const float*)d_in[8];
  const float* ln1b   = (const float*)d_in[9];
  const float* W1     = (const float*)d_in[10];
  const float* b1     = (const float*)d_in[11];
  const float* W2     = (const float*)d_in[12];
  const float* b2     = (const float*)d_in[13];
  const float* ln2g   = (const float*)d_in[14];
  const float* ln2b   = (const float*)d_in[15];
  const float* Wout   = (const float*)d_in[16];
  const float* bout   = (const float*)d_in[17];

  // workspace (>=32 MB): xh | xl | stripH | stripL (8 MB each)
  char* wsb = (char*)d_ws;
  ushort_t* xh     = (ushort_t*)(wsb);
  ushort_t* xl     = (ushort_t*)(wsb + ((size_t)8  << 20));
  ushort_t* stripH = (ushort_t*)(wsb + ((size_t)16 << 20));
  ushort_t* stripL = (ushort_t*)(wsb + ((size_t)24 << 20));

  // scratch in d_out (823 MB; all dead before the logits GEMM writes it)
  char* ob = (char*)d_out;
  float*    x    = (float*)(ob);                          // [S][D] f32 16MB
  float*    yb   = (float*)(ob + ((size_t)16  << 20));    // [S][D] f32 16MB
  ushort_t* qh   = (ushort_t*)(ob + ((size_t)32  << 20)); // [H][S][64] 8MB
  ushort_t* ql   = (ushort_t*)(ob + ((size_t)40  << 20));
  ushort_t* kh   = (ushort_t*)(ob + ((size_t)48  << 20));
  ushort_t* kl   = (ushort_t*)(ob + ((size_t)56  << 20));
  ushort_t* vb16 = (ushort_t*)(ob + ((size_t)64  << 20));
  ushort_t* vt   = (ushort_t*)(ob + ((size_t)72  << 20)); // [H][64][S] 8MB
  ushort_t* h1h  = (ushort_t*)(ob + ((size_t)80  << 20)); // [S][DFF] 32MB
  ushort_t* h1l  = (ushort_t*)(ob + ((size_t)112 << 20));
  ushort_t* wqkvh= (ushort_t*)(ob + ((size_t)144 << 20)); // [3072][1024] 6MB
  ushort_t* wqkvl= (ushort_t*)(ob + ((size_t)150 << 20));
  ushort_t* w1h  = (ushort_t*)(ob + ((size_t)156 << 20)); // [4096][1024] 8MB
  ushort_t* w1l  = (ushort_t*)(ob + ((size_t)164 << 20));
  ushort_t* w2h  = (ushort_t*)(ob + ((size_t)172 << 20)); // [1024][4096] 8MB
  ushort_t* w2l  = (ushort_t*)(ob + ((size_t)180 << 20));
  float*    bqkv = (float*)(ob + ((size_t)188 << 20));    // [3072] f32
  float*    outf = (float*)d_out;

  embed_kernel<<<S_LEN, 256, 0, stream>>>(tokens, emb, x, xh, xl);

  for (int l = 0; l < NLAYER; ++l) {
    const long wofs = (long)l * NHEAD * DMODEL * DHEAD;
    transpose_split<<<dim3(16, 1, 16), 256, 0, stream>>>(
        Wq + wofs, wqkvh, wqkvl, (long)DMODEL * DHEAD, (long)DHEAD * DMODEL,
        DHEAD, DMODEL, DHEAD);
    transpose_split<<<dim3(16, 1, 16), 256, 0, stream>>>(
        Wk + wofs, wqkvh + 1024 * 1024, wqkvl + 1024 * 1024,
        (long)DMODEL * DHEAD, (long)DHEAD * DMODEL, DHEAD, DMODEL, DHEAD);
    transpose_split<<<dim3(16, 1, 16), 256, 0, stream>>>(
        Wv + wofs, wqkvh + 2048 * 1024, wqkvl + 2048 * 1024,
        (long)DMODEL * DHEAD, (long)DHEAD * DMODEL, DHEAD, DMODEL, DHEAD);
    concat3_kernel<<<4, 256, 0, stream>>>(
        bq + (long)l * 1024, bk + (long)l * 1024, bv + (long)l * 1024, bqkv, 1024);
    transpose_split<<<dim3(16, 64, 1), 256, 0, stream>>>(
        W1 + (long)l * DMODEL * DFF, w1h, w1l, 0, 0, DFF, DMODEL, DFF);
    transpose_split<<<dim3(64, 16, 1), 256, 0, stream>>>(
        W2 + (long)l * DFF * DMODEL, w2h, w2l, 0, 0, DMODEL, DFF, DMODEL);

    // fused QKV projection with split/scale/route epilogue
    gemm3<2, false, false, 3><<<dim3(32, 24), 256, 0, stream>>>(
        xh, xl, wqkvh, wqkvl, bqkv, nullptr, qh, ql, kh, kl, vb16,
        1024, 0, 0);
    transpose_v<<<dim3(64, 16), 256, 0, stream>>>(vb16, vt);

    attn_mfma<<<dim3(32, 16), 256, 0, stream>>>(qh, ql, kh, kl, vt, yb);

    resid_ln_kernel<<<S_LEN, 256, 0, stream>>>(x, yb,
        ln1g + (size_t)l * DMODEL, ln1b + (size_t)l * DMODEL, xh, xl);

    gemm3<1, true, false, 3><<<dim3(32, 32), 256, 0, stream>>>(
        xh, xl, w1h, w1l, b1 + (long)l * DFF, nullptr, h1h, h1l,
        nullptr, nullptr, nullptr, 1024, 4096, 0);
    gemm3<0, false, false, 3><<<dim3(32, 8), 256, 0, stream>>>(
        h1h, h1l, w2h, w2l, b2 + (long)l * DMODEL, yb,
        nullptr, nullptr, nullptr, nullptr, nullptr, 4096, 1024, 0);

    resid_ln_kernel<<<S_LEN, 256, 0, stream>>>(x, yb,
        ln2g + (size_t)l * DMODEL, ln2b + (size_t)l * DMODEL, xh, xl);
  }

  // logits: stream Wout strips; 2-product split (drop Al*Bh)
  for (int is = 0; is < 13; ++is) {
    int n0 = is * 4096;
    int ncols = VOCAB - n0; if (ncols > 4096) ncols = 4096;
    int nt64 = (ncols + 63) / 64;
    int nb128 = (ncols + 127) / 128;
    transpose_split<<<dim3(16, nt64, 1), 256, 0, stream>>>(
        Wout + n0, stripH, stripL, 0, 0, VOCAB, DMODEL, ncols);
    gemm3<0, false, true, 2><<<dim3(32, nb128), 256, 0, stream>>>(
        xh, xl, stripH, stripL, bout + n0, outf + n0,
        nullptr, nullptr, nullptr, nullptr, nullptr, 1024, VOCAB, ncols);
  }
  softmax_v_kernel<<<S_LEN, 256, 0, stream>>>(outf);
}

// Round 4
// 5682.223 us; speedup vs baseline: 2.7645x; 1.0423x over previous
//
#include <hip/hip_runtime.h>
#include <math.h>

#define S_LEN  4096
#define DMODEL 1024
#define NHEAD  16
#define DHEAD  64
#define DFF    4096
#define NLAYER 4
#define VOCAB  50257
#define NCBP   400   // partials row stride (col-blocks, padded)

typedef unsigned short ushort_t;
typedef __attribute__((ext_vector_type(8))) __bf16 bf16x8;
typedef __attribute__((ext_vector_type(4))) float f32x4;

static __device__ __forceinline__ ushort_t f2bf(float f) {
  union { float f; unsigned u; } x; x.f = f;
  unsigned r = x.u + 0x7fffu + ((x.u >> 16) & 1u);
  return (ushort_t)(r >> 16);
}
static __device__ __forceinline__ float bf2f(ushort_t h) {
  union { unsigned u; float f; } x; x.u = ((unsigned)h) << 16;
  return x.f;
}

#define GLOAD_LDS16(gp, lp) \
  __builtin_amdgcn_global_load_lds((const __attribute__((address_space(1))) void*)(gp), \
                                   (__attribute__((address_space(3))) void*)(lp), 16, 0, 0)

// ---------------------------------------------------------------------------
// embedding + sinusoidal positional encoding, fused bf16 hi/lo split
// ---------------------------------------------------------------------------
__global__ __launch_bounds__(256) void embed_kernel(
    const int* __restrict__ tokens, const float* __restrict__ emb,
    float* __restrict__ x, ushort_t* __restrict__ xh, ushort_t* __restrict__ xl)
{
  int s = blockIdx.x;
  int tok = tokens[s];
  int d0 = threadIdx.x * 4;
  const double lf = 0.01798894603901598653; // log(10000)/512
  float4 ev = *(const float4*)(emb + (size_t)tok * DMODEL + d0);
  float o[4]; float evr[4] = {ev.x, ev.y, ev.z, ev.w};
  #pragma unroll
  for (int j = 0; j < 4; ++j) {
    int d = d0 + j;
    int i = (d < 512) ? d : d - 512;
    double ang = (double)s * exp(-lf * (double)i);
    float pe = (d < 512) ? (float)sin(ang) : (float)cos(ang);
    o[j] = evr[j] + pe;
  }
  *(float4*)(x + (size_t)s * DMODEL + d0) = make_float4(o[0], o[1], o[2], o[3]);
  ushort_t hv[4], lv[4];
  #pragma unroll
  for (int j = 0; j < 4; ++j) {
    hv[j] = f2bf(o[j]);
    lv[j] = f2bf(o[j] - bf2f(hv[j]));
  }
  *(ushort4*)(xh + (size_t)s * DMODEL + d0) = make_ushort4(hv[0], hv[1], hv[2], hv[3]);
  *(ushort4*)(xl + (size_t)s * DMODEL + d0) = make_ushort4(lv[0], lv[1], lv[2], lv[3]);
}

// ---------------------------------------------------------------------------
// transpose + split: in f32 [K][N] (row stride in_rstride) -> out bf16 hi/lo
// [N][Kout] K-contiguous. Zero-fills columns >= Nvalid. blockIdx.z batches.
// ---------------------------------------------------------------------------
__global__ __launch_bounds__(256)
void transpose_split(const float* __restrict__ in, ushort_t* __restrict__ oh,
                     ushort_t* __restrict__ ol, long in_zstr, long out_zoff,
                     int in_rstride, int Kout, int Nvalid)
{
  __shared__ float tile[64][65];
  const float* inz = in + (long)blockIdx.z * in_zstr;
  ushort_t* ohz = oh + (long)blockIdx.z * out_zoff;
  ushort_t* olz = ol + (long)blockIdx.z * out_zoff;
  int k0 = blockIdx.x * 64, n0 = blockIdx.y * 64;
  int t = threadIdx.x;
  #pragma unroll
  for (int i = 0; i < 4; ++i) {
    int idx = t + i * 256;            // 0..1023
    int kk = idx >> 4, c4 = idx & 15;
    #pragma unroll
    for (int j = 0; j < 4; ++j) {
      int n = n0 + c4 * 4 + j;
      float v = (n < Nvalid) ? inz[(long)(k0 + kk) * in_rstride + n] : 0.f;
      tile[c4 * 4 + j][kk] = v;       // transposed into LDS
    }
  }
  __syncthreads();
  #pragma unroll
  for (int i = 0; i < 4; ++i) {
    int idx = t + i * 256;
    int nn = idx >> 4, k4 = idx & 15;
    ushort_t hv[4], lv[4];
    #pragma unroll
    for (int j = 0; j < 4; ++j) {
      float v = tile[nn][k4 * 4 + j];
      hv[j] = f2bf(v);
      lv[j] = f2bf(v - bf2f(hv[j]));
    }
    long ob = (long)(n0 + nn) * Kout + k0 + k4 * 4;
    *(ushort4*)(ohz + ob) = make_ushort4(hv[0], hv[1], hv[2], hv[3]);
    *(ushort4*)(olz + ob) = make_ushort4(lv[0], lv[1], lv[2], lv[3]);
  }
}

// ---------------------------------------------------------------------------
// bf16 transpose: vb [H][S][64] -> vt [H][64][S]
// ---------------------------------------------------------------------------
__global__ __launch_bounds__(256)
void transpose_v(const ushort_t* __restrict__ vb, ushort_t* __restrict__ vt)
{
  __shared__ ushort_t tile[64][72];
  int h = blockIdx.y, s0 = blockIdx.x * 64;
  int t = threadIdx.x;
  const ushort_t* src = vb + ((size_t)h * S_LEN + s0) * 64;
  #pragma unroll
  for (int i = 0; i < 4; ++i) {
    int idx = t + i * 256;            // 0..1023 ushort4 units
    int row = idx >> 4, c4 = idx & 15;
    *(ushort4*)&tile[row][c4 * 4] = *(const ushort4*)(src + (size_t)row * 64 + c4 * 4);
  }
  __syncthreads();
  ushort_t* dst = vt + (size_t)h * DHEAD * S_LEN + s0;
  #pragma unroll
  for (int i = 0; i < 4; ++i) {
    int idx = t + i * 256;
    int e = idx >> 4, s4 = idx & 15;
    ushort4 o = make_ushort4(tile[s4*4+0][e], tile[s4*4+1][e],
                             tile[s4*4+2][e], tile[s4*4+3][e]);
    *(ushort4*)(dst + (size_t)e * S_LEN + s4 * 4) = o;
  }
}

// ---------------------------------------------------------------------------
// concat 3 bias vectors of length n into one [3n]
// ---------------------------------------------------------------------------
__global__ __launch_bounds__(256)
void concat3_kernel(const float* __restrict__ a, const float* __restrict__ b,
                    const float* __restrict__ c, float* __restrict__ o, int n)
{
  int i = blockIdx.x * 256 + threadIdx.x;
  if (i < n) { o[i] = a[i]; o[n + i] = b[i]; o[2 * n + i] = c[i]; }
}

// ---------------------------------------------------------------------------
// split-bf16 MFMA GEMM: C = A @ B^T (+bias). A hi/lo [M][K], B hi/lo [N][K].
// 128x128 tile, BK=32, 4 waves, 16x16x32 MFMA, NPROD-product split accum.
// EPI: 0 = f32 C, 1 = bf16 hi/lo split C, 2 = QKV routing,
//      3 = exp(logit) + deterministic per-row col-block partial sums.
// ---------------------------------------------------------------------------
template<int EPI, bool RELU, bool BOUND, int NPROD>
__global__ __launch_bounds__(256)
void gemm3(const ushort_t* __restrict__ Ah, const ushort_t* __restrict__ Al,
           const ushort_t* __restrict__ Bh, const ushort_t* __restrict__ Bl,
           const float* __restrict__ bias, float* __restrict__ C,
           ushort_t* __restrict__ O0, ushort_t* __restrict__ O1,
           ushort_t* __restrict__ O2, ushort_t* __restrict__ O3,
           ushort_t* __restrict__ O4,
           int K, long ldc, int Nlimit, float* __restrict__ Ppart, int cbbase)
{
  __shared__ ushort_t lds[4 * 4096];  // Ah | Al | Bh | Bl, each 128x32 bf16
  __shared__ float psum[(EPI == 3) ? 256 : 4];  // [wc][128] row sums

  const int t = threadIdx.x;
  const int l = t & 63;
  const int w = t >> 6;
  const int wr = w >> 1, wc = w & 1;
  const long m0 = (long)blockIdx.x * 128;
  const long n0 = (long)blockIdx.y * 128;
  const int lrow = l & 15;
  const int lk   = (l >> 4) * 8;

  f32x4 acc[4][4];
  #pragma unroll
  for (int m = 0; m < 4; ++m)
    #pragma unroll
    for (int n = 0; n < 4; ++n) acc[m][n] = (f32x4)0.f;

  const ushort_t* ag[2]; const ushort_t* alg[2];
  const ushort_t* bg[2]; const ushort_t* blg[2];
  #pragma unroll
  for (int i = 0; i < 2; ++i) {
    int s = i * 4 + w;
    long ar = m0 + s * 16 + lrow;
    long br = n0 + s * 16 + lrow;
    ag[i]  = Ah + ar * (long)K + lk;
    alg[i] = Al + ar * (long)K + lk;
    bg[i]  = Bh + br * (long)K + lk;
    blg[i] = Bl + br * (long)K + lk;
  }

  for (int k0 = 0; k0 < K; k0 += 32) {
    __syncthreads();
    #pragma unroll
    for (int i = 0; i < 2; ++i) {
      int s = i * 4 + w;
      GLOAD_LDS16(ag[i]  + k0, &lds[        s * 512 + l * 8]);
      if (NPROD == 3) GLOAD_LDS16(alg[i] + k0, &lds[ 4096 + s * 512 + l * 8]);
      GLOAD_LDS16(bg[i]  + k0, &lds[ 8192 + s * 512 + l * 8]);
      GLOAD_LDS16(blg[i] + k0, &lds[12288 + s * 512 + l * 8]);
    }
    __syncthreads();

    bf16x8 bh_[4], bl_[4];
    #pragma unroll
    for (int n = 0; n < 4; ++n) {
      bh_[n] = *(const bf16x8*)&lds[ 8192 + (wc * 4 + n) * 512 + l * 8];
      bl_[n] = *(const bf16x8*)&lds[12288 + (wc * 4 + n) * 512 + l * 8];
    }
    #pragma unroll
    for (int m = 0; m < 4; ++m) {
      bf16x8 ah_ = *(const bf16x8*)&lds[       (wr * 4 + m) * 512 + l * 8];
      #pragma unroll
      for (int n = 0; n < 4; ++n) {
        acc[m][n] = __builtin_amdgcn_mfma_f32_16x16x32_bf16(ah_, bh_[n], acc[m][n], 0, 0, 0);
        acc[m][n] = __builtin_amdgcn_mfma_f32_16x16x32_bf16(ah_, bl_[n], acc[m][n], 0, 0, 0);
      }
      if (NPROD == 3) {
        bf16x8 al_ = *(const bf16x8*)&lds[4096 + (wr * 4 + m) * 512 + l * 8];
        #pragma unroll
        for (int n = 0; n < 4; ++n)
          acc[m][n] = __builtin_amdgcn_mfma_f32_16x16x32_bf16(al_, bh_[n], acc[m][n], 0, 0, 0);
      }
    }
  }

  // epilogue: element (row, col) = acc[m][n][r]
  if (EPI == 3) {
    float smr[4][4];
    #pragma unroll
    for (int m = 0; m < 4; ++m)
      #pragma unroll
      for (int r = 0; r < 4; ++r) smr[m][r] = 0.f;
    #pragma unroll
    for (int n = 0; n < 4; ++n) {
      long col = n0 + wc * 64 + n * 16 + lrow;
      bool cok = (!BOUND) || (col < (long)Nlimit);
      float bv = cok ? bias[col] : 0.f;
      #pragma unroll
      for (int m = 0; m < 4; ++m) {
        #pragma unroll
        for (int r = 0; r < 4; ++r) {
          long row = m0 + wr * 64 + m * 16 + (l >> 4) * 4 + r;
          float e = cok ? __expf(acc[m][n][r] + bv) : 0.f;
          if (cok) C[row * ldc + col] = e;
          smr[m][r] += e;
        }
      }
    }
    #pragma unroll
    for (int m = 0; m < 4; ++m) {
      #pragma unroll
      for (int r = 0; r < 4; ++r) {
        float s = smr[m][r];
        s += __shfl_xor(s, 1);
        s += __shfl_xor(s, 2);
        s += __shfl_xor(s, 4);
        s += __shfl_xor(s, 8);
        if (lrow == 0)
          psum[wc * 128 + wr * 64 + m * 16 + (l >> 4) * 4 + r] = s;
      }
    }
    __syncthreads();
    if (t < 128)
      Ppart[(m0 + t) * NCBP + cbbase + blockIdx.y] = psum[t] + psum[128 + t];
    return;
  }

  #pragma unroll
  for (int n = 0; n < 4; ++n) {
    long col = n0 + wc * 64 + n * 16 + lrow;
    bool cok = (!BOUND) || (col < (long)Nlimit);
    float bv = cok ? bias[col] : 0.f;
    #pragma unroll
    for (int m = 0; m < 4; ++m) {
      #pragma unroll
      for (int r = 0; r < 4; ++r) {
        long row = m0 + wr * 64 + m * 16 + (l >> 4) * 4 + r;
        float v = acc[m][n][r] + bv;
        if (RELU) v = fmaxf(v, 0.f);
        if (cok) {
          if (EPI == 0) {
            C[row * ldc + col] = v;
          } else if (EPI == 1) {
            ushort_t h = f2bf(v);
            O0[row * ldc + col] = h;
            O1[row * ldc + col] = f2bf(v - bf2f(h));
          } else {
            int c = (int)col;
            if (c < 1024) {
              int hh = c >> 6, e = c & 63;
              float qv = v * 0.125f;           // fold 1/sqrt(DH) exactly
              ushort_t hi = f2bf(qv);
              size_t a = ((size_t)hh * S_LEN + row) * 64 + e;
              O0[a] = hi; O1[a] = f2bf(qv - bf2f(hi));
            } else if (c < 2048) {
              int cc = c - 1024;
              int hh = cc >> 6, e = cc & 63;
              ushort_t hi = f2bf(v);
              size_t a = ((size_t)hh * S_LEN + row) * 64 + e;
              O2[a] = hi; O3[a] = f2bf(v - bf2f(hi));
            } else {
              int cc = c - 2048;
              int hh = cc >> 6, e = cc & 63;
              size_t a = ((size_t)hh * S_LEN + row) * 64 + e;
              O4[a] = f2bf(v);
            }
          }
        }
      }
    }
  }
}

// ---------------------------------------------------------------------------
// MFMA flash attention. qh/ql/kh/kl: [H][S][64] bf16 (q pre-scaled by 0.125),
// vt: [H][64][S] bf16. y out: [S][1024] f32.
// ---------------------------------------------------------------------------
__global__ __launch_bounds__(256)
void attn_mfma(const ushort_t* __restrict__ qh, const ushort_t* __restrict__ ql,
               const ushort_t* __restrict__ kh, const ushort_t* __restrict__ kl,
               const ushort_t* __restrict__ vt, float* __restrict__ y)
{
  __shared__ ushort_t lds[20480];  // Kh[4096] Kl[4096] Vt[4096] P[4x2048]

  const int t = threadIdx.x, l = t & 63, w = t >> 6;
  const int lrow = l & 15, lhi = l >> 4;
  const int h = blockIdx.y;
  const int bw = blockIdx.x * 128 + w * 32;      // wave's first q row
  const size_t hS = (size_t)h * S_LEN * DHEAD;   // q/k base
  const size_t hV = (size_t)h * DHEAD * S_LEN;   // vt base
  const int pb = 12288 + w * 2048;               // per-wave P region (shorts)

  bf16x8 qhf[2][2], qlf[2][2];
  #pragma unroll
  for (int m = 0; m < 2; ++m)
    #pragma unroll
    for (int ks = 0; ks < 2; ++ks) {
      size_t a = hS + (size_t)(bw + m * 16 + lrow) * 64 + ks * 32 + lhi * 8;
      qhf[m][ks] = *(const bf16x8*)(qh + a);
      qlf[m][ks] = *(const bf16x8*)(ql + a);
    }

  f32x4 acc[2][4];
  #pragma unroll
  for (int m = 0; m < 2; ++m)
    #pragma unroll
    for (int n = 0; n < 4; ++n) acc[m][n] = (f32x4)0.f;
  float mrow[8], lsum[8];
  #pragma unroll
  for (int i = 0; i < 8; ++i) { mrow[i] = -1e30f; lsum[i] = 0.f; }

  for (int kt = 0; kt < S_LEN; kt += 64) {
    __syncthreads();
    #pragma unroll
    for (int i = 0; i < 2; ++i) {
      int s = i * 4 + w;
      size_t krow = (size_t)(kt + (s >> 1) * 16 + lrow);
      int koff = (s & 1) * 32 + lhi * 8;
      GLOAD_LDS16(kh + hS + krow * 64 + koff, &lds[       s * 512 + l * 8]);
      GLOAD_LDS16(kl + hS + krow * 64 + koff, &lds[4096 + s * 512 + l * 8]);
      size_t erow = (size_t)((s >> 1) * 16 + lrow);
      int toff = kt + (s & 1) * 32 + lhi * 8;
      GLOAD_LDS16(vt + hV + erow * S_LEN + toff, &lds[8192 + s * 512 + l * 8]);
    }
    __syncthreads();

    f32x4 sacc[2][4];
    #pragma unroll
    for (int m = 0; m < 2; ++m)
      #pragma unroll
      for (int n = 0; n < 4; ++n) sacc[m][n] = (f32x4)0.f;
    #pragma unroll
    for (int ks = 0; ks < 2; ++ks) {
      bf16x8 bh_[4], bl_[4];
      #pragma unroll
      for (int n = 0; n < 4; ++n) {
        bh_[n] = *(const bf16x8*)&lds[       (n * 2 + ks) * 512 + l * 8];
        bl_[n] = *(const bf16x8*)&lds[4096 + (n * 2 + ks) * 512 + l * 8];
      }
      #pragma unroll
      for (int m = 0; m < 2; ++m)
        #pragma unroll
        for (int n = 0; n < 4; ++n) {
          sacc[m][n] = __builtin_amdgcn_mfma_f32_16x16x32_bf16(qhf[m][ks], bh_[n], sacc[m][n], 0, 0, 0);
          sacc[m][n] = __builtin_amdgcn_mfma_f32_16x16x32_bf16(qhf[m][ks], bl_[n], sacc[m][n], 0, 0, 0);
          sacc[m][n] = __builtin_amdgcn_mfma_f32_16x16x32_bf16(qlf[m][ks], bh_[n], sacc[m][n], 0, 0, 0);
        }
    }

    #pragma unroll
    for (int m = 0; m < 2; ++m) {
      #pragma unroll
      for (int r = 0; r < 4; ++r) {
        const int idx = m * 4 + r;
        float tm = fmaxf(fmaxf(sacc[m][0][r], sacc[m][1][r]),
                         fmaxf(sacc[m][2][r], sacc[m][3][r]));
        tm = fmaxf(tm, __shfl_xor(tm, 1));
        tm = fmaxf(tm, __shfl_xor(tm, 2));
        tm = fmaxf(tm, __shfl_xor(tm, 4));
        tm = fmaxf(tm, __shfl_xor(tm, 8));
        float mn = fmaxf(mrow[idx], tm);
        float al = __expf(mrow[idx] - mn);
        mrow[idx] = mn;
        float rs = 0.f;
        #pragma unroll
        for (int n = 0; n < 4; ++n) {
          float p = __expf(sacc[m][n][r] - mn);
          rs += p;
          int pa = pb + ((m * 2 + (n >> 1)) << 9) + (((n & 1) * 2 + (lrow >> 3)) << 7)
                   + ((lhi * 4 + r) << 3) + (l & 7);
          pa ^= (lrow >> 3) << 3;          // bank swizzle
          lds[pa] = f2bf(p);
        }
        rs += __shfl_xor(rs, 1);
        rs += __shfl_xor(rs, 2);
        rs += __shfl_xor(rs, 4);
        rs += __shfl_xor(rs, 8);
        lsum[idx] = lsum[idx] * al + rs;
        #pragma unroll
        for (int n = 0; n < 4; ++n) acc[m][n][r] *= al;
      }
    }

    #pragma unroll
    for (int ks = 0; ks < 2; ++ks) {
      bf16x8 pa_[2];
      #pragma unroll
      for (int m = 0; m < 2; ++m) {
        int ra = pb + ((m * 2 + ks) << 9) + (l << 3);
        ra ^= ((l >> 4) & 1) << 3;
        pa_[m] = *(const bf16x8*)&lds[ra];
      }
      #pragma unroll
      for (int n = 0; n < 4; ++n) {
        bf16x8 vf = *(const bf16x8*)&lds[8192 + (n * 2 + ks) * 512 + l * 8];
        #pragma unroll
        for (int m = 0; m < 2; ++m)
          acc[m][n] = __builtin_amdgcn_mfma_f32_16x16x32_bf16(pa_[m], vf, acc[m][n], 0, 0, 0);
      }
    }
  }

  #pragma unroll
  for (int m = 0; m < 2; ++m) {
    #pragma unroll
    for (int r = 0; r < 4; ++r) {
      float inv = 1.0f / lsum[m * 4 + r];
      int row = bw + m * 16 + lhi * 4 + r;
      #pragma unroll
      for (int n = 0; n < 4; ++n)
        y[(size_t)row * DMODEL + h * 64 + n * 16 + lrow] = acc[m][n][r] * inv;
    }
  }
}

// ---------------------------------------------------------------------------
__device__ __forceinline__ float block_sum256(float v, float* sm)
{
  #pragma unroll
  for (int off = 32; off >= 1; off >>= 1) v += __shfl_xor(v, off);
  int w = threadIdx.x >> 6;
  if ((threadIdx.x & 63) == 0) sm[w] = v;
  __syncthreads();
  v = sm[0] + sm[1] + sm[2] + sm[3];
  __syncthreads();
  return v;
}

// x = layernorm(x + y) * g + b, fused bf16 hi/lo split of the result
__global__ __launch_bounds__(256)
void resid_ln_kernel(float* __restrict__ x, const float* __restrict__ y,
                     const float* __restrict__ g, const float* __restrict__ b,
                     ushort_t* __restrict__ xh, ushort_t* __restrict__ xl)
{
  __shared__ float sm[4];
  int row = blockIdx.x, t = threadIdx.x;
  float4 xv = *(const float4*)(x + (size_t)row * DMODEL + t * 4);
  float4 yv = *(const float4*)(y + (size_t)row * DMODEL + t * 4);
  float a0 = xv.x + yv.x, a1 = xv.y + yv.y, a2 = xv.z + yv.z, a3 = xv.w + yv.w;
  float s = block_sum256(a0 + a1 + a2 + a3, sm);
  float mean = s * (1.0f / DMODEL);
  float d0 = a0 - mean, d1 = a1 - mean, d2 = a2 - mean, d3 = a3 - mean;
  float vs = block_sum256(d0*d0 + d1*d1 + d2*d2 + d3*d3, sm);
  float inv = rsqrtf(vs * (1.0f / DMODEL) + 1e-5f);
  float4 gv = *(const float4*)(g + t * 4);
  float4 bv = *(const float4*)(b + t * 4);
  float o[4];
  o[0] = d0 * inv * gv.x + bv.x;
  o[1] = d1 * inv * gv.y + bv.y;
  o[2] = d2 * inv * gv.z + bv.z;
  o[3] = d3 * inv * gv.w + bv.w;
  *(float4*)(x + (size_t)row * DMODEL + t * 4) = make_float4(o[0], o[1], o[2], o[3]);
  ushort_t hv[4], lv[4];
  #pragma unroll
  for (int j = 0; j < 4; ++j) {
    hv[j] = f2bf(o[j]);
    lv[j] = f2bf(o[j] - bf2f(hv[j]));
  }
  *(ushort4*)(xh + (size_t)row * DMODEL + t * 4) = make_ushort4(hv[0], hv[1], hv[2], hv[3]);
  *(ushort4*)(xl + (size_t)row * DMODEL + t * 4) = make_ushort4(lv[0], lv[1], lv[2], lv[3]);
}

// ---------------------------------------------------------------------------
// final scale: out[row] *= 1/sum(row); sum from deterministic partials
// ---------------------------------------------------------------------------
__global__ __launch_bounds__(256)
void scale_softmax(float* __restrict__ out, const float* __restrict__ partials,
                   int ncb)
{
  __shared__ float sm[4];
  int row = blockIdx.x, t = threadIdx.x;
  float s = 0.f;
  for (int cb = t; cb < ncb; cb += 256) s += partials[(size_t)row * NCBP + cb];
  s = block_sum256(s, sm);
  float inv = 1.0f / s;
  float* p = out + (size_t)row * VOCAB;
  int head = (int)((((uintptr_t)16 - ((uintptr_t)p & 15)) & 15) >> 2);
  if (t < head) p[t] *= inv;
  int nvec = (VOCAB - head) >> 2;
  float4* pv = (float4*)(p + head);
  for (int i = t; i < nvec; i += 256) {
    float4 v = pv[i];
    v.x *= inv; v.y *= inv; v.z *= inv; v.w *= inv;
    pv[i] = v;
  }
  int done = head + nvec * 4;
  if (t < VOCAB - done) p[done + t] *= inv;
}

// ---------------------------------------------------------------------------
extern "C" void kernel_launch(void* const* d_in, const int* in_sizes, int n_in,
                              void* d_out, int out_size, void* d_ws, size_t ws_size,
                              hipStream_t stream)
{
  const int*   tokens = (const int*)  d_in[0];
  const float* emb    = (const float*)d_in[1];
  const float* Wq     = (const float*)d_in[2];
  const float* bq     = (const float*)d_in[3];
  const float* Wk     = (const float*)d_in[4];
  const float* bk     = (const float*)d_in[5];
  const float* Wv     = (const float*)d_in[6];
  const float* bv     = (const float*)d_in[7];
  const float* ln1g   = (const float*)d_in[8];
  const float* ln1b   = (const float*)d_in[9];
  const float* W1     = (const float*)d_in[10];
  const float* b1     = (const float*)d_in[11];
  const float* W2     = (const float*)d_in[12];
  const float* b2     = (const float*)d_in[13];
  const float* ln2g   = (const float*)d_in[14];
  const float* ln2b   = (const float*)d_in[15];
  const float* Wout   = (const float*)d_in[16];
  const float* bout   = (const float*)d_in[17];

  // workspace (<=32 MB proven): xh|xl 8MB ea, stripH|stripL 4MB ea, partials 6.55MB
  char* wsb = (char*)d_ws;
  ushort_t* xh     = (ushort_t*)(wsb);
  ushort_t* xl     = (ushort_t*)(wsb + ((size_t)8  << 20));
  ushort_t* stripH = (ushort_t*)(wsb + ((size_t)16 << 20));
  ushort_t* stripL = (ushort_t*)(wsb + ((size_t)20 << 20));
  float*    partials = (float*)(wsb + ((size_t)24 << 20)); // [4096][NCBP] f32

  // scratch in d_out (823 MB; all dead before the logits GEMM writes it)
  char* ob = (char*)d_out;
  float*    x    = (float*)(ob);                          // [S][D] f32 16MB
  float*    yb   = (float*)(ob + ((size_t)16  << 20));    // [S][D] f32 16MB
  ushort_t* qh   = (ushort_t*)(ob + ((size_t)32  << 20)); // [H][S][64] 8MB
  ushort_t* ql   = (ushort_t*)(ob + ((size_t)40  << 20));
  ushort_t* kh   = (ushort_t*)(ob + ((size_t)48  << 20));
  ushort_t* kl   = (ushort_t*)(ob + ((size_t)56  << 20));
  ushort_t* vb16 = (ushort_t*)(ob + ((size_t)64  << 20));
  ushort_t* vt   = (ushort_t*)(ob + ((size_t)72  << 20)); // [H][64][S] 8MB
  ushort_t* h1h  = (ushort_t*)(ob + ((size_t)80  << 20)); // [S][DFF] 32MB
  ushort_t* h1l  = (ushort_t*)(ob + ((size_t)112 << 20));
  ushort_t* wqkvh= (ushort_t*)(ob + ((size_t)144 << 20)); // [3072][1024] 6MB
  ushort_t* wqkvl= (ushort_t*)(ob + ((size_t)150 << 20));
  ushort_t* w1h  = (ushort_t*)(ob + ((size_t)156 << 20)); // [4096][1024] 8MB
  ushort_t* w1l  = (ushort_t*)(ob + ((size_t)164 << 20));
  ushort_t* w2h  = (ushort_t*)(ob + ((size_t)172 << 20)); // [1024][4096] 8MB
  ushort_t* w2l  = (ushort_t*)(ob + ((size_t)180 << 20));
  float*    bqkv = (float*)(ob + ((size_t)188 << 20));    // [3072] f32
  float*    outf = (float*)d_out;

  embed_kernel<<<S_LEN, 256, 0, stream>>>(tokens, emb, x, xh, xl);

  for (int l = 0; l < NLAYER; ++l) {
    const long wofs = (long)l * NHEAD * DMODEL * DHEAD;
    transpose_split<<<dim3(16, 1, 16), 256, 0, stream>>>(
        Wq + wofs, wqkvh, wqkvl, (long)DMODEL * DHEAD, (long)DHEAD * DMODEL,
        DHEAD, DMODEL, DHEAD);
    transpose_split<<<dim3(16, 1, 16), 256, 0, stream>>>(
        Wk + wofs, wqkvh + 1024 * 1024, wqkvl + 1024 * 1024,
        (long)DMODEL * DHEAD, (long)DHEAD * DMODEL, DHEAD, DMODEL, DHEAD);
    transpose_split<<<dim3(16, 1, 16), 256, 0, stream>>>(
        Wv + wofs, wqkvh + 2048 * 1024, wqkvl + 2048 * 1024,
        (long)DMODEL * DHEAD, (long)DHEAD * DMODEL, DHEAD, DMODEL, DHEAD);
    concat3_kernel<<<4, 256, 0, stream>>>(
        bq + (long)l * 1024, bk + (long)l * 1024, bv + (long)l * 1024, bqkv, 1024);
    transpose_split<<<dim3(16, 64, 1), 256, 0, stream>>>(
        W1 + (long)l * DMODEL * DFF, w1h, w1l, 0, 0, DFF, DMODEL, DFF);
    transpose_split<<<dim3(64, 16, 1), 256, 0, stream>>>(
        W2 + (long)l * DFF * DMODEL, w2h, w2l, 0, 0, DMODEL, DFF, DMODEL);

    gemm3<2, false, false, 3><<<dim3(32, 24), 256, 0, stream>>>(
        xh, xl, wqkvh, wqkvl, bqkv, nullptr, qh, ql, kh, kl, vb16,
        1024, 0, 0, nullptr, 0);
    transpose_v<<<dim3(64, 16), 256, 0, stream>>>(vb16, vt);

    attn_mfma<<<dim3(32, 16), 256, 0, stream>>>(qh, ql, kh, kl, vt, yb);

    resid_ln_kernel<<<S_LEN, 256, 0, stream>>>(x, yb,
        ln1g + (size_t)l * DMODEL, ln1b + (size_t)l * DMODEL, xh, xl);

    gemm3<1, true, false, 3><<<dim3(32, 32), 256, 0, stream>>>(
        xh, xl, w1h, w1l, b1 + (long)l * DFF, nullptr, h1h, h1l,
        nullptr, nullptr, nullptr, 1024, 4096, 0, nullptr, 0);
    gemm3<0, false, false, 3><<<dim3(32, 8), 256, 0, stream>>>(
        h1h, h1l, w2h, w2l, b2 + (long)l * DMODEL, yb,
        nullptr, nullptr, nullptr, nullptr, nullptr, 4096, 1024, 0, nullptr, 0);

    resid_ln_kernel<<<S_LEN, 256, 0, stream>>>(x, yb,
        ln2g + (size_t)l * DMODEL, ln2b + (size_t)l * DMODEL, xh, xl);
  }

  // logits: 2048-col strips; epilogue writes exp(logit) + per-row partial sums
  const int SW = 2048;
  const int nstrips = (VOCAB + SW - 1) / SW;          // 25
  for (int is = 0; is < nstrips; ++is) {
    int n0 = is * SW;
    int ncols = VOCAB - n0; if (ncols > SW) ncols = SW;
    int nt64 = (ncols + 63) / 64;
    int nb128 = (ncols + 127) / 128;
    transpose_split<<<dim3(16, nt64, 1), 256, 0, stream>>>(
        Wout + n0, stripH, stripL, 0, 0, VOCAB, DMODEL, ncols);
    gemm3<3, false, true, 2><<<dim3(32, nb128), 256, 0, stream>>>(
        xh, xl, stripH, stripL, bout + n0, outf + n0,
        nullptr, nullptr, nullptr, nullptr, nullptr, 1024, VOCAB, ncols,
        partials, is * (SW / 128));
  }
  const int ncb = (VOCAB / 128) + 1;                  // 393 col-blocks total
  scale_softmax<<<S_LEN, 256, 0, stream>>>(outf, partials, ncb);
}

// Round 5
// 5008.052 us; speedup vs baseline: 3.1367x; 1.1346x over previous
//
#include <hip/hip_runtime.h>
#include <math.h>

#define S_LEN  4096
#define DMODEL 1024
#define NHEAD  16
#define DHEAD  64
#define DFF    4096
#define NLAYER 4
#define VOCAB  50257
#define NCBP   400   // partials row stride (col-blocks of 256, padded)

typedef unsigned short ushort_t;
typedef __attribute__((ext_vector_type(8))) __bf16 bf16x8;
typedef __attribute__((ext_vector_type(4))) float f32x4;

static __device__ __forceinline__ ushort_t f2bf(float f) {
  union { float f; unsigned u; } x; x.f = f;
  unsigned r = x.u + 0x7fffu + ((x.u >> 16) & 1u);
  return (ushort_t)(r >> 16);
}
static __device__ __forceinline__ float bf2f(ushort_t h) {
  union { unsigned u; float f; } x; x.u = ((unsigned)h) << 16;
  return x.f;
}

#define GLOAD_LDS16(gp, lp) \
  __builtin_amdgcn_global_load_lds((const __attribute__((address_space(1))) void*)(gp), \
                                   (__attribute__((address_space(3))) void*)(lp), 16, 0, 0)

// ---------------------------------------------------------------------------
// embedding + sinusoidal positional encoding, fused bf16 hi/lo split
// ---------------------------------------------------------------------------
__global__ __launch_bounds__(256) void embed_kernel(
    const int* __restrict__ tokens, const float* __restrict__ emb,
    float* __restrict__ x, ushort_t* __restrict__ xh, ushort_t* __restrict__ xl)
{
  int s = blockIdx.x;
  int tok = tokens[s];
  int d0 = threadIdx.x * 4;
  const double lf = 0.01798894603901598653; // log(10000)/512
  float4 ev = *(const float4*)(emb + (size_t)tok * DMODEL + d0);
  float o[4]; float evr[4] = {ev.x, ev.y, ev.z, ev.w};
  #pragma unroll
  for (int j = 0; j < 4; ++j) {
    int d = d0 + j;
    int i = (d < 512) ? d : d - 512;
    double ang = (double)s * exp(-lf * (double)i);
    float pe = (d < 512) ? (float)sin(ang) : (float)cos(ang);
    o[j] = evr[j] + pe;
  }
  *(float4*)(x + (size_t)s * DMODEL + d0) = make_float4(o[0], o[1], o[2], o[3]);
  ushort_t hv[4], lv[4];
  #pragma unroll
  for (int j = 0; j < 4; ++j) {
    hv[j] = f2bf(o[j]);
    lv[j] = f2bf(o[j] - bf2f(hv[j]));
  }
  *(ushort4*)(xh + (size_t)s * DMODEL + d0) = make_ushort4(hv[0], hv[1], hv[2], hv[3]);
  *(ushort4*)(xl + (size_t)s * DMODEL + d0) = make_ushort4(lv[0], lv[1], lv[2], lv[3]);
}

// ---------------------------------------------------------------------------
// transpose + split: in f32 [K][N] (row stride in_rstride) -> out bf16 hi/lo
// [N][Kout] K-contiguous. Zero-fills columns >= Nvalid. blockIdx.z batches.
// ---------------------------------------------------------------------------
__global__ __launch_bounds__(256)
void transpose_split(const float* __restrict__ in, ushort_t* __restrict__ oh,
                     ushort_t* __restrict__ ol, long in_zstr, long out_zoff,
                     int in_rstride, int Kout, int Nvalid)
{
  __shared__ float tile[64][65];
  const float* inz = in + (long)blockIdx.z * in_zstr;
  ushort_t* ohz = oh + (long)blockIdx.z * out_zoff;
  ushort_t* olz = ol + (long)blockIdx.z * out_zoff;
  int k0 = blockIdx.x * 64, n0 = blockIdx.y * 64;
  int t = threadIdx.x;
  #pragma unroll
  for (int i = 0; i < 4; ++i) {
    int idx = t + i * 256;            // 0..1023
    int kk = idx >> 4, c4 = idx & 15;
    #pragma unroll
    for (int j = 0; j < 4; ++j) {
      int n = n0 + c4 * 4 + j;
      float v = (n < Nvalid) ? inz[(long)(k0 + kk) * in_rstride + n] : 0.f;
      tile[c4 * 4 + j][kk] = v;       // transposed into LDS
    }
  }
  __syncthreads();
  #pragma unroll
  for (int i = 0; i < 4; ++i) {
    int idx = t + i * 256;
    int nn = idx >> 4, k4 = idx & 15;
    ushort_t hv[4], lv[4];
    #pragma unroll
    for (int j = 0; j < 4; ++j) {
      float v = tile[nn][k4 * 4 + j];
      hv[j] = f2bf(v);
      lv[j] = f2bf(v - bf2f(hv[j]));
    }
    long ob = (long)(n0 + nn) * Kout + k0 + k4 * 4;
    *(ushort4*)(ohz + ob) = make_ushort4(hv[0], hv[1], hv[2], hv[3]);
    *(ushort4*)(olz + ob) = make_ushort4(lv[0], lv[1], lv[2], lv[3]);
  }
}

// ---------------------------------------------------------------------------
// bf16 transpose: vb [H][S][64] -> vt [H][64][S]
// ---------------------------------------------------------------------------
__global__ __launch_bounds__(256)
void transpose_v(const ushort_t* __restrict__ vb, ushort_t* __restrict__ vt)
{
  __shared__ ushort_t tile[64][72];
  int h = blockIdx.y, s0 = blockIdx.x * 64;
  int t = threadIdx.x;
  const ushort_t* src = vb + ((size_t)h * S_LEN + s0) * 64;
  #pragma unroll
  for (int i = 0; i < 4; ++i) {
    int idx = t + i * 256;            // 0..1023 ushort4 units
    int row = idx >> 4, c4 = idx & 15;
    *(ushort4*)&tile[row][c4 * 4] = *(const ushort4*)(src + (size_t)row * 64 + c4 * 4);
  }
  __syncthreads();
  ushort_t* dst = vt + (size_t)h * DHEAD * S_LEN + s0;
  #pragma unroll
  for (int i = 0; i < 4; ++i) {
    int idx = t + i * 256;
    int e = idx >> 4, s4 = idx & 15;
    ushort4 o = make_ushort4(tile[s4*4+0][e], tile[s4*4+1][e],
                             tile[s4*4+2][e], tile[s4*4+3][e]);
    *(ushort4*)(dst + (size_t)e * S_LEN + s4 * 4) = o;
  }
}

// ---------------------------------------------------------------------------
// concat 3 bias vectors of length n into one [3n]
// ---------------------------------------------------------------------------
__global__ __launch_bounds__(256)
void concat3_kernel(const float* __restrict__ a, const float* __restrict__ b,
                    const float* __restrict__ c, float* __restrict__ o, int n)
{
  int i = blockIdx.x * 256 + threadIdx.x;
  if (i < n) { o[i] = a[i]; o[n + i] = b[i]; o[2 * n + i] = c[i]; }
}

// ---------------------------------------------------------------------------
// OLD split-bf16 MFMA GEMM (m97 structure, 128x128, 4 waves) — kept for the
// shapes whose grid would underfill the chip at 1 block/CU (QKV, FFN2).
// EPI: 0 = f32 C, 2 = QKV routing.
// ---------------------------------------------------------------------------
template<int EPI, bool RELU, bool BOUND, int NPROD>
__global__ __launch_bounds__(256)
void gemm3(const ushort_t* __restrict__ Ah, const ushort_t* __restrict__ Al,
           const ushort_t* __restrict__ Bh, const ushort_t* __restrict__ Bl,
           const float* __restrict__ bias, float* __restrict__ C,
           ushort_t* __restrict__ O0, ushort_t* __restrict__ O1,
           ushort_t* __restrict__ O2, ushort_t* __restrict__ O3,
           ushort_t* __restrict__ O4,
           int K, long ldc, int Nlimit)
{
  __shared__ ushort_t lds[4 * 4096];  // Ah | Al | Bh | Bl, each 128x32 bf16

  const int t = threadIdx.x;
  const int l = t & 63;
  const int w = t >> 6;
  const int wr = w >> 1, wc = w & 1;
  const long m0 = (long)blockIdx.x * 128;
  const long n0 = (long)blockIdx.y * 128;
  const int lrow = l & 15;
  const int lk   = (l >> 4) * 8;

  f32x4 acc[4][4];
  #pragma unroll
  for (int m = 0; m < 4; ++m)
    #pragma unroll
    for (int n = 0; n < 4; ++n) acc[m][n] = (f32x4)0.f;

  const ushort_t* ag[2]; const ushort_t* alg[2];
  const ushort_t* bg[2]; const ushort_t* blg[2];
  #pragma unroll
  for (int i = 0; i < 2; ++i) {
    int s = i * 4 + w;
    long ar = m0 + s * 16 + lrow;
    long br = n0 + s * 16 + lrow;
    ag[i]  = Ah + ar * (long)K + lk;
    alg[i] = Al + ar * (long)K + lk;
    bg[i]  = Bh + br * (long)K + lk;
    blg[i] = Bl + br * (long)K + lk;
  }

  for (int k0 = 0; k0 < K; k0 += 32) {
    __syncthreads();
    #pragma unroll
    for (int i = 0; i < 2; ++i) {
      int s = i * 4 + w;
      GLOAD_LDS16(ag[i]  + k0, &lds[        s * 512 + l * 8]);
      if (NPROD == 3) GLOAD_LDS16(alg[i] + k0, &lds[ 4096 + s * 512 + l * 8]);
      GLOAD_LDS16(bg[i]  + k0, &lds[ 8192 + s * 512 + l * 8]);
      GLOAD_LDS16(blg[i] + k0, &lds[12288 + s * 512 + l * 8]);
    }
    __syncthreads();

    bf16x8 bh_[4], bl_[4];
    #pragma unroll
    for (int n = 0; n < 4; ++n) {
      bh_[n] = *(const bf16x8*)&lds[ 8192 + (wc * 4 + n) * 512 + l * 8];
      bl_[n] = *(const bf16x8*)&lds[12288 + (wc * 4 + n) * 512 + l * 8];
    }
    #pragma unroll
    for (int m = 0; m < 4; ++m) {
      bf16x8 ah_ = *(const bf16x8*)&lds[       (wr * 4 + m) * 512 + l * 8];
      #pragma unroll
      for (int n = 0; n < 4; ++n) {
        acc[m][n] = __builtin_amdgcn_mfma_f32_16x16x32_bf16(ah_, bh_[n], acc[m][n], 0, 0, 0);
        acc[m][n] = __builtin_amdgcn_mfma_f32_16x16x32_bf16(ah_, bl_[n], acc[m][n], 0, 0, 0);
      }
      if (NPROD == 3) {
        bf16x8 al_ = *(const bf16x8*)&lds[4096 + (wr * 4 + m) * 512 + l * 8];
        #pragma unroll
        for (int n = 0; n < 4; ++n)
          acc[m][n] = __builtin_amdgcn_mfma_f32_16x16x32_bf16(al_, bh_[n], acc[m][n], 0, 0, 0);
      }
    }
  }

  #pragma unroll
  for (int n = 0; n < 4; ++n) {
    long col = n0 + wc * 64 + n * 16 + lrow;
    bool cok = (!BOUND) || (col < (long)Nlimit);
    float bv = cok ? bias[col] : 0.f;
    #pragma unroll
    for (int m = 0; m < 4; ++m) {
      #pragma unroll
      for (int r = 0; r < 4; ++r) {
        long row = m0 + wr * 64 + m * 16 + (l >> 4) * 4 + r;
        float v = acc[m][n][r] + bv;
        if (RELU) v = fmaxf(v, 0.f);
        if (cok) {
          if (EPI == 0) {
            C[row * ldc + col] = v;
          } else {
            int c = (int)col;
            if (c < 1024) {
              int hh = c >> 6, e = c & 63;
              float qv = v * 0.125f;           // fold 1/sqrt(DH) exactly
              ushort_t hi = f2bf(qv);
              size_t a = ((size_t)hh * S_LEN + row) * 64 + e;
              O0[a] = hi; O1[a] = f2bf(qv - bf2f(hi));
            } else if (c < 2048) {
              int cc = c - 1024;
              int hh = cc >> 6, e = cc & 63;
              ushort_t hi = f2bf(v);
              size_t a = ((size_t)hh * S_LEN + row) * 64 + e;
              O2[a] = hi; O3[a] = f2bf(v - bf2f(hi));
            } else {
              int cc = c - 2048;
              int hh = cc >> 6, e = cc & 63;
              size_t a = ((size_t)hh * S_LEN + row) * 64 + e;
              O4[a] = f2bf(v);
            }
          }
        }
      }
    }
  }
}

// ---------------------------------------------------------------------------
// NEW 256x256-tile 8-wave split-bf16 GEMM with counted-vmcnt phase pipeline
// (T3+T4+T5). BK=32, product-split phases: P0 Ah*Bh, P1 Ah*Bl, P2 Al*Bh.
// Per-tile issue order [Ah0,Ah1,Bh0 | Bh1,Bl0,Bl1 | Al0,Al1] -> waits
// vmcnt(4)/(5)/(6) (2-prod: (2)/(3)); loads never drain to 0 in the loop.
// EPI: 1 = bf16 hi/lo split C (RELU), 3 = exp(logit) + per-row partials.
// Grid must be >= 256 blocks (1 block/CU, 128 KiB LDS).
// ---------------------------------------------------------------------------
template<int EPI, bool RELU, bool BOUND, int NPROD>
__global__ __launch_bounds__(512, 2)
void gemm8p(const ushort_t* __restrict__ Ah, const ushort_t* __restrict__ Al,
            const ushort_t* __restrict__ Bh, const ushort_t* __restrict__ Bl,
            const float* __restrict__ bias, float* __restrict__ C,
            ushort_t* __restrict__ O0, ushort_t* __restrict__ O1,
            int K, long ldc, int Nlimit, float* __restrict__ Ppart, int cbbase)
{
  constexpr int NSTR   = (NPROD == 3) ? 4 : 3;
  constexpr int BUFSTR = NSTR * 8192;             // ushorts per buffer
  constexpr int OAL    = 8192;                    // Al offset (NPROD==3 only)
  constexpr int OBH    = (NPROD == 3) ? 16384 : 8192;
  constexpr int OBL    = OBH + 8192;
  __shared__ ushort_t lds[2 * BUFSTR];
  __shared__ float psum[(EPI == 3) ? 1024 : 4];

  const int t = threadIdx.x;
  const int l = t & 63;
  const int w = t >> 6;            // 0..7
  const int wr = w >> 2;           // 0..1  (row half)
  const int wc = w & 3;            // 0..3  (col quarter)
  const int lrow = l & 15;
  const int lk = (l >> 4) * 8;
  const int l8 = l * 8;
  const long m0 = (long)blockIdx.x * 256;
  const long n0 = (long)blockIdx.y * 256;

  const ushort_t *agp[2], *algp[2], *bgp[2], *blgp[2];
  int dst[2];
  #pragma unroll
  for (int i = 0; i < 2; ++i) {
    int s = i * 8 + w;                       // subtile 0..15
    dst[i] = s * 512 + l8;
    agp[i]  = Ah + (m0 + s * 16 + lrow) * (long)K + lk;
    bgp[i]  = Bh + (n0 + s * 16 + lrow) * (long)K + lk;
    blgp[i] = Bl + (n0 + s * 16 + lrow) * (long)K + lk;
    algp[i] = (NPROD == 3) ? (Al + (m0 + s * 16 + lrow) * (long)K + lk) : agp[i];
  }

  f32x4 acc[8][4];
  #pragma unroll
  for (int m = 0; m < 8; ++m)
    #pragma unroll
    for (int n = 0; n < 4; ++n) acc[m][n] = (f32x4)0.f;

  // prologue: stage tile 0 into buffer 0, canonical per-tile order
  GLOAD_LDS16(agp[0],  &lds[dst[0]]);
  GLOAD_LDS16(agp[1],  &lds[dst[1]]);
  GLOAD_LDS16(bgp[0],  &lds[OBH + dst[0]]);
  GLOAD_LDS16(bgp[1],  &lds[OBH + dst[1]]);
  GLOAD_LDS16(blgp[0], &lds[OBL + dst[0]]);
  GLOAD_LDS16(blgp[1], &lds[OBL + dst[1]]);
  if constexpr (NPROD == 3) {
    GLOAD_LDS16(algp[0], &lds[OAL + dst[0]]);
    GLOAD_LDS16(algp[1], &lds[OAL + dst[1]]);
  }

  const int nk = K >> 5;
  int cur = 0;
  for (int kt = 0; kt < nk; ++kt) {
    const int knx = (kt + 1 < nk) ? (kt + 1) * 32 : 0;  // last iter: harmless reload
    ushort_t* cb = &lds[cur * BUFSTR];
    ushort_t* nb = &lds[(cur ^ 1) * BUFSTR];
    bf16x8 af[8], bhf[4], blf[4];

    // ---------- P0: needs Ah,Bh of tile kt ----------
    if constexpr (NPROD == 3) asm volatile("s_waitcnt vmcnt(4)" ::: "memory");
    else                      asm volatile("s_waitcnt vmcnt(2)" ::: "memory");
    __builtin_amdgcn_sched_barrier(0);
    __builtin_amdgcn_s_barrier();
    __builtin_amdgcn_sched_barrier(0);
    #pragma unroll
    for (int m = 0; m < 8; ++m)
      af[m] = *(const bf16x8*)&cb[(wr * 8 + m) * 512 + l8];
    #pragma unroll
    for (int n = 0; n < 4; ++n)
      bhf[n] = *(const bf16x8*)&cb[OBH + (wc * 4 + n) * 512 + l8];
    GLOAD_LDS16(agp[0] + knx, &nb[dst[0]]);
    GLOAD_LDS16(agp[1] + knx, &nb[dst[1]]);
    GLOAD_LDS16(bgp[0] + knx, &nb[OBH + dst[0]]);
    __builtin_amdgcn_s_setprio(1);
    #pragma unroll
    for (int m = 0; m < 8; ++m)
      #pragma unroll
      for (int n = 0; n < 4; ++n)
        acc[m][n] = __builtin_amdgcn_mfma_f32_16x16x32_bf16(af[m], bhf[n], acc[m][n], 0, 0, 0);
    __builtin_amdgcn_s_setprio(0);
    __builtin_amdgcn_sched_barrier(0);

    // ---------- P1: needs Bl of tile kt ----------
    if constexpr (NPROD == 3) asm volatile("s_waitcnt vmcnt(5)" ::: "memory");
    else                      asm volatile("s_waitcnt vmcnt(3)" ::: "memory");
    __builtin_amdgcn_sched_barrier(0);
    __builtin_amdgcn_s_barrier();
    __builtin_amdgcn_sched_barrier(0);
    #pragma unroll
    for (int n = 0; n < 4; ++n)
      blf[n] = *(const bf16x8*)&cb[OBL + (wc * 4 + n) * 512 + l8];
    GLOAD_LDS16(bgp[1] + knx,  &nb[OBH + dst[1]]);
    GLOAD_LDS16(blgp[0] + knx, &nb[OBL + dst[0]]);
    GLOAD_LDS16(blgp[1] + knx, &nb[OBL + dst[1]]);
    __builtin_amdgcn_s_setprio(1);
    #pragma unroll
    for (int m = 0; m < 8; ++m)
      #pragma unroll
      for (int n = 0; n < 4; ++n)
        acc[m][n] = __builtin_amdgcn_mfma_f32_16x16x32_bf16(af[m], blf[n], acc[m][n], 0, 0, 0);
    __builtin_amdgcn_s_setprio(0);
    __builtin_amdgcn_sched_barrier(0);

    // ---------- P2 (NPROD==3): needs Al of tile kt ----------
    if constexpr (NPROD == 3) {
      asm volatile("s_waitcnt vmcnt(6)" ::: "memory");
      __builtin_amdgcn_sched_barrier(0);
      __builtin_amdgcn_s_barrier();
      __builtin_amdgcn_sched_barrier(0);
      #pragma unroll
      for (int m = 0; m < 8; ++m)
        af[m] = *(const bf16x8*)&cb[OAL + (wr * 8 + m) * 512 + l8];
      GLOAD_LDS16(algp[0] + knx, &nb[OAL + dst[0]]);
      GLOAD_LDS16(algp[1] + knx, &nb[OAL + dst[1]]);
      __builtin_amdgcn_s_setprio(1);
      #pragma unroll
      for (int m = 0; m < 8; ++m)
        #pragma unroll
        for (int n = 0; n < 4; ++n)
          acc[m][n] = __builtin_amdgcn_mfma_f32_16x16x32_bf16(af[m], bhf[n], acc[m][n], 0, 0, 0);
      __builtin_amdgcn_s_setprio(0);
      __builtin_amdgcn_sched_barrier(0);
    }
    cur ^= 1;
  }
  asm volatile("s_waitcnt vmcnt(0)" ::: "memory");

  // ---------------- epilogue ----------------
  if constexpr (EPI == 3) {
    float smr[8][4];
    #pragma unroll
    for (int m = 0; m < 8; ++m)
      #pragma unroll
      for (int r = 0; r < 4; ++r) smr[m][r] = 0.f;
    #pragma unroll
    for (int n = 0; n < 4; ++n) {
      long col = n0 + wc * 64 + n * 16 + lrow;
      bool cok = (!BOUND) || (col < (long)Nlimit);
      float bv = cok ? bias[col] : 0.f;
      #pragma unroll
      for (int m = 0; m < 8; ++m) {
        #pragma unroll
        for (int r = 0; r < 4; ++r) {
          long row = m0 + wr * 128 + m * 16 + (l >> 4) * 4 + r;
          float e = cok ? __expf(acc[m][n][r] + bv) : 0.f;
          if (cok) C[row * ldc + col] = e;
          smr[m][r] += e;
        }
      }
    }
    #pragma unroll
    for (int m = 0; m < 8; ++m) {
      #pragma unroll
      for (int r = 0; r < 4; ++r) {
        float s = smr[m][r];
        s += __shfl_xor(s, 1);
        s += __shfl_xor(s, 2);
        s += __shfl_xor(s, 4);
        s += __shfl_xor(s, 8);
        if (lrow == 0)
          psum[wc * 256 + wr * 128 + m * 16 + (l >> 4) * 4 + r] = s;
      }
    }
    __syncthreads();
    if (t < 256) {
      float s = psum[t] + psum[256 + t] + psum[512 + t] + psum[768 + t];
      Ppart[(m0 + t) * NCBP + cbbase + blockIdx.y] = s;
    }
  } else {
    #pragma unroll
    for (int n = 0; n < 4; ++n) {
      long col = n0 + wc * 64 + n * 16 + lrow;
      float bv = bias[col];
      #pragma unroll
      for (int m = 0; m < 8; ++m) {
        #pragma unroll
        for (int r = 0; r < 4; ++r) {
          long row = m0 + wr * 128 + m * 16 + (l >> 4) * 4 + r;
          float v = acc[m][n][r] + bv;
          if (RELU) v = fmaxf(v, 0.f);
          ushort_t h = f2bf(v);
          O0[row * ldc + col] = h;
          O1[row * ldc + col] = f2bf(v - bf2f(h));
        }
      }
    }
  }
}

// ---------------------------------------------------------------------------
// MFMA flash attention. qh/ql/kh/kl: [H][S][64] bf16 (q pre-scaled by 0.125),
// vt: [H][64][S] bf16. y out: [S][1024] f32.
// ---------------------------------------------------------------------------
__global__ __launch_bounds__(256)
void attn_mfma(const ushort_t* __restrict__ qh, const ushort_t* __restrict__ ql,
               const ushort_t* __restrict__ kh, const ushort_t* __restrict__ kl,
               const ushort_t* __restrict__ vt, float* __restrict__ y)
{
  __shared__ ushort_t lds[20480];  // Kh[4096] Kl[4096] Vt[4096] P[4x2048]

  const int t = threadIdx.x, l = t & 63, w = t >> 6;
  const int lrow = l & 15, lhi = l >> 4;
  const int h = blockIdx.y;
  const int bw = blockIdx.x * 128 + w * 32;
  const size_t hS = (size_t)h * S_LEN * DHEAD;
  const size_t hV = (size_t)h * DHEAD * S_LEN;
  const int pb = 12288 + w * 2048;

  bf16x8 qhf[2][2], qlf[2][2];
  #pragma unroll
  for (int m = 0; m < 2; ++m)
    #pragma unroll
    for (int ks = 0; ks < 2; ++ks) {
      size_t a = hS + (size_t)(bw + m * 16 + lrow) * 64 + ks * 32 + lhi * 8;
      qhf[m][ks] = *(const bf16x8*)(qh + a);
      qlf[m][ks] = *(const bf16x8*)(ql + a);
    }

  f32x4 acc[2][4];
  #pragma unroll
  for (int m = 0; m < 2; ++m)
    #pragma unroll
    for (int n = 0; n < 4; ++n) acc[m][n] = (f32x4)0.f;
  float mrow[8], lsum[8];
  #pragma unroll
  for (int i = 0; i < 8; ++i) { mrow[i] = -1e30f; lsum[i] = 0.f; }

  for (int kt = 0; kt < S_LEN; kt += 64) {
    __syncthreads();
    #pragma unroll
    for (int i = 0; i < 2; ++i) {
      int s = i * 4 + w;
      size_t krow = (size_t)(kt + (s >> 1) * 16 + lrow);
      int koff = (s & 1) * 32 + lhi * 8;
      GLOAD_LDS16(kh + hS + krow * 64 + koff, &lds[       s * 512 + l * 8]);
      GLOAD_LDS16(kl + hS + krow * 64 + koff, &lds[4096 + s * 512 + l * 8]);
      size_t erow = (size_t)((s >> 1) * 16 + lrow);
      int toff = kt + (s & 1) * 32 + lhi * 8;
      GLOAD_LDS16(vt + hV + erow * S_LEN + toff, &lds[8192 + s * 512 + l * 8]);
    }
    __syncthreads();

    f32x4 sacc[2][4];
    #pragma unroll
    for (int m = 0; m < 2; ++m)
      #pragma unroll
      for (int n = 0; n < 4; ++n) sacc[m][n] = (f32x4)0.f;
    #pragma unroll
    for (int ks = 0; ks < 2; ++ks) {
      bf16x8 bh_[4], bl_[4];
      #pragma unroll
      for (int n = 0; n < 4; ++n) {
        bh_[n] = *(const bf16x8*)&lds[       (n * 2 + ks) * 512 + l * 8];
        bl_[n] = *(const bf16x8*)&lds[4096 + (n * 2 + ks) * 512 + l * 8];
      }
      #pragma unroll
      for (int m = 0; m < 2; ++m)
        #pragma unroll
        for (int n = 0; n < 4; ++n) {
          sacc[m][n] = __builtin_amdgcn_mfma_f32_16x16x32_bf16(qhf[m][ks], bh_[n], sacc[m][n], 0, 0, 0);
          sacc[m][n] = __builtin_amdgcn_mfma_f32_16x16x32_bf16(qhf[m][ks], bl_[n], sacc[m][n], 0, 0, 0);
          sacc[m][n] = __builtin_amdgcn_mfma_f32_16x16x32_bf16(qlf[m][ks], bh_[n], sacc[m][n], 0, 0, 0);
        }
    }

    #pragma unroll
    for (int m = 0; m < 2; ++m) {
      #pragma unroll
      for (int r = 0; r < 4; ++r) {
        const int idx = m * 4 + r;
        float tm = fmaxf(fmaxf(sacc[m][0][r], sacc[m][1][r]),
                         fmaxf(sacc[m][2][r], sacc[m][3][r]));
        tm = fmaxf(tm, __shfl_xor(tm, 1));
        tm = fmaxf(tm, __shfl_xor(tm, 2));
        tm = fmaxf(tm, __shfl_xor(tm, 4));
        tm = fmaxf(tm, __shfl_xor(tm, 8));
        float mn = fmaxf(mrow[idx], tm);
        float al = __expf(mrow[idx] - mn);
        mrow[idx] = mn;
        float rs = 0.f;
        #pragma unroll
        for (int n = 0; n < 4; ++n) {
          float p = __expf(sacc[m][n][r] - mn);
          rs += p;
          int pa = pb + ((m * 2 + (n >> 1)) << 9) + (((n & 1) * 2 + (lrow >> 3)) << 7)
                   + ((lhi * 4 + r) << 3) + (l & 7);
          pa ^= (lrow >> 3) << 3;
          lds[pa] = f2bf(p);
        }
        rs += __shfl_xor(rs, 1);
        rs += __shfl_xor(rs, 2);
        rs += __shfl_xor(rs, 4);
        rs += __shfl_xor(rs, 8);
        lsum[idx] = lsum[idx] * al + rs;
        #pragma unroll
        for (int n = 0; n < 4; ++n) acc[m][n][r] *= al;
      }
    }

    #pragma unroll
    for (int ks = 0; ks < 2; ++ks) {
      bf16x8 pa_[2];
      #pragma unroll
      for (int m = 0; m < 2; ++m) {
        int ra = pb + ((m * 2 + ks) << 9) + (l << 3);
        ra ^= ((l >> 4) & 1) << 3;
        pa_[m] = *(const bf16x8*)&lds[ra];
      }
      #pragma unroll
      for (int n = 0; n < 4; ++n) {
        bf16x8 vf = *(const bf16x8*)&lds[8192 + (n * 2 + ks) * 512 + l * 8];
        #pragma unroll
        for (int m = 0; m < 2; ++m)
          acc[m][n] = __builtin_amdgcn_mfma_f32_16x16x32_bf16(pa_[m], vf, acc[m][n], 0, 0, 0);
      }
    }
  }

  #pragma unroll
  for (int m = 0; m < 2; ++m) {
    #pragma unroll
    for (int r = 0; r < 4; ++r) {
      float inv = 1.0f / lsum[m * 4 + r];
      int row = bw + m * 16 + lhi * 4 + r;
      #pragma unroll
      for (int n = 0; n < 4; ++n)
        y[(size_t)row * DMODEL + h * 64 + n * 16 + lrow] = acc[m][n][r] * inv;
    }
  }
}

// ---------------------------------------------------------------------------
__device__ __forceinline__ float block_sum256(float v, float* sm)
{
  #pragma unroll
  for (int off = 32; off >= 1; off >>= 1) v += __shfl_xor(v, off);
  int w = threadIdx.x >> 6;
  if ((threadIdx.x & 63) == 0) sm[w] = v;
  __syncthreads();
  v = sm[0] + sm[1] + sm[2] + sm[3];
  __syncthreads();
  return v;
}

// x = layernorm(x + y) * g + b, fused bf16 hi/lo split of the result
__global__ __launch_bounds__(256)
void resid_ln_kernel(float* __restrict__ x, const float* __restrict__ y,
                     const float* __restrict__ g, const float* __restrict__ b,
                     ushort_t* __restrict__ xh, ushort_t* __restrict__ xl)
{
  __shared__ float sm[4];
  int row = blockIdx.x, t = threadIdx.x;
  float4 xv = *(const float4*)(x + (size_t)row * DMODEL + t * 4);
  float4 yv = *(const float4*)(y + (size_t)row * DMODEL + t * 4);
  float a0 = xv.x + yv.x, a1 = xv.y + yv.y, a2 = xv.z + yv.z, a3 = xv.w + yv.w;
  float s = block_sum256(a0 + a1 + a2 + a3, sm);
  float mean = s * (1.0f / DMODEL);
  float d0 = a0 - mean, d1 = a1 - mean, d2 = a2 - mean, d3 = a3 - mean;
  float vs = block_sum256(d0*d0 + d1*d1 + d2*d2 + d3*d3, sm);
  float inv = rsqrtf(vs * (1.0f / DMODEL) + 1e-5f);
  float4 gv = *(const float4*)(g + t * 4);
  float4 bv = *(const float4*)(b + t * 4);
  float o[4];
  o[0] = d0 * inv * gv.x + bv.x;
  o[1] = d1 * inv * gv.y + bv.y;
  o[2] = d2 * inv * gv.z + bv.z;
  o[3] = d3 * inv * gv.w + bv.w;
  *(float4*)(x + (size_t)row * DMODEL + t * 4) = make_float4(o[0], o[1], o[2], o[3]);
  ushort_t hv[4], lv[4];
  #pragma unroll
  for (int j = 0; j < 4; ++j) {
    hv[j] = f2bf(o[j]);
    lv[j] = f2bf(o[j] - bf2f(hv[j]));
  }
  *(ushort4*)(xh + (size_t)row * DMODEL + t * 4) = make_ushort4(hv[0], hv[1], hv[2], hv[3]);
  *(ushort4*)(xl + (size_t)row * DMODEL + t * 4) = make_ushort4(lv[0], lv[1], lv[2], lv[3]);
}

// ---------------------------------------------------------------------------
// final scale: out[row] *= 1/sum(row); sum from deterministic partials
// ---------------------------------------------------------------------------
__global__ __launch_bounds__(256)
void scale_softmax(float* __restrict__ out, const float* __restrict__ partials,
                   int ncb)
{
  __shared__ float sm[4];
  int row = blockIdx.x, t = threadIdx.x;
  float s = 0.f;
  for (int cb = t; cb < ncb; cb += 256) s += partials[(size_t)row * NCBP + cb];
  s = block_sum256(s, sm);
  float inv = 1.0f / s;
  float* p = out + (size_t)row * VOCAB;
  int head = (int)((((uintptr_t)16 - ((uintptr_t)p & 15)) & 15) >> 2);
  if (t < head) p[t] *= inv;
  int nvec = (VOCAB - head) >> 2;
  float4* pv = (float4*)(p + head);
  for (int i = t; i < nvec; i += 256) {
    float4 v = pv[i];
    v.x *= inv; v.y *= inv; v.z *= inv; v.w *= inv;
    pv[i] = v;
  }
  int done = head + nvec * 4;
  if (t < VOCAB - done) p[done + t] *= inv;
}

// ---------------------------------------------------------------------------
extern "C" void kernel_launch(void* const* d_in, const int* in_sizes, int n_in,
                              void* d_out, int out_size, void* d_ws, size_t ws_size,
                              hipStream_t stream)
{
  const int*   tokens = (const int*)  d_in[0];
  const float* emb    = (const float*)d_in[1];
  const float* Wq     = (const float*)d_in[2];
  const float* bq     = (const float*)d_in[3];
  const float* Wk     = (const float*)d_in[4];
  const float* bk     = (const float*)d_in[5];
  const float* Wv     = (const float*)d_in[6];
  const float* bv     = (const float*)d_in[7];
  const float* ln1g   = (const float*)d_in[8];
  const float* ln1b   = (const float*)d_in[9];
  const float* W1     = (const float*)d_in[10];
  const float* b1     = (const float*)d_in[11];
  const float* W2     = (const float*)d_in[12];
  const float* b2     = (const float*)d_in[13];
  const float* ln2g   = (const float*)d_in[14];
  const float* ln2b   = (const float*)d_in[15];
  const float* Wout   = (const float*)d_in[16];
  const float* bout   = (const float*)d_in[17];

  // workspace (<=30.6 MB): xh 0-8, xl 8-16 (layers); logits phase reuses the
  // dead xl region: stripH 8-16, stripL 16-24, partials 24-30.55
  char* wsb = (char*)d_ws;
  ushort_t* xh     = (ushort_t*)(wsb);
  ushort_t* xl     = (ushort_t*)(wsb + ((size_t)8  << 20));
  ushort_t* stripH = (ushort_t*)(wsb + ((size_t)8  << 20));
  ushort_t* stripL = (ushort_t*)(wsb + ((size_t)16 << 20));
  float*    partials = (float*)(wsb + ((size_t)24 << 20)); // [4096][NCBP] f32

  // scratch in d_out (823 MB; all dead before the logits GEMM writes it)
  char* ob = (char*)d_out;
  float*    x    = (float*)(ob);                          // [S][D] f32 16MB
  float*    yb   = (float*)(ob + ((size_t)16  << 20));    // [S][D] f32 16MB
  ushort_t* qh   = (ushort_t*)(ob + ((size_t)32  << 20)); // [H][S][64] 8MB
  ushort_t* ql   = (ushort_t*)(ob + ((size_t)40  << 20));
  ushort_t* kh   = (ushort_t*)(ob + ((size_t)48  << 20));
  ushort_t* kl   = (ushort_t*)(ob + ((size_t)56  << 20));
  ushort_t* vb16 = (ushort_t*)(ob + ((size_t)64  << 20));
  ushort_t* vt   = (ushort_t*)(ob + ((size_t)72  << 20)); // [H][64][S] 8MB
  ushort_t* h1h  = (ushort_t*)(ob + ((size_t)80  << 20)); // [S][DFF] 32MB
  ushort_t* h1l  = (ushort_t*)(ob + ((size_t)112 << 20));
  ushort_t* wqkvh= (ushort_t*)(ob + ((size_t)144 << 20)); // [3072][1024] 6MB
  ushort_t* wqkvl= (ushort_t*)(ob + ((size_t)150 << 20));
  ushort_t* w1h  = (ushort_t*)(ob + ((size_t)156 << 20)); // [4096][1024] 8MB
  ushort_t* w1l  = (ushort_t*)(ob + ((size_t)164 << 20));
  ushort_t* w2h  = (ushort_t*)(ob + ((size_t)172 << 20)); // [1024][4096] 8MB
  ushort_t* w2l  = (ushort_t*)(ob + ((size_t)180 << 20));
  float*    bqkv = (float*)(ob + ((size_t)188 << 20));    // [3072] f32
  float*    outf = (float*)d_out;

  embed_kernel<<<S_LEN, 256, 0, stream>>>(tokens, emb, x, xh, xl);

  for (int l = 0; l < NLAYER; ++l) {
    const long wofs = (long)l * NHEAD * DMODEL * DHEAD;
    transpose_split<<<dim3(16, 1, 16), 256, 0, stream>>>(
        Wq + wofs, wqkvh, wqkvl, (long)DMODEL * DHEAD, (long)DHEAD * DMODEL,
        DHEAD, DMODEL, DHEAD);
    transpose_split<<<dim3(16, 1, 16), 256, 0, stream>>>(
        Wk + wofs, wqkvh + 1024 * 1024, wqkvl + 1024 * 1024,
        (long)DMODEL * DHEAD, (long)DHEAD * DMODEL, DHEAD, DMODEL, DHEAD);
    transpose_split<<<dim3(16, 1, 16), 256, 0, stream>>>(
        Wv + wofs, wqkvh + 2048 * 1024, wqkvl + 2048 * 1024,
        (long)DMODEL * DHEAD, (long)DHEAD * DMODEL, DHEAD, DMODEL, DHEAD);
    concat3_kernel<<<4, 256, 0, stream>>>(
        bq + (long)l * 1024, bk + (long)l * 1024, bv + (long)l * 1024, bqkv, 1024);
    transpose_split<<<dim3(16, 64, 1), 256, 0, stream>>>(
        W1 + (long)l * DMODEL * DFF, w1h, w1l, 0, 0, DFF, DMODEL, DFF);
    transpose_split<<<dim3(64, 16, 1), 256, 0, stream>>>(
        W2 + (long)l * DFF * DMODEL, w2h, w2l, 0, 0, DMODEL, DFF, DMODEL);

    gemm3<2, false, false, 3><<<dim3(32, 24), 256, 0, stream>>>(
        xh, xl, wqkvh, wqkvl, bqkv, nullptr, qh, ql, kh, kl, vb16,
        1024, 0, 0);
    transpose_v<<<dim3(64, 16), 256, 0, stream>>>(vb16, vt);

    attn_mfma<<<dim3(32, 16), 256, 0, stream>>>(qh, ql, kh, kl, vt, yb);

    resid_ln_kernel<<<S_LEN, 256, 0, stream>>>(x, yb,
        ln1g + (size_t)l * DMODEL, ln1b + (size_t)l * DMODEL, xh, xl);

    // FFN1: 256^2 8-phase kernel, grid 16x16 = 256 blocks
    gemm8p<1, true, false, 3><<<dim3(16, 16), 512, 0, stream>>>(
        xh, xl, w1h, w1l, b1 + (long)l * DFF, nullptr, h1h, h1l,
        1024, 4096, 0, nullptr, 0);
    gemm3<0, false, false, 3><<<dim3(32, 8), 256, 0, stream>>>(
        h1h, h1l, w2h, w2l, b2 + (long)l * DMODEL, yb,
        nullptr, nullptr, nullptr, nullptr, nullptr, 4096, 1024, 0);

    resid_ln_kernel<<<S_LEN, 256, 0, stream>>>(x, yb,
        ln2g + (size_t)l * DMODEL, ln2b + (size_t)l * DMODEL, xh, xl);
  }

  // logits: 4096-col strips, 256^2 8-phase kernel (2-prod), exp+partials epi
  const int SW = 4096;
  for (int is = 0; is < 12; ++is) {
    int n0 = is * SW;
    transpose_split<<<dim3(16, 64, 1), 256, 0, stream>>>(
        Wout + n0, stripH, stripL, 0, 0, VOCAB, DMODEL, SW);
    gemm8p<3, false, false, 2><<<dim3(16, 16), 512, 0, stream>>>(
        xh, nullptr, stripH, stripL, bout + n0, outf + n0, nullptr, nullptr,
        1024, VOCAB, SW, partials, is * 16);
  }
  {
    int n0 = 12 * SW;                       // 49152
    int ncols = VOCAB - n0;                 // 1105
    int nt64 = (ncols + 63) / 64;           // 18
    int nb256 = (ncols + 255) / 256;        // 5
    transpose_split<<<dim3(16, nt64, 1), 256, 0, stream>>>(
        Wout + n0, stripH, stripL, 0, 0, VOCAB, DMODEL, ncols);
    gemm8p<3, false, true, 2><<<dim3(16, nb256), 512, 0, stream>>>(
        xh, nullptr, stripH, stripL, bout + n0, outf + n0, nullptr, nullptr,
        1024, VOCAB, ncols, partials, 12 * 16);
  }
  const int ncb = (VOCAB + 255) / 256;      // 197
  scale_softmax<<<S_LEN, 256, 0, stream>>>(outf, partials, ncb);
}

// Round 6
// 4626.545 us; speedup vs baseline: 3.3954x; 1.0825x over previous
//
#include <hip/hip_runtime.h>
#include <math.h>

#define S_LEN  4096
#define DMODEL 1024
#define NHEAD  16
#define DHEAD  64
#define DFF    4096
#define NLAYER 4
#define VOCAB  50257
#define NCBP   400   // partials row stride (col-blocks of 256, padded)

typedef unsigned short ushort_t;
typedef __attribute__((ext_vector_type(8))) __bf16 bf16x8;
typedef __attribute__((ext_vector_type(4))) float f32x4;

static __device__ __forceinline__ ushort_t f2bf(float f) {
  union { float f; unsigned u; } x; x.f = f;
  unsigned r = x.u + 0x7fffu + ((x.u >> 16) & 1u);
  return (ushort_t)(r >> 16);
}
static __device__ __forceinline__ float bf2f(ushort_t h) {
  union { unsigned u; float f; } x; x.u = ((unsigned)h) << 16;
  return x.f;
}

#define GLOAD_LDS16(gp, lp) \
  __builtin_amdgcn_global_load_lds((const __attribute__((address_space(1))) void*)(gp), \
                                   (__attribute__((address_space(3))) void*)(lp), 16, 0, 0)

// ---------------------------------------------------------------------------
// embedding + sinusoidal positional encoding, fused bf16 hi/lo split
// ---------------------------------------------------------------------------
__global__ __launch_bounds__(256) void embed_kernel(
    const int* __restrict__ tokens, const float* __restrict__ emb,
    float* __restrict__ x, ushort_t* __restrict__ xh, ushort_t* __restrict__ xl)
{
  int s = blockIdx.x;
  int tok = tokens[s];
  int d0 = threadIdx.x * 4;
  const double lf = 0.01798894603901598653; // log(10000)/512
  float4 ev = *(const float4*)(emb + (size_t)tok * DMODEL + d0);
  float o[4]; float evr[4] = {ev.x, ev.y, ev.z, ev.w};
  #pragma unroll
  for (int j = 0; j < 4; ++j) {
    int d = d0 + j;
    int i = (d < 512) ? d : d - 512;
    double ang = (double)s * exp(-lf * (double)i);
    float pe = (d < 512) ? (float)sin(ang) : (float)cos(ang);
    o[j] = evr[j] + pe;
  }
  *(float4*)(x + (size_t)s * DMODEL + d0) = make_float4(o[0], o[1], o[2], o[3]);
  ushort_t hv[4], lv[4];
  #pragma unroll
  for (int j = 0; j < 4; ++j) {
    hv[j] = f2bf(o[j]);
    lv[j] = f2bf(o[j] - bf2f(hv[j]));
  }
  *(ushort4*)(xh + (size_t)s * DMODEL + d0) = make_ushort4(hv[0], hv[1], hv[2], hv[3]);
  *(ushort4*)(xl + (size_t)s * DMODEL + d0) = make_ushort4(lv[0], lv[1], lv[2], lv[3]);
}

// ---------------------------------------------------------------------------
// transpose + split: in f32 [K][N] (row stride in_rstride) -> out bf16 hi/lo
// [N][Kout] K-contiguous. Zero-fills columns >= Nvalid. blockIdx.z batches.
// ---------------------------------------------------------------------------
__global__ __launch_bounds__(256)
void transpose_split(const float* __restrict__ in, ushort_t* __restrict__ oh,
                     ushort_t* __restrict__ ol, long in_zstr, long out_zoff,
                     int in_rstride, int Kout, int Nvalid)
{
  __shared__ float tile[64][65];
  const float* inz = in + (long)blockIdx.z * in_zstr;
  ushort_t* ohz = oh + (long)blockIdx.z * out_zoff;
  ushort_t* olz = ol + (long)blockIdx.z * out_zoff;
  int k0 = blockIdx.x * 64, n0 = blockIdx.y * 64;
  int t = threadIdx.x;
  #pragma unroll
  for (int i = 0; i < 4; ++i) {
    int idx = t + i * 256;            // 0..1023
    int kk = idx >> 4, c4 = idx & 15;
    #pragma unroll
    for (int j = 0; j < 4; ++j) {
      int n = n0 + c4 * 4 + j;
      float v = (n < Nvalid) ? inz[(long)(k0 + kk) * in_rstride + n] : 0.f;
      tile[c4 * 4 + j][kk] = v;       // transposed into LDS
    }
  }
  __syncthreads();
  #pragma unroll
  for (int i = 0; i < 4; ++i) {
    int idx = t + i * 256;
    int nn = idx >> 4, k4 = idx & 15;
    ushort_t hv[4], lv[4];
    #pragma unroll
    for (int j = 0; j < 4; ++j) {
      float v = tile[nn][k4 * 4 + j];
      hv[j] = f2bf(v);
      lv[j] = f2bf(v - bf2f(hv[j]));
    }
    long ob = (long)(n0 + nn) * Kout + k0 + k4 * 4;
    *(ushort4*)(ohz + ob) = make_ushort4(hv[0], hv[1], hv[2], hv[3]);
    *(ushort4*)(olz + ob) = make_ushort4(lv[0], lv[1], lv[2], lv[3]);
  }
}

// ---------------------------------------------------------------------------
// bf16 transpose: vb [H][S][64] -> vt [H][64][S]
// ---------------------------------------------------------------------------
__global__ __launch_bounds__(256)
void transpose_v(const ushort_t* __restrict__ vb, ushort_t* __restrict__ vt)
{
  __shared__ ushort_t tile[64][72];
  int h = blockIdx.y, s0 = blockIdx.x * 64;
  int t = threadIdx.x;
  const ushort_t* src = vb + ((size_t)h * S_LEN + s0) * 64;
  #pragma unroll
  for (int i = 0; i < 4; ++i) {
    int idx = t + i * 256;            // 0..1023 ushort4 units
    int row = idx >> 4, c4 = idx & 15;
    *(ushort4*)&tile[row][c4 * 4] = *(const ushort4*)(src + (size_t)row * 64 + c4 * 4);
  }
  __syncthreads();
  ushort_t* dst = vt + (size_t)h * DHEAD * S_LEN + s0;
  #pragma unroll
  for (int i = 0; i < 4; ++i) {
    int idx = t + i * 256;
    int e = idx >> 4, s4 = idx & 15;
    ushort4 o = make_ushort4(tile[s4*4+0][e], tile[s4*4+1][e],
                             tile[s4*4+2][e], tile[s4*4+3][e]);
    *(ushort4*)(dst + (size_t)e * S_LEN + s4 * 4) = o;
  }
}

// ---------------------------------------------------------------------------
// concat 3 bias vectors of length n into one [3n]
// ---------------------------------------------------------------------------
__global__ __launch_bounds__(256)
void concat3_kernel(const float* __restrict__ a, const float* __restrict__ b,
                    const float* __restrict__ c, float* __restrict__ o, int n)
{
  int i = blockIdx.x * 256 + threadIdx.x;
  if (i < n) { o[i] = a[i]; o[n + i] = b[i]; o[2 * n + i] = c[i]; }
}

// ---------------------------------------------------------------------------
// 256x256-tile 8-wave split-bf16 GEMM with counted-vmcnt phase pipeline
// (T3+T4+T5). BK=32, product-split phases: P0 Ah*Bh, P1 Ah*Bl, P2 Al*Bh.
// Per-tile issue order [Ah0,Ah1,Bh0 | Bh1,Bl0,Bl1 | Al0,Al1] -> waits
// vmcnt(4)/(5)/(6) (2-prod: (2)/(3)); loads never drain to 0 in the loop.
// ldk = row stride (full K); K = iterated length; blockIdx.z = K-chunk
// (A/B offset z*K along K, C offset z*czStride) for split-K.
// EPI: 0 = raw f32 partial (no bias), 1 = bf16 hi/lo split C (+bias,RELU),
//      2 = QKV routing, 3 = exp(logit)+bias + per-row col-block partials.
// ---------------------------------------------------------------------------
template<int EPI, bool RELU, bool BOUND, int NPROD>
__global__ __launch_bounds__(512, 2)
void gemm8p(const ushort_t* __restrict__ Ah, const ushort_t* __restrict__ Al,
            const ushort_t* __restrict__ Bh, const ushort_t* __restrict__ Bl,
            const float* __restrict__ bias, float* __restrict__ C,
            ushort_t* __restrict__ O0, ushort_t* __restrict__ O1,
            ushort_t* __restrict__ O2, ushort_t* __restrict__ O3,
            ushort_t* __restrict__ O4,
            int K, int ldk, long ldc, long czStride, int Nlimit,
            float* __restrict__ Ppart, int cbbase)
{
  constexpr int NSTR   = (NPROD == 3) ? 4 : 3;
  constexpr int BUFSTR = NSTR * 8192;             // ushorts per buffer
  constexpr int OAL    = 8192;                    // Al offset (NPROD==3 only)
  constexpr int OBH    = (NPROD == 3) ? 16384 : 8192;
  constexpr int OBL    = OBH + 8192;
  __shared__ ushort_t lds[2 * BUFSTR];
  __shared__ float psum[(EPI == 3) ? 1024 : 4];

  const int t = threadIdx.x;
  const int l = t & 63;
  const int w = t >> 6;            // 0..7
  const int wr = w >> 2;           // 0..1  (row half)
  const int wc = w & 3;            // 0..3  (col quarter)
  const int lrow = l & 15;
  const int lk = (l >> 4) * 8;
  const int l8 = l * 8;
  const long m0 = (long)blockIdx.x * 256;
  const long n0 = (long)blockIdx.y * 256;
  const long kz = (long)blockIdx.z * K;

  const ushort_t *agp[2], *algp[2], *bgp[2], *blgp[2];
  int dst[2];
  #pragma unroll
  for (int i = 0; i < 2; ++i) {
    int s = i * 8 + w;                       // subtile 0..15
    dst[i] = s * 512 + l8;
    agp[i]  = Ah + (m0 + s * 16 + lrow) * (long)ldk + kz + lk;
    bgp[i]  = Bh + (n0 + s * 16 + lrow) * (long)ldk + kz + lk;
    blgp[i] = Bl + (n0 + s * 16 + lrow) * (long)ldk + kz + lk;
    algp[i] = (NPROD == 3) ? (Al + (m0 + s * 16 + lrow) * (long)ldk + kz + lk) : agp[i];
  }

  f32x4 acc[8][4];
  #pragma unroll
  for (int m = 0; m < 8; ++m)
    #pragma unroll
    for (int n = 0; n < 4; ++n) acc[m][n] = (f32x4)0.f;

  // prologue: stage tile 0 into buffer 0, canonical per-tile order
  GLOAD_LDS16(agp[0],  &lds[dst[0]]);
  GLOAD_LDS16(agp[1],  &lds[dst[1]]);
  GLOAD_LDS16(bgp[0],  &lds[OBH + dst[0]]);
  GLOAD_LDS16(bgp[1],  &lds[OBH + dst[1]]);
  GLOAD_LDS16(blgp[0], &lds[OBL + dst[0]]);
  GLOAD_LDS16(blgp[1], &lds[OBL + dst[1]]);
  if constexpr (NPROD == 3) {
    GLOAD_LDS16(algp[0], &lds[OAL + dst[0]]);
    GLOAD_LDS16(algp[1], &lds[OAL + dst[1]]);
  }

  const int nk = K >> 5;
  int cur = 0;
  for (int kt = 0; kt < nk; ++kt) {
    const int knx = (kt + 1 < nk) ? (kt + 1) * 32 : 0;  // last iter: harmless reload
    ushort_t* cb = &lds[cur * BUFSTR];
    ushort_t* nb = &lds[(cur ^ 1) * BUFSTR];
    bf16x8 af[8], bhf[4], blf[4];

    // ---------- P0: needs Ah,Bh of tile kt ----------
    if constexpr (NPROD == 3) asm volatile("s_waitcnt vmcnt(4)" ::: "memory");
    else                      asm volatile("s_waitcnt vmcnt(2)" ::: "memory");
    __builtin_amdgcn_sched_barrier(0);
    __builtin_amdgcn_s_barrier();
    __builtin_amdgcn_sched_barrier(0);
    #pragma unroll
    for (int m = 0; m < 8; ++m)
      af[m] = *(const bf16x8*)&cb[(wr * 8 + m) * 512 + l8];
    #pragma unroll
    for (int n = 0; n < 4; ++n)
      bhf[n] = *(const bf16x8*)&cb[OBH + (wc * 4 + n) * 512 + l8];
    GLOAD_LDS16(agp[0] + knx, &nb[dst[0]]);
    GLOAD_LDS16(agp[1] + knx, &nb[dst[1]]);
    GLOAD_LDS16(bgp[0] + knx, &nb[OBH + dst[0]]);
    __builtin_amdgcn_s_setprio(1);
    #pragma unroll
    for (int m = 0; m < 8; ++m)
      #pragma unroll
      for (int n = 0; n < 4; ++n)
        acc[m][n] = __builtin_amdgcn_mfma_f32_16x16x32_bf16(af[m], bhf[n], acc[m][n], 0, 0, 0);
    __builtin_amdgcn_s_setprio(0);
    __builtin_amdgcn_sched_barrier(0);

    // ---------- P1: needs Bl of tile kt ----------
    if constexpr (NPROD == 3) asm volatile("s_waitcnt vmcnt(5)" ::: "memory");
    else                      asm volatile("s_waitcnt vmcnt(3)" ::: "memory");
    __builtin_amdgcn_sched_barrier(0);
    __builtin_amdgcn_s_barrier();
    __builtin_amdgcn_sched_barrier(0);
    #pragma unroll
    for (int n = 0; n < 4; ++n)
      blf[n] = *(const bf16x8*)&cb[OBL + (wc * 4 + n) * 512 + l8];
    GLOAD_LDS16(bgp[1] + knx,  &nb[OBH + dst[1]]);
    GLOAD_LDS16(blgp[0] + knx, &nb[OBL + dst[0]]);
    GLOAD_LDS16(blgp[1] + knx, &nb[OBL + dst[1]]);
    __builtin_amdgcn_s_setprio(1);
    #pragma unroll
    for (int m = 0; m < 8; ++m)
      #pragma unroll
      for (int n = 0; n < 4; ++n)
        acc[m][n] = __builtin_amdgcn_mfma_f32_16x16x32_bf16(af[m], blf[n], acc[m][n], 0, 0, 0);
    __builtin_amdgcn_s_setprio(0);
    __builtin_amdgcn_sched_barrier(0);

    // ---------- P2 (NPROD==3): needs Al of tile kt ----------
    if constexpr (NPROD == 3) {
      asm volatile("s_waitcnt vmcnt(6)" ::: "memory");
      __builtin_amdgcn_sched_barrier(0);
      __builtin_amdgcn_s_barrier();
      __builtin_amdgcn_sched_barrier(0);
      #pragma unroll
      for (int m = 0; m < 8; ++m)
        af[m] = *(const bf16x8*)&cb[OAL + (wr * 8 + m) * 512 + l8];
      GLOAD_LDS16(algp[0] + knx, &nb[OAL + dst[0]]);
      GLOAD_LDS16(algp[1] + knx, &nb[OAL + dst[1]]);
      __builtin_amdgcn_s_setprio(1);
      #pragma unroll
      for (int m = 0; m < 8; ++m)
        #pragma unroll
        for (int n = 0; n < 4; ++n)
          acc[m][n] = __builtin_amdgcn_mfma_f32_16x16x32_bf16(af[m], bhf[n], acc[m][n], 0, 0, 0);
      __builtin_amdgcn_s_setprio(0);
      __builtin_amdgcn_sched_barrier(0);
    }
    cur ^= 1;
  }
  asm volatile("s_waitcnt vmcnt(0)" ::: "memory");

  // ---------------- epilogue ----------------
  if constexpr (EPI == 3) {
    float* Cz = C;
    float smr[8][4];
    #pragma unroll
    for (int m = 0; m < 8; ++m)
      #pragma unroll
      for (int r = 0; r < 4; ++r) smr[m][r] = 0.f;
    #pragma unroll
    for (int n = 0; n < 4; ++n) {
      long col = n0 + wc * 64 + n * 16 + lrow;
      bool cok = (!BOUND) || (col < (long)Nlimit);
      float bv = cok ? bias[col] : 0.f;
      #pragma unroll
      for (int m = 0; m < 8; ++m) {
        #pragma unroll
        for (int r = 0; r < 4; ++r) {
          long row = m0 + wr * 128 + m * 16 + (l >> 4) * 4 + r;
          float e = cok ? __expf(acc[m][n][r] + bv) : 0.f;
          if (cok) Cz[row * ldc + col] = e;
          smr[m][r] += e;
        }
      }
    }
    #pragma unroll
    for (int m = 0; m < 8; ++m) {
      #pragma unroll
      for (int r = 0; r < 4; ++r) {
        float s = smr[m][r];
        s += __shfl_xor(s, 1);
        s += __shfl_xor(s, 2);
        s += __shfl_xor(s, 4);
        s += __shfl_xor(s, 8);
        if (lrow == 0)
          psum[wc * 256 + wr * 128 + m * 16 + (l >> 4) * 4 + r] = s;
      }
    }
    __syncthreads();
    if (t < 256) {
      float s = psum[t] + psum[256 + t] + psum[512 + t] + psum[768 + t];
      Ppart[(m0 + t) * NCBP + cbbase + blockIdx.y] = s;
    }
  } else if constexpr (EPI == 2) {
    #pragma unroll
    for (int n = 0; n < 4; ++n) {
      long col = n0 + wc * 64 + n * 16 + lrow;
      float bv = bias[col];
      #pragma unroll
      for (int m = 0; m < 8; ++m) {
        #pragma unroll
        for (int r = 0; r < 4; ++r) {
          long row = m0 + wr * 128 + m * 16 + (l >> 4) * 4 + r;
          float v = acc[m][n][r] + bv;
          int c = (int)col;
          if (c < 1024) {
            int hh = c >> 6, e = c & 63;
            float qv = v * 0.125f;           // fold 1/sqrt(DH) exactly
            ushort_t hi = f2bf(qv);
            size_t a = ((size_t)hh * S_LEN + row) * 64 + e;
            O0[a] = hi; O1[a] = f2bf(qv - bf2f(hi));
          } else if (c < 2048) {
            int cc = c - 1024;
            int hh = cc >> 6, e = cc & 63;
            ushort_t hi = f2bf(v);
            size_t a = ((size_t)hh * S_LEN + row) * 64 + e;
            O2[a] = hi; O3[a] = f2bf(v - bf2f(hi));
          } else {
            int cc = c - 2048;
            int hh = cc >> 6, e = cc & 63;
            size_t a = ((size_t)hh * S_LEN + row) * 64 + e;
            O4[a] = f2bf(v);
          }
        }
      }
    }
  } else if constexpr (EPI == 1) {
    #pragma unroll
    for (int n = 0; n < 4; ++n) {
      long col = n0 + wc * 64 + n * 16 + lrow;
      float bv = bias[col];
      #pragma unroll
      for (int m = 0; m < 8; ++m) {
        #pragma unroll
        for (int r = 0; r < 4; ++r) {
          long row = m0 + wr * 128 + m * 16 + (l >> 4) * 4 + r;
          float v = acc[m][n][r] + bv;
          if (RELU) v = fmaxf(v, 0.f);
          ushort_t h = f2bf(v);
          O0[row * ldc + col] = h;
          O1[row * ldc + col] = f2bf(v - bf2f(h));
        }
      }
    }
  } else {  // EPI == 0: raw f32 partial (split-K), no bias
    float* Cz = C + (long)blockIdx.z * czStride;
    #pragma unroll
    for (int n = 0; n < 4; ++n) {
      long col = n0 + wc * 64 + n * 16 + lrow;
      #pragma unroll
      for (int m = 0; m < 8; ++m) {
        #pragma unroll
        for (int r = 0; r < 4; ++r) {
          long row = m0 + wr * 128 + m * 16 + (l >> 4) * 4 + r;
          Cz[row * ldc + col] = acc[m][n][r];
        }
      }
    }
  }
}

// ---------------------------------------------------------------------------
// MFMA flash attention. qh/ql/kh/kl: [H][S][64] bf16 (q pre-scaled by 0.125),
// vt: [H][64][S] bf16. y out: [S][1024] f32.
// ---------------------------------------------------------------------------
__global__ __launch_bounds__(256)
void attn_mfma(const ushort_t* __restrict__ qh, const ushort_t* __restrict__ ql,
               const ushort_t* __restrict__ kh, const ushort_t* __restrict__ kl,
               const ushort_t* __restrict__ vt, float* __restrict__ y)
{
  __shared__ ushort_t lds[20480];  // Kh[4096] Kl[4096] Vt[4096] P[4x2048]

  const int t = threadIdx.x, l = t & 63, w = t >> 6;
  const int lrow = l & 15, lhi = l >> 4;
  const int h = blockIdx.y;
  const int bw = blockIdx.x * 128 + w * 32;
  const size_t hS = (size_t)h * S_LEN * DHEAD;
  const size_t hV = (size_t)h * DHEAD * S_LEN;
  const int pb = 12288 + w * 2048;

  bf16x8 qhf[2][2], qlf[2][2];
  #pragma unroll
  for (int m = 0; m < 2; ++m)
    #pragma unroll
    for (int ks = 0; ks < 2; ++ks) {
      size_t a = hS + (size_t)(bw + m * 16 + lrow) * 64 + ks * 32 + lhi * 8;
      qhf[m][ks] = *(const bf16x8*)(qh + a);
      qlf[m][ks] = *(const bf16x8*)(ql + a);
    }

  f32x4 acc[2][4];
  #pragma unroll
  for (int m = 0; m < 2; ++m)
    #pragma unroll
    for (int n = 0; n < 4; ++n) acc[m][n] = (f32x4)0.f;
  float mrow[8], lsum[8];
  #pragma unroll
  for (int i = 0; i < 8; ++i) { mrow[i] = -1e30f; lsum[i] = 0.f; }

  for (int kt = 0; kt < S_LEN; kt += 64) {
    __syncthreads();
    #pragma unroll
    for (int i = 0; i < 2; ++i) {
      int s = i * 4 + w;
      size_t krow = (size_t)(kt + (s >> 1) * 16 + lrow);
      int koff = (s & 1) * 32 + lhi * 8;
      GLOAD_LDS16(kh + hS + krow * 64 + koff, &lds[       s * 512 + l * 8]);
      GLOAD_LDS16(kl + hS + krow * 64 + koff, &lds[4096 + s * 512 + l * 8]);
      size_t erow = (size_t)((s >> 1) * 16 + lrow);
      int toff = kt + (s & 1) * 32 + lhi * 8;
      GLOAD_LDS16(vt + hV + erow * S_LEN + toff, &lds[8192 + s * 512 + l * 8]);
    }
    __syncthreads();

    f32x4 sacc[2][4];
    #pragma unroll
    for (int m = 0; m < 2; ++m)
      #pragma unroll
      for (int n = 0; n < 4; ++n) sacc[m][n] = (f32x4)0.f;
    #pragma unroll
    for (int ks = 0; ks < 2; ++ks) {
      bf16x8 bh_[4], bl_[4];
      #pragma unroll
      for (int n = 0; n < 4; ++n) {
        bh_[n] = *(const bf16x8*)&lds[       (n * 2 + ks) * 512 + l * 8];
        bl_[n] = *(const bf16x8*)&lds[4096 + (n * 2 + ks) * 512 + l * 8];
      }
      #pragma unroll
      for (int m = 0; m < 2; ++m)
        #pragma unroll
        for (int n = 0; n < 4; ++n) {
          sacc[m][n] = __builtin_amdgcn_mfma_f32_16x16x32_bf16(qhf[m][ks], bh_[n], sacc[m][n], 0, 0, 0);
          sacc[m][n] = __builtin_amdgcn_mfma_f32_16x16x32_bf16(qhf[m][ks], bl_[n], sacc[m][n], 0, 0, 0);
          sacc[m][n] = __builtin_amdgcn_mfma_f32_16x16x32_bf16(qlf[m][ks], bh_[n], sacc[m][n], 0, 0, 0);
        }
    }

    #pragma unroll
    for (int m = 0; m < 2; ++m) {
      #pragma unroll
      for (int r = 0; r < 4; ++r) {
        const int idx = m * 4 + r;
        float tm = fmaxf(fmaxf(sacc[m][0][r], sacc[m][1][r]),
                         fmaxf(sacc[m][2][r], sacc[m][3][r]));
        tm = fmaxf(tm, __shfl_xor(tm, 1));
        tm = fmaxf(tm, __shfl_xor(tm, 2));
        tm = fmaxf(tm, __shfl_xor(tm, 4));
        tm = fmaxf(tm, __shfl_xor(tm, 8));
        float mn = fmaxf(mrow[idx], tm);
        float al = __expf(mrow[idx] - mn);
        mrow[idx] = mn;
        float rs = 0.f;
        #pragma unroll
        for (int n = 0; n < 4; ++n) {
          float p = __expf(sacc[m][n][r] - mn);
          rs += p;
          int pa = pb + ((m * 2 + (n >> 1)) << 9) + (((n & 1) * 2 + (lrow >> 3)) << 7)
                   + ((lhi * 4 + r) << 3) + (l & 7);
          pa ^= (lrow >> 3) << 3;
          lds[pa] = f2bf(p);
        }
        rs += __shfl_xor(rs, 1);
        rs += __shfl_xor(rs, 2);
        rs += __shfl_xor(rs, 4);
        rs += __shfl_xor(rs, 8);
        lsum[idx] = lsum[idx] * al + rs;
        #pragma unroll
        for (int n = 0; n < 4; ++n) acc[m][n][r] *= al;
      }
    }

    #pragma unroll
    for (int ks = 0; ks < 2; ++ks) {
      bf16x8 pa_[2];
      #pragma unroll
      for (int m = 0; m < 2; ++m) {
        int ra = pb + ((m * 2 + ks) << 9) + (l << 3);
        ra ^= ((l >> 4) & 1) << 3;
        pa_[m] = *(const bf16x8*)&lds[ra];
      }
      #pragma unroll
      for (int n = 0; n < 4; ++n) {
        bf16x8 vf = *(const bf16x8*)&lds[8192 + (n * 2 + ks) * 512 + l * 8];
        #pragma unroll
        for (int m = 0; m < 2; ++m)
          acc[m][n] = __builtin_amdgcn_mfma_f32_16x16x32_bf16(pa_[m], vf, acc[m][n], 0, 0, 0);
      }
    }
  }

  #pragma unroll
  for (int m = 0; m < 2; ++m) {
    #pragma unroll
    for (int r = 0; r < 4; ++r) {
      float inv = 1.0f / lsum[m * 4 + r];
      int row = bw + m * 16 + lhi * 4 + r;
      #pragma unroll
      for (int n = 0; n < 4; ++n)
        y[(size_t)row * DMODEL + h * 64 + n * 16 + lrow] = acc[m][n][r] * inv;
    }
  }
}

// ---------------------------------------------------------------------------
__device__ __forceinline__ float block_sum256(float v, float* sm)
{
  #pragma unroll
  for (int off = 32; off >= 1; off >>= 1) v += __shfl_xor(v, off);
  int w = threadIdx.x >> 6;
  if ((threadIdx.x & 63) == 0) sm[w] = v;
  __syncthreads();
  v = sm[0] + sm[1] + sm[2] + sm[3];
  __syncthreads();
  return v;
}

// x = layernorm(x + y) * g + b, fused bf16 hi/lo split of the result
__global__ __launch_bounds__(256)
void resid_ln_kernel(float* __restrict__ x, const float* __restrict__ y,
                     const float* __restrict__ g, const float* __restrict__ b,
                     ushort_t* __restrict__ xh, ushort_t* __restrict__ xl)
{
  __shared__ float sm[4];
  int row = blockIdx.x, t = threadIdx.x;
  float4 xv = *(const float4*)(x + (size_t)row * DMODEL + t * 4);
  float4 yv = *(const float4*)(y + (size_t)row * DMODEL + t * 4);
  float a0 = xv.x + yv.x, a1 = xv.y + yv.y, a2 = xv.z + yv.z, a3 = xv.w + yv.w;
  float s = block_sum256(a0 + a1 + a2 + a3, sm);
  float mean = s * (1.0f / DMODEL);
  float d0 = a0 - mean, d1 = a1 - mean, d2 = a2 - mean, d3 = a3 - mean;
  float vs = block_sum256(d0*d0 + d1*d1 + d2*d2 + d3*d3, sm);
  float inv = rsqrtf(vs * (1.0f / DMODEL) + 1e-5f);
  float4 gv = *(const float4*)(g + t * 4);
  float4 bv = *(const float4*)(b + t * 4);
  float o[4];
  o[0] = d0 * inv * gv.x + bv.x;
  o[1] = d1 * inv * gv.y + bv.y;
  o[2] = d2 * inv * gv.z + bv.z;
  o[3] = d3 * inv * gv.w + bv.w;
  *(float4*)(x + (size_t)row * DMODEL + t * 4) = make_float4(o[0], o[1], o[2], o[3]);
  ushort_t hv[4], lv[4];
  #pragma unroll
  for (int j = 0; j < 4; ++j) {
    hv[j] = f2bf(o[j]);
    lv[j] = f2bf(o[j] - bf2f(hv[j]));
  }
  *(ushort4*)(xh + (size_t)row * DMODEL + t * 4) = make_ushort4(hv[0], hv[1], hv[2], hv[3]);
  *(ushort4*)(xl + (size_t)row * DMODEL + t * 4) = make_ushort4(lv[0], lv[1], lv[2], lv[3]);
}

// ---------------------------------------------------------------------------
// x = layernorm(x + sum_{z<4} parts[z] + bias) * g + b, fused bf16 split.
// Fuses the split-K reduction of FFN2 into the residual+LN pass.
// ---------------------------------------------------------------------------
__global__ __launch_bounds__(256)
void resid_ln_red(float* __restrict__ x, const float* __restrict__ parts,
                  long pstride, const float* __restrict__ bias,
                  const float* __restrict__ g, const float* __restrict__ b,
                  ushort_t* __restrict__ xh, ushort_t* __restrict__ xl)
{
  __shared__ float sm[4];
  int row = blockIdx.x, t = threadIdx.x;
  size_t base = (size_t)row * DMODEL + t * 4;
  float4 xv = *(const float4*)(x + base);
  float4 bb = *(const float4*)(bias + t * 4);
  float a0 = xv.x + bb.x, a1 = xv.y + bb.y, a2 = xv.z + bb.z, a3 = xv.w + bb.w;
  #pragma unroll
  for (int z = 0; z < 4; ++z) {
    float4 pv = *(const float4*)(parts + (size_t)z * pstride + base);
    a0 += pv.x; a1 += pv.y; a2 += pv.z; a3 += pv.w;
  }
  float s = block_sum256(a0 + a1 + a2 + a3, sm);
  float mean = s * (1.0f / DMODEL);
  float d0 = a0 - mean, d1 = a1 - mean, d2 = a2 - mean, d3 = a3 - mean;
  float vs = block_sum256(d0*d0 + d1*d1 + d2*d2 + d3*d3, sm);
  float inv = rsqrtf(vs * (1.0f / DMODEL) + 1e-5f);
  float4 gv = *(const float4*)(g + t * 4);
  float4 bv = *(const float4*)(b + t * 4);
  float o[4];
  o[0] = d0 * inv * gv.x + bv.x;
  o[1] = d1 * inv * gv.y + bv.y;
  o[2] = d2 * inv * gv.z + bv.z;
  o[3] = d3 * inv * gv.w + bv.w;
  *(float4*)(x + base) = make_float4(o[0], o[1], o[2], o[3]);
  ushort_t hv[4], lv[4];
  #pragma unroll
  for (int j = 0; j < 4; ++j) {
    hv[j] = f2bf(o[j]);
    lv[j] = f2bf(o[j] - bf2f(hv[j]));
  }
  *(ushort4*)(xh + base) = make_ushort4(hv[0], hv[1], hv[2], hv[3]);
  *(ushort4*)(xl + base) = make_ushort4(lv[0], lv[1], lv[2], lv[3]);
}

// ---------------------------------------------------------------------------
// final scale: out[row] *= 1/sum(row); sum from deterministic partials
// ---------------------------------------------------------------------------
__global__ __launch_bounds__(256)
void scale_softmax(float* __restrict__ out, const float* __restrict__ partials,
                   int ncb)
{
  __shared__ float sm[4];
  int row = blockIdx.x, t = threadIdx.x;
  float s = 0.f;
  for (int cb = t; cb < ncb; cb += 256) s += partials[(size_t)row * NCBP + cb];
  s = block_sum256(s, sm);
  float inv = 1.0f / s;
  float* p = out + (size_t)row * VOCAB;
  int head = (int)((((uintptr_t)16 - ((uintptr_t)p & 15)) & 15) >> 2);
  if (t < head) p[t] *= inv;
  int nvec = (VOCAB - head) >> 2;
  float4* pv = (float4*)(p + head);
  for (int i = t; i < nvec; i += 256) {
    float4 v = pv[i];
    v.x *= inv; v.y *= inv; v.z *= inv; v.w *= inv;
    pv[i] = v;
  }
  int done = head + nvec * 4;
  if (t < VOCAB - done) p[done + t] *= inv;
}

// ---------------------------------------------------------------------------
extern "C" void kernel_launch(void* const* d_in, const int* in_sizes, int n_in,
                              void* d_out, int out_size, void* d_ws, size_t ws_size,
                              hipStream_t stream)
{
  const int*   tokens = (const int*)  d_in[0];
  const float* emb    = (const float*)d_in[1];
  const float* Wq     = (const float*)d_in[2];
  const float* bq     = (const float*)d_in[3];
  const float* Wk     = (const float*)d_in[4];
  const float* bk     = (const float*)d_in[5];
  const float* Wv     = (const float*)d_in[6];
  const float* bv     = (const float*)d_in[7];
  const float* ln1g   = (const float*)d_in[8];
  const float* ln1b   = (const float*)d_in[9];
  const float* W1     = (const float*)d_in[10];
  const float* b1     = (const float*)d_in[11];
  const float* W2     = (const float*)d_in[12];
  const float* b2     = (const float*)d_in[13];
  const float* ln2g   = (const float*)d_in[14];
  const float* ln2b   = (const float*)d_in[15];
  const float* Wout   = (const float*)d_in[16];
  const float* bout   = (const float*)d_in[17];

  // workspace (<=30.6 MB): xh 0-8, xl 8-16 (layers); logits phase reuses the
  // dead xl region: stripH 8-16, stripL 16-24, partials 24-30.55
  char* wsb = (char*)d_ws;
  ushort_t* xh     = (ushort_t*)(wsb);
  ushort_t* xl     = (ushort_t*)(wsb + ((size_t)8  << 20));
  ushort_t* stripH = (ushort_t*)(wsb + ((size_t)8  << 20));
  ushort_t* stripL = (ushort_t*)(wsb + ((size_t)16 << 20));
  float*    partials = (float*)(wsb + ((size_t)24 << 20)); // [4096][NCBP] f32

  // scratch in d_out (823 MB; all dead before the logits GEMM writes it)
  char* ob = (char*)d_out;
  float*    x    = (float*)(ob);                          // [S][D] f32 16MB
  float*    yb   = (float*)(ob + ((size_t)16  << 20));    // [S][D] f32 16MB
  ushort_t* qh   = (ushort_t*)(ob + ((size_t)32  << 20)); // [H][S][64] 8MB
  ushort_t* ql   = (ushort_t*)(ob + ((size_t)40  << 20));
  ushort_t* kh   = (ushort_t*)(ob + ((size_t)48  << 20));
  ushort_t* kl   = (ushort_t*)(ob + ((size_t)56  << 20));
  ushort_t* vb16 = (ushort_t*)(ob + ((size_t)64  << 20));
  ushort_t* vt   = (ushort_t*)(ob + ((size_t)72  << 20)); // [H][64][S] 8MB
  ushort_t* h1h  = (ushort_t*)(ob + ((size_t)80  << 20)); // [S][DFF] 32MB
  ushort_t* h1l  = (ushort_t*)(ob + ((size_t)112 << 20));
  ushort_t* wqkvh= (ushort_t*)(ob + ((size_t)144 << 20)); // [3072][1024] 6MB
  ushort_t* wqkvl= (ushort_t*)(ob + ((size_t)150 << 20));
  ushort_t* w1h  = (ushort_t*)(ob + ((size_t)156 << 20)); // [4096][1024] 8MB
  ushort_t* w1l  = (ushort_t*)(ob + ((size_t)164 << 20));
  ushort_t* w2h  = (ushort_t*)(ob + ((size_t)172 << 20)); // [1024][4096] 8MB
  ushort_t* w2l  = (ushort_t*)(ob + ((size_t)180 << 20));
  float*    bqkv = (float*)(ob + ((size_t)188 << 20));    // [3072] f32
  float*    fparts = (float*)(ob + ((size_t)192 << 20));  // [4][S][D] f32 64MB
  float*    outf = (float*)d_out;

  embed_kernel<<<S_LEN, 256, 0, stream>>>(tokens, emb, x, xh, xl);

  for (int l = 0; l < NLAYER; ++l) {
    const long wofs = (long)l * NHEAD * DMODEL * DHEAD;
    transpose_split<<<dim3(16, 1, 16), 256, 0, stream>>>(
        Wq + wofs, wqkvh, wqkvl, (long)DMODEL * DHEAD, (long)DHEAD * DMODEL,
        DHEAD, DMODEL, DHEAD);
    transpose_split<<<dim3(16, 1, 16), 256, 0, stream>>>(
        Wk + wofs, wqkvh + 1024 * 1024, wqkvl + 1024 * 1024,
        (long)DMODEL * DHEAD, (long)DHEAD * DMODEL, DHEAD, DMODEL, DHEAD);
    transpose_split<<<dim3(16, 1, 16), 256, 0, stream>>>(
        Wv + wofs, wqkvh + 2048 * 1024, wqkvl + 2048 * 1024,
        (long)DMODEL * DHEAD, (long)DHEAD * DMODEL, DHEAD, DMODEL, DHEAD);
    concat3_kernel<<<4, 256, 0, stream>>>(
        bq + (long)l * 1024, bk + (long)l * 1024, bv + (long)l * 1024, bqkv, 1024);
    transpose_split<<<dim3(16, 64, 1), 256, 0, stream>>>(
        W1 + (long)l * DMODEL * DFF, w1h, w1l, 0, 0, DFF, DMODEL, DFF);
    transpose_split<<<dim3(64, 16, 1), 256, 0, stream>>>(
        W2 + (long)l * DFF * DMODEL, w2h, w2l, 0, 0, DMODEL, DFF, DMODEL);

    // fused QKV projection: 256^2 8-phase, grid 16x12 = 192 blocks
    gemm8p<2, false, false, 3><<<dim3(16, 12), 512, 0, stream>>>(
        xh, xl, wqkvh, wqkvl, bqkv, nullptr, qh, ql, kh, kl, vb16,
        1024, 1024, 0, 0, 0, nullptr, 0);
    transpose_v<<<dim3(64, 16), 256, 0, stream>>>(vb16, vt);

    attn_mfma<<<dim3(32, 16), 256, 0, stream>>>(qh, ql, kh, kl, vt, yb);

    resid_ln_kernel<<<S_LEN, 256, 0, stream>>>(x, yb,
        ln1g + (size_t)l * DMODEL, ln1b + (size_t)l * DMODEL, xh, xl);

    // FFN1: 256^2 8-phase kernel, grid 16x16 = 256 blocks
    gemm8p<1, true, false, 3><<<dim3(16, 16), 512, 0, stream>>>(
        xh, xl, w1h, w1l, b1 + (long)l * DFF, nullptr, h1h, h1l,
        nullptr, nullptr, nullptr, 1024, 1024, 4096, 0, 0, nullptr, 0);
    // FFN2: split-K x4 (grid 16x4x4 = 256 blocks), f32 partials
    gemm8p<0, false, false, 3><<<dim3(16, 4, 4), 512, 0, stream>>>(
        h1h, h1l, w2h, w2l, nullptr, fparts,
        nullptr, nullptr, nullptr, nullptr, nullptr,
        1024, 4096, 1024, (long)S_LEN * DMODEL, 0, nullptr, 0);
    // fused: x = LN(x + sum(parts) + b2), bf16 split out
    resid_ln_red<<<S_LEN, 256, 0, stream>>>(x, fparts, (long)S_LEN * DMODEL,
        b2 + (long)l * DMODEL,
        ln2g + (size_t)l * DMODEL, ln2b + (size_t)l * DMODEL, xh, xl);
  }

  // logits: 4096-col strips, 256^2 8-phase kernel (2-prod), exp+partials epi
  const int SW = 4096;
  for (int is = 0; is < 12; ++is) {
    int n0 = is * SW;
    transpose_split<<<dim3(16, 64, 1), 256, 0, stream>>>(
        Wout + n0, stripH, stripL, 0, 0, VOCAB, DMODEL, SW);
    gemm8p<3, false, false, 2><<<dim3(16, 16), 512, 0, stream>>>(
        xh, nullptr, stripH, stripL, bout + n0, outf + n0,
        nullptr, nullptr, nullptr, nullptr, nullptr,
        1024, 1024, VOCAB, 0, SW, partials, is * 16);
  }
  {
    int n0 = 12 * SW;                       // 49152
    int ncols = VOCAB - n0;                 // 1105
    int nt64 = (ncols + 63) / 64;           // 18
    int nb256 = (ncols + 255) / 256;        // 5
    transpose_split<<<dim3(16, nt64, 1), 256, 0, stream>>>(
        Wout + n0, stripH, stripL, 0, 0, VOCAB, DMODEL, ncols);
    gemm8p<3, false, true, 2><<<dim3(16, nb256), 512, 0, stream>>>(
        xh, nullptr, stripH, stripL, bout + n0, outf + n0,
        nullptr, nullptr, nullptr, nullptr, nullptr,
        1024, 1024, VOCAB, 0, ncols, partials, 12 * 16);
  }
  const int ncb = (VOCAB + 255) / 256;      // 197
  scale_softmax<<<S_LEN, 256, 0, stream>>>(outf, partials, ncb);
}

// Round 8
// 4163.058 us; speedup vs baseline: 3.7734x; 1.1113x over previous
//
#include <hip/hip_runtime.h>
#include <math.h>

#define S_LEN  4096
#define DMODEL 1024
#define NHEAD  16
#define DHEAD  64
#define DFF    4096
#define NLAYER 4
#define VOCAB  50257
#define NCBP   400   // partials row stride (col-blocks of 256, padded)

typedef unsigned short ushort_t;
typedef __attribute__((ext_vector_type(8))) __bf16 bf16x8;
typedef __attribute__((ext_vector_type(4))) float f32x4;

static __device__ __forceinline__ ushort_t f2bf(float f) {
  union { float f; unsigned u; } x; x.f = f;
  unsigned r = x.u + 0x7fffu + ((x.u >> 16) & 1u);
  return (ushort_t)(r >> 16);
}
static __device__ __forceinline__ float bf2f(ushort_t h) {
  union { unsigned u; float f; } x; x.u = ((unsigned)h) << 16;
  return x.f;
}
// 2^x via v_exp_f32 (avoid __exp2f: collides with glibc math.h macros)
static __device__ __forceinline__ float exp2fast(float x) {
  return __builtin_amdgcn_exp2f(x);
}

#define GLOAD_LDS16(gp, lp) \
  __builtin_amdgcn_global_load_lds((const __attribute__((address_space(1))) void*)(gp), \
                                   (__attribute__((address_space(3))) void*)(lp), 16, 0, 0)

// q pre-scale: 1/sqrt(64) * log2(e)  (softmax runs in exp2 domain)
#define QSCALE 0.18033688011112042f

// ---------------------------------------------------------------------------
// embedding + sinusoidal positional encoding, fused bf16 hi/lo split
// ---------------------------------------------------------------------------
__global__ __launch_bounds__(256) void embed_kernel(
    const int* __restrict__ tokens, const float* __restrict__ emb,
    float* __restrict__ x, ushort_t* __restrict__ xh, ushort_t* __restrict__ xl)
{
  int s = blockIdx.x;
  int tok = tokens[s];
  int d0 = threadIdx.x * 4;
  const double lf = 0.01798894603901598653; // log(10000)/512
  float4 ev = *(const float4*)(emb + (size_t)tok * DMODEL + d0);
  float o[4]; float evr[4] = {ev.x, ev.y, ev.z, ev.w};
  #pragma unroll
  for (int j = 0; j < 4; ++j) {
    int d = d0 + j;
    int i = (d < 512) ? d : d - 512;
    double ang = (double)s * exp(-lf * (double)i);
    float pe = (d < 512) ? (float)sin(ang) : (float)cos(ang);
    o[j] = evr[j] + pe;
  }
  *(float4*)(x + (size_t)s * DMODEL + d0) = make_float4(o[0], o[1], o[2], o[3]);
  ushort_t hv[4], lv[4];
  #pragma unroll
  for (int j = 0; j < 4; ++j) {
    hv[j] = f2bf(o[j]);
    lv[j] = f2bf(o[j] - bf2f(hv[j]));
  }
  *(ushort4*)(xh + (size_t)s * DMODEL + d0) = make_ushort4(hv[0], hv[1], hv[2], hv[3]);
  *(ushort4*)(xl + (size_t)s * DMODEL + d0) = make_ushort4(lv[0], lv[1], lv[2], lv[3]);
}

// ---------------------------------------------------------------------------
// transpose + split: in f32 [K][N] (row stride in_rstride) -> out bf16 hi/lo
// [N][Kout] K-contiguous. Zero-fills columns >= Nvalid. blockIdx.z batches.
// ---------------------------------------------------------------------------
__global__ __launch_bounds__(256)
void transpose_split(const float* __restrict__ in, ushort_t* __restrict__ oh,
                     ushort_t* __restrict__ ol, long in_zstr, long out_zoff,
                     int in_rstride, int Kout, int Nvalid)
{
  __shared__ float tile[64][65];
  const float* inz = in + (long)blockIdx.z * in_zstr;
  ushort_t* ohz = oh + (long)blockIdx.z * out_zoff;
  ushort_t* olz = ol + (long)blockIdx.z * out_zoff;
  int k0 = blockIdx.x * 64, n0 = blockIdx.y * 64;
  int t = threadIdx.x;
  #pragma unroll
  for (int i = 0; i < 4; ++i) {
    int idx = t + i * 256;            // 0..1023
    int kk = idx >> 4, c4 = idx & 15;
    #pragma unroll
    for (int j = 0; j < 4; ++j) {
      int n = n0 + c4 * 4 + j;
      float v = (n < Nvalid) ? inz[(long)(k0 + kk) * in_rstride + n] : 0.f;
      tile[c4 * 4 + j][kk] = v;       // transposed into LDS
    }
  }
  __syncthreads();
  #pragma unroll
  for (int i = 0; i < 4; ++i) {
    int idx = t + i * 256;
    int nn = idx >> 4, k4 = idx & 15;
    ushort_t hv[4], lv[4];
    #pragma unroll
    for (int j = 0; j < 4; ++j) {
      float v = tile[nn][k4 * 4 + j];
      hv[j] = f2bf(v);
      lv[j] = f2bf(v - bf2f(hv[j]));
    }
    long ob = (long)(n0 + nn) * Kout + k0 + k4 * 4;
    *(ushort4*)(ohz + ob) = make_ushort4(hv[0], hv[1], hv[2], hv[3]);
    *(ushort4*)(olz + ob) = make_ushort4(lv[0], lv[1], lv[2], lv[3]);
  }
}

// hi-only variant (for the 1-product logits GEMM)
__global__ __launch_bounds__(256)
void transpose_h(const float* __restrict__ in, ushort_t* __restrict__ oh,
                 int in_rstride, int Kout, int Nvalid)
{
  __shared__ float tile[64][65];
  int k0 = blockIdx.x * 64, n0 = blockIdx.y * 64;
  int t = threadIdx.x;
  #pragma unroll
  for (int i = 0; i < 4; ++i) {
    int idx = t + i * 256;
    int kk = idx >> 4, c4 = idx & 15;
    #pragma unroll
    for (int j = 0; j < 4; ++j) {
      int n = n0 + c4 * 4 + j;
      float v = (n < Nvalid) ? in[(long)(k0 + kk) * in_rstride + n] : 0.f;
      tile[c4 * 4 + j][kk] = v;
    }
  }
  __syncthreads();
  #pragma unroll
  for (int i = 0; i < 4; ++i) {
    int idx = t + i * 256;
    int nn = idx >> 4, k4 = idx & 15;
    ushort_t hv[4];
    #pragma unroll
    for (int j = 0; j < 4; ++j) hv[j] = f2bf(tile[nn][k4 * 4 + j]);
    long ob = (long)(n0 + nn) * Kout + k0 + k4 * 4;
    *(ushort4*)(oh + ob) = make_ushort4(hv[0], hv[1], hv[2], hv[3]);
  }
}

// ---------------------------------------------------------------------------
// bf16 transpose: vb [H][S][64] -> vt [H][64][S]
// ---------------------------------------------------------------------------
__global__ __launch_bounds__(256)
void transpose_v(const ushort_t* __restrict__ vb, ushort_t* __restrict__ vt)
{
  __shared__ ushort_t tile[64][72];
  int h = blockIdx.y, s0 = blockIdx.x * 64;
  int t = threadIdx.x;
  const ushort_t* src = vb + ((size_t)h * S_LEN + s0) * 64;
  #pragma unroll
  for (int i = 0; i < 4; ++i) {
    int idx = t + i * 256;
    int row = idx >> 4, c4 = idx & 15;
    *(ushort4*)&tile[row][c4 * 4] = *(const ushort4*)(src + (size_t)row * 64 + c4 * 4);
  }
  __syncthreads();
  ushort_t* dst = vt + (size_t)h * DHEAD * S_LEN + s0;
  #pragma unroll
  for (int i = 0; i < 4; ++i) {
    int idx = t + i * 256;
    int e = idx >> 4, s4 = idx & 15;
    ushort4 o = make_ushort4(tile[s4*4+0][e], tile[s4*4+1][e],
                             tile[s4*4+2][e], tile[s4*4+3][e]);
    *(ushort4*)(dst + (size_t)e * S_LEN + s4 * 4) = o;
  }
}

// ---------------------------------------------------------------------------
// concat 3 bias vectors of length n into one [3n]
// ---------------------------------------------------------------------------
__global__ __launch_bounds__(256)
void concat3_kernel(const float* __restrict__ a, const float* __restrict__ b,
                    const float* __restrict__ c, float* __restrict__ o, int n)
{
  int i = blockIdx.x * 256 + threadIdx.x;
  if (i < n) { o[i] = a[i]; o[n + i] = b[i]; o[2 * n + i] = c[i]; }
}

// ---------------------------------------------------------------------------
// 256x256-tile 8-wave split-bf16 GEMM, counted-vmcnt phase pipeline (3-prod).
// EPI: 0 = raw f32 partial (split-K), 1 = bf16 hi/lo split C (+bias, RELU),
//      2 = QKV routing (q scaled hi/lo, k hi, v).
// ---------------------------------------------------------------------------
template<int EPI, bool RELU>
__global__ __launch_bounds__(512, 2)
void gemm8p(const ushort_t* __restrict__ Ah, const ushort_t* __restrict__ Al,
            const ushort_t* __restrict__ Bh, const ushort_t* __restrict__ Bl,
            const float* __restrict__ bias, float* __restrict__ C,
            ushort_t* __restrict__ O0, ushort_t* __restrict__ O1,
            ushort_t* __restrict__ O2, ushort_t* __restrict__ O4,
            int K, int ldk, long ldc, long czStride)
{
  constexpr int BUFSTR = 4 * 8192;
  constexpr int OAL = 8192, OBH = 16384, OBL = 24576;
  __shared__ ushort_t lds[2 * BUFSTR];

  const int t = threadIdx.x;
  const int l = t & 63;
  const int w = t >> 6;
  const int wr = w >> 2;
  const int wc = w & 3;
  const int lrow = l & 15;
  const int lk = (l >> 4) * 8;
  const int l8 = l * 8;
  const long m0 = (long)blockIdx.x * 256;
  const long n0 = (long)blockIdx.y * 256;
  const long kz = (long)blockIdx.z * K;

  const ushort_t *agp[2], *algp[2], *bgp[2], *blgp[2];
  int dst[2];
  #pragma unroll
  for (int i = 0; i < 2; ++i) {
    int s = i * 8 + w;
    dst[i] = s * 512 + l8;
    agp[i]  = Ah + (m0 + s * 16 + lrow) * (long)ldk + kz + lk;
    bgp[i]  = Bh + (n0 + s * 16 + lrow) * (long)ldk + kz + lk;
    blgp[i] = Bl + (n0 + s * 16 + lrow) * (long)ldk + kz + lk;
    algp[i] = Al + (m0 + s * 16 + lrow) * (long)ldk + kz + lk;
  }

  f32x4 acc[8][4];
  #pragma unroll
  for (int m = 0; m < 8; ++m)
    #pragma unroll
    for (int n = 0; n < 4; ++n) acc[m][n] = (f32x4)0.f;

  GLOAD_LDS16(agp[0],  &lds[dst[0]]);
  GLOAD_LDS16(agp[1],  &lds[dst[1]]);
  GLOAD_LDS16(bgp[0],  &lds[OBH + dst[0]]);
  GLOAD_LDS16(bgp[1],  &lds[OBH + dst[1]]);
  GLOAD_LDS16(blgp[0], &lds[OBL + dst[0]]);
  GLOAD_LDS16(blgp[1], &lds[OBL + dst[1]]);
  GLOAD_LDS16(algp[0], &lds[OAL + dst[0]]);
  GLOAD_LDS16(algp[1], &lds[OAL + dst[1]]);

  const int nk = K >> 5;
  int cur = 0;
  for (int kt = 0; kt < nk; ++kt) {
    const int knx = (kt + 1 < nk) ? (kt + 1) * 32 : 0;
    ushort_t* cb = &lds[cur * BUFSTR];
    ushort_t* nb = &lds[(cur ^ 1) * BUFSTR];
    bf16x8 af[8], bhf[4], blf[4];

    // P0: Ah*Bh
    asm volatile("s_waitcnt vmcnt(4)" ::: "memory");
    __builtin_amdgcn_sched_barrier(0);
    __builtin_amdgcn_s_barrier();
    __builtin_amdgcn_sched_barrier(0);
    #pragma unroll
    for (int m = 0; m < 8; ++m)
      af[m] = *(const bf16x8*)&cb[(wr * 8 + m) * 512 + l8];
    #pragma unroll
    for (int n = 0; n < 4; ++n)
      bhf[n] = *(const bf16x8*)&cb[OBH + (wc * 4 + n) * 512 + l8];
    GLOAD_LDS16(agp[0] + knx, &nb[dst[0]]);
    GLOAD_LDS16(agp[1] + knx, &nb[dst[1]]);
    GLOAD_LDS16(bgp[0] + knx, &nb[OBH + dst[0]]);
    __builtin_amdgcn_s_setprio(1);
    #pragma unroll
    for (int m = 0; m < 8; ++m)
      #pragma unroll
      for (int n = 0; n < 4; ++n)
        acc[m][n] = __builtin_amdgcn_mfma_f32_16x16x32_bf16(af[m], bhf[n], acc[m][n], 0, 0, 0);
    __builtin_amdgcn_s_setprio(0);
    __builtin_amdgcn_sched_barrier(0);

    // P1: Ah*Bl
    asm volatile("s_waitcnt vmcnt(5)" ::: "memory");
    __builtin_amdgcn_sched_barrier(0);
    __builtin_amdgcn_s_barrier();
    __builtin_amdgcn_sched_barrier(0);
    #pragma unroll
    for (int n = 0; n < 4; ++n)
      blf[n] = *(const bf16x8*)&cb[OBL + (wc * 4 + n) * 512 + l8];
    GLOAD_LDS16(bgp[1] + knx,  &nb[OBH + dst[1]]);
    GLOAD_LDS16(blgp[0] + knx, &nb[OBL + dst[0]]);
    GLOAD_LDS16(blgp[1] + knx, &nb[OBL + dst[1]]);
    __builtin_amdgcn_s_setprio(1);
    #pragma unroll
    for (int m = 0; m < 8; ++m)
      #pragma unroll
      for (int n = 0; n < 4; ++n)
        acc[m][n] = __builtin_amdgcn_mfma_f32_16x16x32_bf16(af[m], blf[n], acc[m][n], 0, 0, 0);
    __builtin_amdgcn_s_setprio(0);
    __builtin_amdgcn_sched_barrier(0);

    // P2: Al*Bh
    asm volatile("s_waitcnt vmcnt(6)" ::: "memory");
    __builtin_amdgcn_sched_barrier(0);
    __builtin_amdgcn_s_barrier();
    __builtin_amdgcn_sched_barrier(0);
    #pragma unroll
    for (int m = 0; m < 8; ++m)
      af[m] = *(const bf16x8*)&cb[OAL + (wr * 8 + m) * 512 + l8];
    GLOAD_LDS16(algp[0] + knx, &nb[OAL + dst[0]]);
    GLOAD_LDS16(algp[1] + knx, &nb[OAL + dst[1]]);
    __builtin_amdgcn_s_setprio(1);
    #pragma unroll
    for (int m = 0; m < 8; ++m)
      #pragma unroll
      for (int n = 0; n < 4; ++n)
        acc[m][n] = __builtin_amdgcn_mfma_f32_16x16x32_bf16(af[m], bhf[n], acc[m][n], 0, 0, 0);
    __builtin_amdgcn_s_setprio(0);
    __builtin_amdgcn_sched_barrier(0);
    cur ^= 1;
  }
  asm volatile("s_waitcnt vmcnt(0)" ::: "memory");

  // ---------------- epilogue ----------------
  if constexpr (EPI == 2) {
    #pragma unroll
    for (int n = 0; n < 4; ++n) {
      long col = n0 + wc * 64 + n * 16 + lrow;
      float bv = bias[col];
      #pragma unroll
      for (int m = 0; m < 8; ++m) {
        #pragma unroll
        for (int r = 0; r < 4; ++r) {
          long row = m0 + wr * 128 + m * 16 + (l >> 4) * 4 + r;
          float v = acc[m][n][r] + bv;
          int c = (int)col;
          if (c < 1024) {
            int hh = c >> 6, e = c & 63;
            float qv = v * QSCALE;            // fold 1/sqrt(DH)*log2e
            ushort_t hi = f2bf(qv);
            size_t a = ((size_t)hh * S_LEN + row) * 64 + e;
            O0[a] = hi; O1[a] = f2bf(qv - bf2f(hi));
          } else if (c < 2048) {
            int cc = c - 1024;
            int hh = cc >> 6, e = cc & 63;
            size_t a = ((size_t)hh * S_LEN + row) * 64 + e;
            O2[a] = f2bf(v);
          } else {
            int cc = c - 2048;
            int hh = cc >> 6, e = cc & 63;
            size_t a = ((size_t)hh * S_LEN + row) * 64 + e;
            O4[a] = f2bf(v);
          }
        }
      }
    }
  } else if constexpr (EPI == 1) {
    #pragma unroll
    for (int n = 0; n < 4; ++n) {
      long col = n0 + wc * 64 + n * 16 + lrow;
      float bv = bias[col];
      #pragma unroll
      for (int m = 0; m < 8; ++m) {
        #pragma unroll
        for (int r = 0; r < 4; ++r) {
          long row = m0 + wr * 128 + m * 16 + (l >> 4) * 4 + r;
          float v = acc[m][n][r] + bv;
          if (RELU) v = fmaxf(v, 0.f);
          ushort_t h = f2bf(v);
          O0[row * ldc + col] = h;
          O1[row * ldc + col] = f2bf(v - bf2f(h));
        }
      }
    }
  } else {  // EPI == 0: raw f32 partial (split-K), no bias
    float* Cz = C + (long)blockIdx.z * czStride;
    #pragma unroll
    for (int n = 0; n < 4; ++n) {
      long col = n0 + wc * 64 + n * 16 + lrow;
      #pragma unroll
      for (int m = 0; m < 8; ++m) {
        #pragma unroll
        for (int r = 0; r < 4; ++r) {
          long row = m0 + wr * 128 + m * 16 + (l >> 4) * 4 + r;
          Cz[row * ldc + col] = acc[m][n][r];
        }
      }
    }
  }
}

// ---------------------------------------------------------------------------
// 1-product 256x256 GEMM (logits): C = exp(Ah@Bh^T + bias), per-row partials.
// 2 streams, 2-tile-deep prefetch, vmcnt(4) counted waits, 32 MFMA/K-step.
// ---------------------------------------------------------------------------
template<bool BOUND>
__global__ __launch_bounds__(512, 2)
void gemm1p(const ushort_t* __restrict__ Ah, const ushort_t* __restrict__ Bh,
            const float* __restrict__ bias, float* __restrict__ C,
            int K, int ldk, long ldc, int Nlimit,
            float* __restrict__ Ppart, int cbbase)
{
  constexpr int OB = 8192;
  constexpr int BUFSTR = 16384;
  __shared__ ushort_t lds[2 * BUFSTR];
  __shared__ float psum[1024];

  const int t = threadIdx.x;
  const int l = t & 63;
  const int w = t >> 6;
  const int wr = w >> 2;
  const int wc = w & 3;
  const int lrow = l & 15;
  const int lk = (l >> 4) * 8;
  const int l8 = l * 8;
  const long m0 = (long)blockIdx.x * 256;
  const long n0 = (long)blockIdx.y * 256;

  const ushort_t *agp[2], *bgp[2];
  int dst[2];
  #pragma unroll
  for (int i = 0; i < 2; ++i) {
    int s = i * 8 + w;
    dst[i] = s * 512 + l8;
    agp[i] = Ah + (m0 + s * 16 + lrow) * (long)ldk + lk;
    bgp[i] = Bh + (n0 + s * 16 + lrow) * (long)ldk + lk;
  }

  f32x4 acc[8][4];
  #pragma unroll
  for (int m = 0; m < 8; ++m)
    #pragma unroll
    for (int n = 0; n < 4; ++n) acc[m][n] = (f32x4)0.f;

  // prologue: tiles 0 and 1 (8 loads outstanding)
  GLOAD_LDS16(agp[0], &lds[dst[0]]);
  GLOAD_LDS16(agp[1], &lds[dst[1]]);
  GLOAD_LDS16(bgp[0], &lds[OB + dst[0]]);
  GLOAD_LDS16(bgp[1], &lds[OB + dst[1]]);
  GLOAD_LDS16(agp[0] + 32, &lds[BUFSTR + dst[0]]);
  GLOAD_LDS16(agp[1] + 32, &lds[BUFSTR + dst[1]]);
  GLOAD_LDS16(bgp[0] + 32, &lds[BUFSTR + OB + dst[0]]);
  GLOAD_LDS16(bgp[1] + 32, &lds[BUFSTR + OB + dst[1]]);

  const int nk = K >> 5;
  int cur = 0;
  for (int kt = 0; kt < nk; ++kt) {
    ushort_t* cb = &lds[cur * BUFSTR];
    bf16x8 af[8], bhf[4];

    asm volatile("s_waitcnt vmcnt(4)" ::: "memory");
    __builtin_amdgcn_sched_barrier(0);
    __builtin_amdgcn_s_barrier();
    __builtin_amdgcn_sched_barrier(0);
    #pragma unroll
    for (int m = 0; m < 8; ++m)
      af[m] = *(const bf16x8*)&cb[(wr * 8 + m) * 512 + l8];
    #pragma unroll
    for (int n = 0; n < 4; ++n)
      bhf[n] = *(const bf16x8*)&cb[OB + (wc * 4 + n) * 512 + l8];
    __builtin_amdgcn_sched_barrier(0);
    asm volatile("s_waitcnt lgkmcnt(0)" ::: "memory");
    __builtin_amdgcn_sched_barrier(0);
    __builtin_amdgcn_s_barrier();      // all waves done reading cb
    __builtin_amdgcn_sched_barrier(0);
    const int knx2 = (kt + 2 < nk) ? (kt + 2) * 32 : 0;  // tail: harmless refill
    GLOAD_LDS16(agp[0] + knx2, &cb[dst[0]]);
    GLOAD_LDS16(agp[1] + knx2, &cb[dst[1]]);
    GLOAD_LDS16(bgp[0] + knx2, &cb[OB + dst[0]]);
    GLOAD_LDS16(bgp[1] + knx2, &cb[OB + dst[1]]);
    __builtin_amdgcn_s_setprio(1);
    #pragma unroll
    for (int m = 0; m < 8; ++m)
      #pragma unroll
      for (int n = 0; n < 4; ++n)
        acc[m][n] = __builtin_amdgcn_mfma_f32_16x16x32_bf16(af[m], bhf[n], acc[m][n], 0, 0, 0);
    __builtin_amdgcn_s_setprio(0);
    __builtin_amdgcn_sched_barrier(0);
    cur ^= 1;
  }
  asm volatile("s_waitcnt vmcnt(0)" ::: "memory");

  // epilogue: exp(logit) + deterministic per-row partial sums
  float smr[8][4];
  #pragma unroll
  for (int m = 0; m < 8; ++m)
    #pragma unroll
    for (int r = 0; r < 4; ++r) smr[m][r] = 0.f;
  #pragma unroll
  for (int n = 0; n < 4; ++n) {
    long col = n0 + wc * 64 + n * 16 + lrow;
    bool cok = (!BOUND) || (col < (long)Nlimit);
    float bv = cok ? bias[col] : 0.f;
    #pragma unroll
    for (int m = 0; m < 8; ++m) {
      #pragma unroll
      for (int r = 0; r < 4; ++r) {
        long row = m0 + wr * 128 + m * 16 + (l >> 4) * 4 + r;
        float e = cok ? __expf(acc[m][n][r] + bv) : 0.f;
        if (cok) C[row * ldc + col] = e;
        smr[m][r] += e;
      }
    }
  }
  #pragma unroll
  for (int m = 0; m < 8; ++m) {
    #pragma unroll
    for (int r = 0; r < 4; ++r) {
      float s = smr[m][r];
      s += __shfl_xor(s, 1);
      s += __shfl_xor(s, 2);
      s += __shfl_xor(s, 4);
      s += __shfl_xor(s, 8);
      if (lrow == 0)
        psum[wc * 256 + wr * 128 + m * 16 + (l >> 4) * 4 + r] = s;
    }
  }
  __syncthreads();
  if (t < 256) {
    float s = psum[t] + psum[256 + t] + psum[512 + t] + psum[768 + t];
    Ppart[(m0 + t) * NCBP + cbbase + blockIdx.y] = s;
  }
}

// ---------------------------------------------------------------------------
// MFMA flash attention v2. qh/ql: [H][S][64] bf16 (pre-scaled by QSCALE),
// kh: [H][S][64] bf16, vt: [H][64][S] bf16. y: [S][1024] f32.
// 2-product QK^T (q split, k bf16); exp2-domain softmax; defer-rescale vote.
// ---------------------------------------------------------------------------
__global__ __launch_bounds__(256)
void attn_mfma(const ushort_t* __restrict__ qh, const ushort_t* __restrict__ ql,
               const ushort_t* __restrict__ kh, const ushort_t* __restrict__ vt,
               float* __restrict__ y)
{
  __shared__ ushort_t lds[16384];  // Kh[4096] Vt[4096] P[4x2048]

  const int t = threadIdx.x, l = t & 63, w = t >> 6;
  const int lrow = l & 15, lhi = l >> 4;
  const int h = blockIdx.y;
  const int bw = blockIdx.x * 128 + w * 32;
  const size_t hS = (size_t)h * S_LEN * DHEAD;
  const size_t hV = (size_t)h * DHEAD * S_LEN;
  const int pb = 8192 + w * 2048;

  bf16x8 qhf[2][2], qlf[2][2];
  #pragma unroll
  for (int m = 0; m < 2; ++m)
    #pragma unroll
    for (int ks = 0; ks < 2; ++ks) {
      size_t a = hS + (size_t)(bw + m * 16 + lrow) * 64 + ks * 32 + lhi * 8;
      qhf[m][ks] = *(const bf16x8*)(qh + a);
      qlf[m][ks] = *(const bf16x8*)(ql + a);
    }

  f32x4 acc[2][4];
  #pragma unroll
  for (int m = 0; m < 2; ++m)
    #pragma unroll
    for (int n = 0; n < 4; ++n) acc[m][n] = (f32x4)0.f;
  float mrow[8], lsum[8];
  #pragma unroll
  for (int i = 0; i < 8; ++i) { mrow[i] = -1e30f; lsum[i] = 0.f; }

  for (int kt = 0; kt < S_LEN; kt += 64) {
    __syncthreads();
    #pragma unroll
    for (int i = 0; i < 2; ++i) {
      int s = i * 4 + w;
      size_t krow = (size_t)(kt + (s >> 1) * 16 + lrow);
      int koff = (s & 1) * 32 + lhi * 8;
      GLOAD_LDS16(kh + hS + krow * 64 + koff, &lds[s * 512 + l * 8]);
      size_t erow = (size_t)((s >> 1) * 16 + lrow);
      int toff = kt + (s & 1) * 32 + lhi * 8;
      GLOAD_LDS16(vt + hV + erow * S_LEN + toff, &lds[4096 + s * 512 + l * 8]);
    }
    __syncthreads();

    // scores (exp2 domain), 2-product: (qh + ql) * kh
    f32x4 sacc[2][4];
    #pragma unroll
    for (int m = 0; m < 2; ++m)
      #pragma unroll
      for (int n = 0; n < 4; ++n) sacc[m][n] = (f32x4)0.f;
    #pragma unroll
    for (int ks = 0; ks < 2; ++ks) {
      bf16x8 bh_[4];
      #pragma unroll
      for (int n = 0; n < 4; ++n)
        bh_[n] = *(const bf16x8*)&lds[(n * 2 + ks) * 512 + l * 8];
      #pragma unroll
      for (int m = 0; m < 2; ++m)
        #pragma unroll
        for (int n = 0; n < 4; ++n) {
          sacc[m][n] = __builtin_amdgcn_mfma_f32_16x16x32_bf16(qhf[m][ks], bh_[n], sacc[m][n], 0, 0, 0);
          sacc[m][n] = __builtin_amdgcn_mfma_f32_16x16x32_bf16(qlf[m][ks], bh_[n], sacc[m][n], 0, 0, 0);
        }
    }

    // tile maxes + wave vote (defer rescale when no row's max grew)
    float tmv[2][4];
    bool up = false;
    #pragma unroll
    for (int m = 0; m < 2; ++m) {
      #pragma unroll
      for (int r = 0; r < 4; ++r) {
        float tm = fmaxf(fmaxf(sacc[m][0][r], sacc[m][1][r]),
                         fmaxf(sacc[m][2][r], sacc[m][3][r]));
        tm = fmaxf(tm, __shfl_xor(tm, 1));
        tm = fmaxf(tm, __shfl_xor(tm, 2));
        tm = fmaxf(tm, __shfl_xor(tm, 4));
        tm = fmaxf(tm, __shfl_xor(tm, 8));
        tmv[m][r] = tm;
        up = up || (tm > mrow[m * 4 + r]);
      }
    }
    if (__ballot(up) != 0ULL) {
      #pragma unroll
      for (int m = 0; m < 2; ++m) {
        #pragma unroll
        for (int r = 0; r < 4; ++r) {
          const int idx = m * 4 + r;
          float mn = fmaxf(mrow[idx], tmv[m][r]);
          float al = exp2fast(mrow[idx] - mn);
          mrow[idx] = mn;
          lsum[idx] *= al;
          #pragma unroll
          for (int n = 0; n < 4; ++n) acc[m][n][r] *= al;
        }
      }
    }
    #pragma unroll
    for (int m = 0; m < 2; ++m) {
      #pragma unroll
      for (int r = 0; r < 4; ++r) {
        const int idx = m * 4 + r;
        float rs = 0.f;
        #pragma unroll
        for (int n = 0; n < 4; ++n) {
          float p = exp2fast(sacc[m][n][r] - mrow[idx]);
          rs += p;
          int pa = pb + ((m * 2 + (n >> 1)) << 9) + (((n & 1) * 2 + (lrow >> 3)) << 7)
                   + ((lhi * 4 + r) << 3) + (l & 7);
          pa ^= (lrow >> 3) << 3;
          lds[pa] = f2bf(p);
        }
        rs += __shfl_xor(rs, 1);
        rs += __shfl_xor(rs, 2);
        rs += __shfl_xor(rs, 4);
        rs += __shfl_xor(rs, 8);
        lsum[idx] += rs;
      }
    }

    // O += P V
    #pragma unroll
    for (int ks = 0; ks < 2; ++ks) {
      bf16x8 pa_[2];
      #pragma unroll
      for (int m = 0; m < 2; ++m) {
        int ra = pb + ((m * 2 + ks) << 9) + (l << 3);
        ra ^= ((l >> 4) & 1) << 3;
        pa_[m] = *(const bf16x8*)&lds[ra];
      }
      #pragma unroll
      for (int n = 0; n < 4; ++n) {
        bf16x8 vf = *(const bf16x8*)&lds[4096 + (n * 2 + ks) * 512 + l * 8];
        #pragma unroll
        for (int m = 0; m < 2; ++m)
          acc[m][n] = __builtin_amdgcn_mfma_f32_16x16x32_bf16(pa_[m], vf, acc[m][n], 0, 0, 0);
      }
    }
  }

  #pragma unroll
  for (int m = 0; m < 2; ++m) {
    #pragma unroll
    for (int r = 0; r < 4; ++r) {
      float inv = 1.0f / lsum[m * 4 + r];
      int row = bw + m * 16 + lhi * 4 + r;
      #pragma unroll
      for (int n = 0; n < 4; ++n)
        y[(size_t)row * DMODEL + h * 64 + n * 16 + lrow] = acc[m][n][r] * inv;
    }
  }
}

// ---------------------------------------------------------------------------
__device__ __forceinline__ float block_sum256(float v, float* sm)
{
  #pragma unroll
  for (int off = 32; off >= 1; off >>= 1) v += __shfl_xor(v, off);
  int w = threadIdx.x >> 6;
  if ((threadIdx.x & 63) == 0) sm[w] = v;
  __syncthreads();
  v = sm[0] + sm[1] + sm[2] + sm[3];
  __syncthreads();
  return v;
}

// x = layernorm(x + y) * g + b, fused bf16 hi/lo split of the result
__global__ __launch_bounds__(256)
void resid_ln_kernel(float* __restrict__ x, const float* __restrict__ y,
                     const float* __restrict__ g, const float* __restrict__ b,
                     ushort_t* __restrict__ xh, ushort_t* __restrict__ xl)
{
  __shared__ float sm[4];
  int row = blockIdx.x, t = threadIdx.x;
  float4 xv = *(const float4*)(x + (size_t)row * DMODEL + t * 4);
  float4 yv = *(const float4*)(y + (size_t)row * DMODEL + t * 4);
  float a0 = xv.x + yv.x, a1 = xv.y + yv.y, a2 = xv.z + yv.z, a3 = xv.w + yv.w;
  float s = block_sum256(a0 + a1 + a2 + a3, sm);
  float mean = s * (1.0f / DMODEL);
  float d0 = a0 - mean, d1 = a1 - mean, d2 = a2 - mean, d3 = a3 - mean;
  float vs = block_sum256(d0*d0 + d1*d1 + d2*d2 + d3*d3, sm);
  float inv = rsqrtf(vs * (1.0f / DMODEL) + 1e-5f);
  float4 gv = *(const float4*)(g + t * 4);
  float4 bv = *(const float4*)(b + t * 4);
  float o[4];
  o[0] = d0 * inv * gv.x + bv.x;
  o[1] = d1 * inv * gv.y + bv.y;
  o[2] = d2 * inv * gv.z + bv.z;
  o[3] = d3 * inv * gv.w + bv.w;
  *(float4*)(x + (size_t)row * DMODEL + t * 4) = make_float4(o[0], o[1], o[2], o[3]);
  ushort_t hv[4], lv[4];
  #pragma unroll
  for (int j = 0; j < 4; ++j) {
    hv[j] = f2bf(o[j]);
    lv[j] = f2bf(o[j] - bf2f(hv[j]));
  }
  *(ushort4*)(xh + (size_t)row * DMODEL + t * 4) = make_ushort4(hv[0], hv[1], hv[2], hv[3]);
  *(ushort4*)(xl + (size_t)row * DMODEL + t * 4) = make_ushort4(lv[0], lv[1], lv[2], lv[3]);
}

// ---------------------------------------------------------------------------
// x = layernorm(x + sum_{z<4} parts[z] + bias) * g + b, fused bf16 split.
// ---------------------------------------------------------------------------
__global__ __launch_bounds__(256)
void resid_ln_red(float* __restrict__ x, const float* __restrict__ parts,
                  long pstride, const float* __restrict__ bias,
                  const float* __restrict__ g, const float* __restrict__ b,
                  ushort_t* __restrict__ xh, ushort_t* __restrict__ xl)
{
  __shared__ float sm[4];
  int row = blockIdx.x, t = threadIdx.x;
  size_t base = (size_t)row * DMODEL + t * 4;
  float4 xv = *(const float4*)(x + base);
  float4 bb = *(const float4*)(bias + t * 4);
  float a0 = xv.x + bb.x, a1 = xv.y + bb.y, a2 = xv.z + bb.z, a3 = xv.w + bb.w;
  #pragma unroll
  for (int z = 0; z < 4; ++z) {
    float4 pv = *(const float4*)(parts + (size_t)z * pstride + base);
    a0 += pv.x; a1 += pv.y; a2 += pv.z; a3 += pv.w;
  }
  float s = block_sum256(a0 + a1 + a2 + a3, sm);
  float mean = s * (1.0f / DMODEL);
  float d0 = a0 - mean, d1 = a1 - mean, d2 = a2 - mean, d3 = a3 - mean;
  float vs = block_sum256(d0*d0 + d1*d1 + d2*d2 + d3*d3, sm);
  float inv = rsqrtf(vs * (1.0f / DMODEL) + 1e-5f);
  float4 gv = *(const float4*)(g + t * 4);
  float4 bv = *(const float4*)(b + t * 4);
  float o[4];
  o[0] = d0 * inv * gv.x + bv.x;
  o[1] = d1 * inv * gv.y + bv.y;
  o[2] = d2 * inv * gv.z + bv.z;
  o[3] = d3 * inv * gv.w + bv.w;
  *(float4*)(x + base) = make_float4(o[0], o[1], o[2], o[3]);
  ushort_t hv[4], lv[4];
  #pragma unroll
  for (int j = 0; j < 4; ++j) {
    hv[j] = f2bf(o[j]);
    lv[j] = f2bf(o[j] - bf2f(hv[j]));
  }
  *(ushort4*)(xh + base) = make_ushort4(hv[0], hv[1], hv[2], hv[3]);
  *(ushort4*)(xl + base) = make_ushort4(lv[0], lv[1], lv[2], lv[3]);
}

// ---------------------------------------------------------------------------
// final scale: out[row] *= 1/sum(row); sum from deterministic partials
// ---------------------------------------------------------------------------
__global__ __launch_bounds__(256)
void scale_softmax(float* __restrict__ out, const float* __restrict__ partials,
                   int ncb)
{
  __shared__ float sm[4];
  int row = blockIdx.x, t = threadIdx.x;
  float s = 0.f;
  for (int cb = t; cb < ncb; cb += 256) s += partials[(size_t)row * NCBP + cb];
  s = block_sum256(s, sm);
  float inv = 1.0f / s;
  float* p = out + (size_t)row * VOCAB;
  int head = (int)((((uintptr_t)16 - ((uintptr_t)p & 15)) & 15) >> 2);
  if (t < head) p[t] *= inv;
  int nvec = (VOCAB - head) >> 2;
  float4* pv = (float4*)(p + head);
  for (int i = t; i < nvec; i += 256) {
    float4 v = pv[i];
    v.x *= inv; v.y *= inv; v.z *= inv; v.w *= inv;
    pv[i] = v;
  }
  int done = head + nvec * 4;
  if (t < VOCAB - done) p[done + t] *= inv;
}

// ---------------------------------------------------------------------------
extern "C" void kernel_launch(void* const* d_in, const int* in_sizes, int n_in,
                              void* d_out, int out_size, void* d_ws, size_t ws_size,
                              hipStream_t stream)
{
  const int*   tokens = (const int*)  d_in[0];
  const float* emb    = (const float*)d_in[1];
  const float* Wq     = (const float*)d_in[2];
  const float* bq     = (const float*)d_in[3];
  const float* Wk     = (const float*)d_in[4];
  const float* bk     = (const float*)d_in[5];
  const float* Wv     = (const float*)d_in[6];
  const float* bv     = (const float*)d_in[7];
  const float* ln1g   = (const float*)d_in[8];
  const float* ln1b   = (const float*)d_in[9];
  const float* W1     = (const float*)d_in[10];
  const float* b1     = (const float*)d_in[11];
  const float* W2     = (const float*)d_in[12];
  const float* b2     = (const float*)d_in[13];
  const float* ln2g   = (const float*)d_in[14];
  const float* ln2b   = (const float*)d_in[15];
  const float* Wout   = (const float*)d_in[16];
  const float* bout   = (const float*)d_in[17];

  // workspace: xh 0-8, xl 8-16 (layers); logits phase: stripH overlays dead
  // xl at 8-16; partials 24-30.55
  char* wsb = (char*)d_ws;
  ushort_t* xh     = (ushort_t*)(wsb);
  ushort_t* xl     = (ushort_t*)(wsb + ((size_t)8  << 20));
  ushort_t* stripH = (ushort_t*)(wsb + ((size_t)8  << 20));
  float*    partials = (float*)(wsb + ((size_t)24 << 20)); // [4096][NCBP] f32

  // scratch in d_out (823 MB; all dead before the logits GEMM writes it)
  char* ob = (char*)d_out;
  float*    x    = (float*)(ob);                          // [S][D] f32 16MB
  float*    yb   = (float*)(ob + ((size_t)16  << 20));    // [S][D] f32 16MB
  ushort_t* qh   = (ushort_t*)(ob + ((size_t)32  << 20)); // [H][S][64] 8MB
  ushort_t* ql   = (ushort_t*)(ob + ((size_t)40  << 20));
  ushort_t* kh   = (ushort_t*)(ob + ((size_t)48  << 20));
  ushort_t* vb16 = (ushort_t*)(ob + ((size_t)64  << 20));
  ushort_t* vt   = (ushort_t*)(ob + ((size_t)72  << 20)); // [H][64][S] 8MB
  ushort_t* h1h  = (ushort_t*)(ob + ((size_t)80  << 20)); // [S][DFF] 32MB
  ushort_t* h1l  = (ushort_t*)(ob + ((size_t)112 << 20));
  ushort_t* wqkvh= (ushort_t*)(ob + ((size_t)144 << 20)); // [3072][1024] 6MB
  ushort_t* wqkvl= (ushort_t*)(ob + ((size_t)150 << 20));
  ushort_t* w1h  = (ushort_t*)(ob + ((size_t)156 << 20)); // [4096][1024] 8MB
  ushort_t* w1l  = (ushort_t*)(ob + ((size_t)164 << 20));
  ushort_t* w2h  = (ushort_t*)(ob + ((size_t)172 << 20)); // [1024][4096] 8MB
  ushort_t* w2l  = (ushort_t*)(ob + ((size_t)180 << 20));
  float*    bqkv = (float*)(ob + ((size_t)188 << 20));    // [3072] f32
  float*    fparts = (float*)(ob + ((size_t)192 << 20));  // [4][S][D] f32 64MB
  float*    outf = (float*)d_out;

  embed_kernel<<<S_LEN, 256, 0, stream>>>(tokens, emb, x, xh, xl);

  for (int l = 0; l < NLAYER; ++l) {
    const long wofs = (long)l * NHEAD * DMODEL * DHEAD;
    transpose_split<<<dim3(16, 1, 16), 256, 0, stream>>>(
        Wq + wofs, wqkvh, wqkvl, (long)DMODEL * DHEAD, (long)DHEAD * DMODEL,
        DHEAD, DMODEL, DHEAD);
    transpose_split<<<dim3(16, 1, 16), 256, 0, stream>>>(
        Wk + wofs, wqkvh + 1024 * 1024, wqkvl + 1024 * 1024,
        (long)DMODEL * DHEAD, (long)DHEAD * DMODEL, DHEAD, DMODEL, DHEAD);
    transpose_split<<<dim3(16, 1, 16), 256, 0, stream>>>(
        Wv + wofs, wqkvh + 2048 * 1024, wqkvl + 2048 * 1024,
        (long)DMODEL * DHEAD, (long)DHEAD * DMODEL, DHEAD, DMODEL, DHEAD);
    concat3_kernel<<<4, 256, 0, stream>>>(
        bq + (long)l * 1024, bk + (long)l * 1024, bv + (long)l * 1024, bqkv, 1024);
    transpose_split<<<dim3(16, 64, 1), 256, 0, stream>>>(
        W1 + (long)l * DMODEL * DFF, w1h, w1l, 0, 0, DFF, DMODEL, DFF);
    transpose_split<<<dim3(64, 16, 1), 256, 0, stream>>>(
        W2 + (long)l * DFF * DMODEL, w2h, w2l, 0, 0, DMODEL, DFF, DMODEL);

    // fused QKV projection: 256^2 8-phase, grid 16x12
    gemm8p<2, false><<<dim3(16, 12), 512, 0, stream>>>(
        xh, xl, wqkvh, wqkvl, bqkv, nullptr, qh, ql, kh, vb16,
        1024, 1024, 0, 0);
    transpose_v<<<dim3(64, 16), 256, 0, stream>>>(vb16, vt);

    attn_mfma<<<dim3(32, 16), 256, 0, stream>>>(qh, ql, kh, vt, yb);

    resid_ln_kernel<<<S_LEN, 256, 0, stream>>>(x, yb,
        ln1g + (size_t)l * DMODEL, ln1b + (size_t)l * DMODEL, xh, xl);

    // FFN1: 256^2 8-phase, grid 16x16
    gemm8p<1, true><<<dim3(16, 16), 512, 0, stream>>>(
        xh, xl, w1h, w1l, b1 + (long)l * DFF, nullptr, h1h, h1l,
        nullptr, nullptr, 1024, 1024, 4096, 0);
    // FFN2: split-K x4 (grid 16x4x4), f32 partials
    gemm8p<0, false><<<dim3(16, 4, 4), 512, 0, stream>>>(
        h1h, h1l, w2h, w2l, nullptr, fparts,
        nullptr, nullptr, nullptr, nullptr,
        1024, 4096, 1024, (long)S_LEN * DMODEL);
    resid_ln_red<<<S_LEN, 256, 0, stream>>>(x, fparts, (long)S_LEN * DMODEL,
        b2 + (long)l * DMODEL,
        ln2g + (size_t)l * DMODEL, ln2b + (size_t)l * DMODEL, xh, xl);
  }

  // logits: 4096-col strips, 1-product kernel, exp+partials epilogue
  const int SW = 4096;
  for (int is = 0; is < 12; ++is) {
    int n0 = is * SW;
    transpose_h<<<dim3(16, 64, 1), 256, 0, stream>>>(
        Wout + n0, stripH, VOCAB, DMODEL, SW);
    gemm1p<false><<<dim3(16, 16), 512, 0, stream>>>(
        xh, stripH, bout + n0, outf + n0,
        1024, 1024, VOCAB, SW, partials, is * 16);
  }
  {
    int n0 = 12 * SW;                       // 49152
    int ncols = VOCAB - n0;                 // 1105
    int nt64 = (ncols + 63) / 64;           // 18
    int nb256 = (ncols + 255) / 256;        // 5
    transpose_h<<<dim3(16, nt64, 1), 256, 0, stream>>>(
        Wout + n0, stripH, VOCAB, DMODEL, ncols);
    gemm1p<true><<<dim3(16, nb256), 512, 0, stream>>>(
        xh, stripH, bout + n0, outf + n0,
        1024, 1024, VOCAB, ncols, partials, 12 * 16);
  }
  const int ncb = (VOCAB + 255) / 256;      // 197
  scale_softmax<<<S_LEN, 256, 0, stream>>>(outf, partials, ncb);
}

// Round 9
// 3820.015 us; speedup vs baseline: 4.1122x; 1.0898x over previous
//
#include <hip/hip_runtime.h>
#include <math.h>

#define S_LEN  4096
#define DMODEL 1024
#define NHEAD  16
#define DHEAD  64
#define DFF    4096
#define NLAYER 4
#define VOCAB  50257
#define NCBP   400   // partials row stride (col-blocks of 256, padded)

typedef unsigned short ushort_t;
typedef __attribute__((ext_vector_type(8))) __bf16 bf16x8;
typedef __attribute__((ext_vector_type(4))) float f32x4;

static __device__ __forceinline__ ushort_t f2bf(float f) {
  union { float f; unsigned u; } x; x.f = f;
  unsigned r = x.u + 0x7fffu + ((x.u >> 16) & 1u);
  return (ushort_t)(r >> 16);
}
static __device__ __forceinline__ float bf2f(ushort_t h) {
  union { unsigned u; float f; } x; x.u = ((unsigned)h) << 16;
  return x.f;
}
// 2^x via v_exp_f32 (avoid __exp2f: collides with glibc math.h macros)
static __device__ __forceinline__ float exp2fast(float x) {
  return __builtin_amdgcn_exp2f(x);
}

#define GLOAD_LDS16(gp, lp) \
  __builtin_amdgcn_global_load_lds((const __attribute__((address_space(1))) void*)(gp), \
                                   (__attribute__((address_space(3))) void*)(lp), 16, 0, 0)

// q pre-scale: 1/sqrt(64) * log2(e)  (softmax runs in exp2 domain)
#define QSCALE 0.18033688011112042f

// ---------------------------------------------------------------------------
// embedding + sinusoidal positional encoding, fused bf16 split (hi only)
// ---------------------------------------------------------------------------
__global__ __launch_bounds__(256) void embed_kernel(
    const int* __restrict__ tokens, const float* __restrict__ emb,
    float* __restrict__ x, ushort_t* __restrict__ xh)
{
  int s = blockIdx.x;
  int tok = tokens[s];
  int d0 = threadIdx.x * 4;
  const double lf = 0.01798894603901598653; // log(10000)/512
  float4 ev = *(const float4*)(emb + (size_t)tok * DMODEL + d0);
  float o[4]; float evr[4] = {ev.x, ev.y, ev.z, ev.w};
  #pragma unroll
  for (int j = 0; j < 4; ++j) {
    int d = d0 + j;
    int i = (d < 512) ? d : d - 512;
    double ang = (double)s * exp(-lf * (double)i);
    float pe = (d < 512) ? (float)sin(ang) : (float)cos(ang);
    o[j] = evr[j] + pe;
  }
  *(float4*)(x + (size_t)s * DMODEL + d0) = make_float4(o[0], o[1], o[2], o[3]);
  ushort_t hv[4];
  #pragma unroll
  for (int j = 0; j < 4; ++j) hv[j] = f2bf(o[j]);
  *(ushort4*)(xh + (size_t)s * DMODEL + d0) = make_ushort4(hv[0], hv[1], hv[2], hv[3]);
}

// ---------------------------------------------------------------------------
// transpose + split: in f32 [K][N] (row stride in_rstride) -> out bf16 hi/lo
// [N][Kout] K-contiguous. Two-level z batching: z1 = z % zdiv (e.g. head),
// z2 = z / zdiv (e.g. layer).
// ---------------------------------------------------------------------------
__global__ __launch_bounds__(256)
void transpose_split(const float* __restrict__ in, ushort_t* __restrict__ oh,
                     ushort_t* __restrict__ ol,
                     long in_zstr, long out_zoff, long in_z2str, long out_z2off,
                     int zdiv, int in_rstride, int Kout, int Nvalid)
{
  __shared__ float tile[64][65];
  int z1 = blockIdx.z % zdiv, z2 = blockIdx.z / zdiv;
  long ioff = (long)z1 * in_zstr + (long)z2 * in_z2str;
  long ooff = (long)z1 * out_zoff + (long)z2 * out_z2off;
  const float* inz = in + ioff;
  ushort_t* ohz = oh + ooff;
  ushort_t* olz = ol + ooff;
  int k0 = blockIdx.x * 64, n0 = blockIdx.y * 64;
  int t = threadIdx.x;
  #pragma unroll
  for (int i = 0; i < 4; ++i) {
    int idx = t + i * 256;            // 0..1023
    int kk = idx >> 4, c4 = idx & 15;
    #pragma unroll
    for (int j = 0; j < 4; ++j) {
      int n = n0 + c4 * 4 + j;
      float v = (n < Nvalid) ? inz[(long)(k0 + kk) * in_rstride + n] : 0.f;
      tile[c4 * 4 + j][kk] = v;       // transposed into LDS
    }
  }
  __syncthreads();
  #pragma unroll
  for (int i = 0; i < 4; ++i) {
    int idx = t + i * 256;
    int nn = idx >> 4, k4 = idx & 15;
    ushort_t hv[4], lv[4];
    #pragma unroll
    for (int j = 0; j < 4; ++j) {
      float v = tile[nn][k4 * 4 + j];
      hv[j] = f2bf(v);
      lv[j] = f2bf(v - bf2f(hv[j]));
    }
    long ob = (long)(n0 + nn) * Kout + k0 + k4 * 4;
    *(ushort4*)(ohz + ob) = make_ushort4(hv[0], hv[1], hv[2], hv[3]);
    *(ushort4*)(olz + ob) = make_ushort4(lv[0], lv[1], lv[2], lv[3]);
  }
}

// hi-only variant (for the 1-product logits GEMM)
__global__ __launch_bounds__(256)
void transpose_h(const float* __restrict__ in, ushort_t* __restrict__ oh,
                 int in_rstride, int Kout, int Nvalid)
{
  __shared__ float tile[64][65];
  int k0 = blockIdx.x * 64, n0 = blockIdx.y * 64;
  int t = threadIdx.x;
  #pragma unroll
  for (int i = 0; i < 4; ++i) {
    int idx = t + i * 256;
    int kk = idx >> 4, c4 = idx & 15;
    #pragma unroll
    for (int j = 0; j < 4; ++j) {
      int n = n0 + c4 * 4 + j;
      float v = (n < Nvalid) ? in[(long)(k0 + kk) * in_rstride + n] : 0.f;
      tile[c4 * 4 + j][kk] = v;
    }
  }
  __syncthreads();
  #pragma unroll
  for (int i = 0; i < 4; ++i) {
    int idx = t + i * 256;
    int nn = idx >> 4, k4 = idx & 15;
    ushort_t hv[4];
    #pragma unroll
    for (int j = 0; j < 4; ++j) hv[j] = f2bf(tile[nn][k4 * 4 + j]);
    long ob = (long)(n0 + nn) * Kout + k0 + k4 * 4;
    *(ushort4*)(oh + ob) = make_ushort4(hv[0], hv[1], hv[2], hv[3]);
  }
}

// ---------------------------------------------------------------------------
// bf16 transpose: vb [H][S][64] -> vt [H][64][S]
// ---------------------------------------------------------------------------
__global__ __launch_bounds__(256)
void transpose_v(const ushort_t* __restrict__ vb, ushort_t* __restrict__ vt)
{
  __shared__ ushort_t tile[64][72];
  int h = blockIdx.y, s0 = blockIdx.x * 64;
  int t = threadIdx.x;
  const ushort_t* src = vb + ((size_t)h * S_LEN + s0) * 64;
  #pragma unroll
  for (int i = 0; i < 4; ++i) {
    int idx = t + i * 256;
    int row = idx >> 4, c4 = idx & 15;
    *(ushort4*)&tile[row][c4 * 4] = *(const ushort4*)(src + (size_t)row * 64 + c4 * 4);
  }
  __syncthreads();
  ushort_t* dst = vt + (size_t)h * DHEAD * S_LEN + s0;
  #pragma unroll
  for (int i = 0; i < 4; ++i) {
    int idx = t + i * 256;
    int e = idx >> 4, s4 = idx & 15;
    ushort4 o = make_ushort4(tile[s4*4+0][e], tile[s4*4+1][e],
                             tile[s4*4+2][e], tile[s4*4+3][e]);
    *(ushort4*)(dst + (size_t)e * S_LEN + s4 * 4) = o;
  }
}

// ---------------------------------------------------------------------------
// concat 3 bias vectors of length n into [3n], batched over layers (y)
// ---------------------------------------------------------------------------
__global__ __launch_bounds__(256)
void concat3_kernel(const float* __restrict__ a, const float* __restrict__ b,
                    const float* __restrict__ c, float* __restrict__ o,
                    int n, long lstrA, long lstrO)
{
  int i = blockIdx.x * 256 + threadIdx.x;
  long l = blockIdx.y;
  if (i < n) {
    o[l * lstrO + i]         = a[l * lstrA + i];
    o[l * lstrO + n + i]     = b[l * lstrA + i];
    o[l * lstrO + 2 * n + i] = c[l * lstrA + i];
  }
}

// ---------------------------------------------------------------------------
// 256x256-tile 8-wave GEMM, counted-vmcnt phase pipeline, 2-product split:
// C = Ah @ (Bh + Bl)^T. Streams Ah|Bh|Bl, double-buffered (96 KB LDS).
// Per-tile issue order [Ah0,Ah1,Bh0 | Bh1,Bl0,Bl1] -> waits vmcnt(2)/(3);
// loads never drain to 0 in the loop.
// EPI: 0 = raw f32 partial (split-K via blockIdx.z), 1 = bf16 hi C (+bias,
// RELU), 2 = QKV routing (q scaled hi/lo, k hi, v).
// ---------------------------------------------------------------------------
template<int EPI, bool RELU>
__global__ __launch_bounds__(512, 2)
void gemm8p(const ushort_t* __restrict__ Ah,
            const ushort_t* __restrict__ Bh, const ushort_t* __restrict__ Bl,
            const float* __restrict__ bias, float* __restrict__ C,
            ushort_t* __restrict__ O0, ushort_t* __restrict__ O1,
            ushort_t* __restrict__ O2, ushort_t* __restrict__ O4,
            int K, int ldk, long ldc, long czStride)
{
  constexpr int BUFSTR = 3 * 8192;              // Ah | Bh | Bl
  constexpr int OBH = 8192, OBL = 16384;
  __shared__ ushort_t lds[2 * BUFSTR];          // 96 KB

  const int t = threadIdx.x;
  const int l = t & 63;
  const int w = t >> 6;            // 0..7
  const int wr = w >> 2;           // 0..1  (row half)
  const int wc = w & 3;            // 0..3  (col quarter)
  const int lrow = l & 15;
  const int lk = (l >> 4) * 8;
  const int l8 = l * 8;
  const long m0 = (long)blockIdx.x * 256;
  const long n0 = (long)blockIdx.y * 256;
  const long kz = (long)blockIdx.z * K;

  const ushort_t *agp[2], *bgp[2], *blgp[2];
  int dst[2];
  #pragma unroll
  for (int i = 0; i < 2; ++i) {
    int s = i * 8 + w;                       // subtile 0..15
    dst[i] = s * 512 + l8;
    agp[i]  = Ah + (m0 + s * 16 + lrow) * (long)ldk + kz + lk;
    bgp[i]  = Bh + (n0 + s * 16 + lrow) * (long)ldk + kz + lk;
    blgp[i] = Bl + (n0 + s * 16 + lrow) * (long)ldk + kz + lk;
  }

  f32x4 acc[8][4];
  #pragma unroll
  for (int m = 0; m < 8; ++m)
    #pragma unroll
    for (int n = 0; n < 4; ++n) acc[m][n] = (f32x4)0.f;

  // prologue: stage tile 0, canonical per-tile order
  GLOAD_LDS16(agp[0],  &lds[dst[0]]);
  GLOAD_LDS16(agp[1],  &lds[dst[1]]);
  GLOAD_LDS16(bgp[0],  &lds[OBH + dst[0]]);
  GLOAD_LDS16(bgp[1],  &lds[OBH + dst[1]]);
  GLOAD_LDS16(blgp[0], &lds[OBL + dst[0]]);
  GLOAD_LDS16(blgp[1], &lds[OBL + dst[1]]);

  const int nk = K >> 5;
  int cur = 0;
  for (int kt = 0; kt < nk; ++kt) {
    const int knx = (kt + 1 < nk) ? (kt + 1) * 32 : 0;  // last iter: harmless reload
    ushort_t* cb = &lds[cur * BUFSTR];
    ushort_t* nb = &lds[(cur ^ 1) * BUFSTR];
    bf16x8 af[8], bhf[4], blf[4];

    // ---------- P0: needs Ah,Bh of tile kt ----------
    asm volatile("s_waitcnt vmcnt(2)" ::: "memory");
    __builtin_amdgcn_sched_barrier(0);
    __builtin_amdgcn_s_barrier();
    __builtin_amdgcn_sched_barrier(0);
    #pragma unroll
    for (int m = 0; m < 8; ++m)
      af[m] = *(const bf16x8*)&cb[(wr * 8 + m) * 512 + l8];
    #pragma unroll
    for (int n = 0; n < 4; ++n)
      bhf[n] = *(const bf16x8*)&cb[OBH + (wc * 4 + n) * 512 + l8];
    GLOAD_LDS16(agp[0] + knx, &nb[dst[0]]);
    GLOAD_LDS16(agp[1] + knx, &nb[dst[1]]);
    GLOAD_LDS16(bgp[0] + knx, &nb[OBH + dst[0]]);
    __builtin_amdgcn_s_setprio(1);
    #pragma unroll
    for (int m = 0; m < 8; ++m)
      #pragma unroll
      for (int n = 0; n < 4; ++n)
        acc[m][n] = __builtin_amdgcn_mfma_f32_16x16x32_bf16(af[m], bhf[n], acc[m][n], 0, 0, 0);
    __builtin_amdgcn_s_setprio(0);
    __builtin_amdgcn_sched_barrier(0);

    // ---------- P1: needs Bl of tile kt ----------
    asm volatile("s_waitcnt vmcnt(3)" ::: "memory");
    __builtin_amdgcn_sched_barrier(0);
    __builtin_amdgcn_s_barrier();
    __builtin_amdgcn_sched_barrier(0);
    #pragma unroll
    for (int n = 0; n < 4; ++n)
      blf[n] = *(const bf16x8*)&cb[OBL + (wc * 4 + n) * 512 + l8];
    GLOAD_LDS16(bgp[1] + knx,  &nb[OBH + dst[1]]);
    GLOAD_LDS16(blgp[0] + knx, &nb[OBL + dst[0]]);
    GLOAD_LDS16(blgp[1] + knx, &nb[OBL + dst[1]]);
    __builtin_amdgcn_s_setprio(1);
    #pragma unroll
    for (int m = 0; m < 8; ++m)
      #pragma unroll
      for (int n = 0; n < 4; ++n)
        acc[m][n] = __builtin_amdgcn_mfma_f32_16x16x32_bf16(af[m], blf[n], acc[m][n], 0, 0, 0);
    __builtin_amdgcn_s_setprio(0);
    __builtin_amdgcn_sched_barrier(0);
    cur ^= 1;
  }
  asm volatile("s_waitcnt vmcnt(0)" ::: "memory");

  // ---------------- epilogue ----------------
  if constexpr (EPI == 2) {
    #pragma unroll
    for (int n = 0; n < 4; ++n) {
      long col = n0 + wc * 64 + n * 16 + lrow;
      float bv = bias[col];
      #pragma unroll
      for (int m = 0; m < 8; ++m) {
        #pragma unroll
        for (int r = 0; r < 4; ++r) {
          long row = m0 + wr * 128 + m * 16 + (l >> 4) * 4 + r;
          float v = acc[m][n][r] + bv;
          int c = (int)col;
          if (c < 1024) {
            int hh = c >> 6, e = c & 63;
            float qv = v * QSCALE;            // fold 1/sqrt(DH)*log2e
            ushort_t hi = f2bf(qv);
            size_t a = ((size_t)hh * S_LEN + row) * 64 + e;
            O0[a] = hi; O1[a] = f2bf(qv - bf2f(hi));
          } else if (c < 2048) {
            int cc = c - 1024;
            int hh = cc >> 6, e = cc & 63;
            size_t a = ((size_t)hh * S_LEN + row) * 64 + e;
            O2[a] = f2bf(v);
          } else {
            int cc = c - 2048;
            int hh = cc >> 6, e = cc & 63;
            size_t a = ((size_t)hh * S_LEN + row) * 64 + e;
            O4[a] = f2bf(v);
          }
        }
      }
    }
  } else if constexpr (EPI == 1) {
    #pragma unroll
    for (int n = 0; n < 4; ++n) {
      long col = n0 + wc * 64 + n * 16 + lrow;
      float bv = bias[col];
      #pragma unroll
      for (int m = 0; m < 8; ++m) {
        #pragma unroll
        for (int r = 0; r < 4; ++r) {
          long row = m0 + wr * 128 + m * 16 + (l >> 4) * 4 + r;
          float v = acc[m][n][r] + bv;
          if (RELU) v = fmaxf(v, 0.f);
          O0[row * ldc + col] = f2bf(v);
        }
      }
    }
  } else {  // EPI == 0: raw f32 partial (split-K), no bias
    float* Cz = C + (long)blockIdx.z * czStride;
    #pragma unroll
    for (int n = 0; n < 4; ++n) {
      long col = n0 + wc * 64 + n * 16 + lrow;
      #pragma unroll
      for (int m = 0; m < 8; ++m) {
        #pragma unroll
        for (int r = 0; r < 4; ++r) {
          long row = m0 + wr * 128 + m * 16 + (l >> 4) * 4 + r;
          Cz[row * ldc + col] = acc[m][n][r];
        }
      }
    }
  }
}

// ---------------------------------------------------------------------------
// 1-product 256x256 GEMM (logits): C = exp(Ah@Bh^T + bias), per-row partials.
// 2 streams, 2-tile-deep prefetch, vmcnt(4) counted waits, 32 MFMA/K-step.
// ---------------------------------------------------------------------------
template<bool BOUND>
__global__ __launch_bounds__(512, 2)
void gemm1p(const ushort_t* __restrict__ Ah, const ushort_t* __restrict__ Bh,
            const float* __restrict__ bias, float* __restrict__ C,
            int K, int ldk, long ldc, int Nlimit,
            float* __restrict__ Ppart, int cbbase)
{
  constexpr int OB = 8192;
  constexpr int BUFSTR = 16384;
  __shared__ ushort_t lds[2 * BUFSTR];
  __shared__ float psum[1024];

  const int t = threadIdx.x;
  const int l = t & 63;
  const int w = t >> 6;
  const int wr = w >> 2;
  const int wc = w & 3;
  const int lrow = l & 15;
  const int lk = (l >> 4) * 8;
  const int l8 = l * 8;
  const long m0 = (long)blockIdx.x * 256;
  const long n0 = (long)blockIdx.y * 256;

  const ushort_t *agp[2], *bgp[2];
  int dst[2];
  #pragma unroll
  for (int i = 0; i < 2; ++i) {
    int s = i * 8 + w;
    dst[i] = s * 512 + l8;
    agp[i] = Ah + (m0 + s * 16 + lrow) * (long)ldk + lk;
    bgp[i] = Bh + (n0 + s * 16 + lrow) * (long)ldk + lk;
  }

  f32x4 acc[8][4];
  #pragma unroll
  for (int m = 0; m < 8; ++m)
    #pragma unroll
    for (int n = 0; n < 4; ++n) acc[m][n] = (f32x4)0.f;

  // prologue: tiles 0 and 1 (8 loads outstanding)
  GLOAD_LDS16(agp[0], &lds[dst[0]]);
  GLOAD_LDS16(agp[1], &lds[dst[1]]);
  GLOAD_LDS16(bgp[0], &lds[OB + dst[0]]);
  GLOAD_LDS16(bgp[1], &lds[OB + dst[1]]);
  GLOAD_LDS16(agp[0] + 32, &lds[BUFSTR + dst[0]]);
  GLOAD_LDS16(agp[1] + 32, &lds[BUFSTR + dst[1]]);
  GLOAD_LDS16(bgp[0] + 32, &lds[BUFSTR + OB + dst[0]]);
  GLOAD_LDS16(bgp[1] + 32, &lds[BUFSTR + OB + dst[1]]);

  const int nk = K >> 5;
  int cur = 0;
  for (int kt = 0; kt < nk; ++kt) {
    ushort_t* cb = &lds[cur * BUFSTR];
    bf16x8 af[8], bhf[4];

    asm volatile("s_waitcnt vmcnt(4)" ::: "memory");
    __builtin_amdgcn_sched_barrier(0);
    __builtin_amdgcn_s_barrier();
    __builtin_amdgcn_sched_barrier(0);
    #pragma unroll
    for (int m = 0; m < 8; ++m)
      af[m] = *(const bf16x8*)&cb[(wr * 8 + m) * 512 + l8];
    #pragma unroll
    for (int n = 0; n < 4; ++n)
      bhf[n] = *(const bf16x8*)&cb[OB + (wc * 4 + n) * 512 + l8];
    __builtin_amdgcn_sched_barrier(0);
    asm volatile("s_waitcnt lgkmcnt(0)" ::: "memory");
    __builtin_amdgcn_sched_barrier(0);
    __builtin_amdgcn_s_barrier();      // all waves done reading cb
    __builtin_amdgcn_sched_barrier(0);
    const int knx2 = (kt + 2 < nk) ? (kt + 2) * 32 : 0;  // tail: harmless refill
    GLOAD_LDS16(agp[0] + knx2, &cb[dst[0]]);
    GLOAD_LDS16(agp[1] + knx2, &cb[dst[1]]);
    GLOAD_LDS16(bgp[0] + knx2, &cb[OB + dst[0]]);
    GLOAD_LDS16(bgp[1] + knx2, &cb[OB + dst[1]]);
    __builtin_amdgcn_s_setprio(1);
    #pragma unroll
    for (int m = 0; m < 8; ++m)
      #pragma unroll
      for (int n = 0; n < 4; ++n)
        acc[m][n] = __builtin_amdgcn_mfma_f32_16x16x32_bf16(af[m], bhf[n], acc[m][n], 0, 0, 0);
    __builtin_amdgcn_s_setprio(0);
    __builtin_amdgcn_sched_barrier(0);
    cur ^= 1;
  }
  asm volatile("s_waitcnt vmcnt(0)" ::: "memory");

  // epilogue: exp(logit) + deterministic per-row partial sums
  float smr[8][4];
  #pragma unroll
  for (int m = 0; m < 8; ++m)
    #pragma unroll
    for (int r = 0; r < 4; ++r) smr[m][r] = 0.f;
  #pragma unroll
  for (int n = 0; n < 4; ++n) {
    long col = n0 + wc * 64 + n * 16 + lrow;
    bool cok = (!BOUND) || (col < (long)Nlimit);
    float bv = cok ? bias[col] : 0.f;
    #pragma unroll
    for (int m = 0; m < 8; ++m) {
      #pragma unroll
      for (int r = 0; r < 4; ++r) {
        long row = m0 + wr * 128 + m * 16 + (l >> 4) * 4 + r;
        float e = cok ? __expf(acc[m][n][r] + bv) : 0.f;
        if (cok) C[row * ldc + col] = e;
        smr[m][r] += e;
      }
    }
  }
  #pragma unroll
  for (int m = 0; m < 8; ++m) {
    #pragma unroll
    for (int r = 0; r < 4; ++r) {
      float s = smr[m][r];
      s += __shfl_xor(s, 1);
      s += __shfl_xor(s, 2);
      s += __shfl_xor(s, 4);
      s += __shfl_xor(s, 8);
      if (lrow == 0)
        psum[wc * 256 + wr * 128 + m * 16 + (l >> 4) * 4 + r] = s;
    }
  }
  __syncthreads();
  if (t < 256) {
    float s = psum[t] + psum[256 + t] + psum[512 + t] + psum[768 + t];
    Ppart[(m0 + t) * NCBP + cbbase + blockIdx.y] = s;
  }
}

// ---------------------------------------------------------------------------
// MFMA flash attention v2. qh/ql: [H][S][64] bf16 (pre-scaled by QSCALE),
// kh: [H][S][64] bf16, vt: [H][64][S] bf16. y: [S][1024] f32.
// 2-product QK^T (q split, k bf16); exp2-domain softmax; defer-rescale vote.
// ---------------------------------------------------------------------------
__global__ __launch_bounds__(256)
void attn_mfma(const ushort_t* __restrict__ qh, const ushort_t* __restrict__ ql,
               const ushort_t* __restrict__ kh, const ushort_t* __restrict__ vt,
               float* __restrict__ y)
{
  __shared__ ushort_t lds[16384];  // Kh[4096] Vt[4096] P[4x2048]

  const int t = threadIdx.x, l = t & 63, w = t >> 6;
  const int lrow = l & 15, lhi = l >> 4;
  const int h = blockIdx.y;
  const int bw = blockIdx.x * 128 + w * 32;
  const size_t hS = (size_t)h * S_LEN * DHEAD;
  const size_t hV = (size_t)h * DHEAD * S_LEN;
  const int pb = 8192 + w * 2048;

  bf16x8 qhf[2][2], qlf[2][2];
  #pragma unroll
  for (int m = 0; m < 2; ++m)
    #pragma unroll
    for (int ks = 0; ks < 2; ++ks) {
      size_t a = hS + (size_t)(bw + m * 16 + lrow) * 64 + ks * 32 + lhi * 8;
      qhf[m][ks] = *(const bf16x8*)(qh + a);
      qlf[m][ks] = *(const bf16x8*)(ql + a);
    }

  f32x4 acc[2][4];
  #pragma unroll
  for (int m = 0; m < 2; ++m)
    #pragma unroll
    for (int n = 0; n < 4; ++n) acc[m][n] = (f32x4)0.f;
  float mrow[8], lsum[8];
  #pragma unroll
  for (int i = 0; i < 8; ++i) { mrow[i] = -1e30f; lsum[i] = 0.f; }

  for (int kt = 0; kt < S_LEN; kt += 64) {
    __syncthreads();
    #pragma unroll
    for (int i = 0; i < 2; ++i) {
      int s = i * 4 + w;
      size_t krow = (size_t)(kt + (s >> 1) * 16 + lrow);
      int koff = (s & 1) * 32 + lhi * 8;
      GLOAD_LDS16(kh + hS + krow * 64 + koff, &lds[s * 512 + l * 8]);
      size_t erow = (size_t)((s >> 1) * 16 + lrow);
      int toff = kt + (s & 1) * 32 + lhi * 8;
      GLOAD_LDS16(vt + hV + erow * S_LEN + toff, &lds[4096 + s * 512 + l * 8]);
    }
    __syncthreads();

    // scores (exp2 domain), 2-product: (qh + ql) * kh
    f32x4 sacc[2][4];
    #pragma unroll
    for (int m = 0; m < 2; ++m)
      #pragma unroll
      for (int n = 0; n < 4; ++n) sacc[m][n] = (f32x4)0.f;
    #pragma unroll
    for (int ks = 0; ks < 2; ++ks) {
      bf16x8 bh_[4];
      #pragma unroll
      for (int n = 0; n < 4; ++n)
        bh_[n] = *(const bf16x8*)&lds[(n * 2 + ks) * 512 + l * 8];
      #pragma unroll
      for (int m = 0; m < 2; ++m)
        #pragma unroll
        for (int n = 0; n < 4; ++n) {
          sacc[m][n] = __builtin_amdgcn_mfma_f32_16x16x32_bf16(qhf[m][ks], bh_[n], sacc[m][n], 0, 0, 0);
          sacc[m][n] = __builtin_amdgcn_mfma_f32_16x16x32_bf16(qlf[m][ks], bh_[n], sacc[m][n], 0, 0, 0);
        }
    }

    // tile maxes + wave vote (defer rescale when no row's max grew)
    float tmv[2][4];
    bool up = false;
    #pragma unroll
    for (int m = 0; m < 2; ++m) {
      #pragma unroll
      for (int r = 0; r < 4; ++r) {
        float tm = fmaxf(fmaxf(sacc[m][0][r], sacc[m][1][r]),
                         fmaxf(sacc[m][2][r], sacc[m][3][r]));
        tm = fmaxf(tm, __shfl_xor(tm, 1));
        tm = fmaxf(tm, __shfl_xor(tm, 2));
        tm = fmaxf(tm, __shfl_xor(tm, 4));
        tm = fmaxf(tm, __shfl_xor(tm, 8));
        tmv[m][r] = tm;
        up = up || (tm > mrow[m * 4 + r]);
      }
    }
    if (__ballot(up) != 0ULL) {
      #pragma unroll
      for (int m = 0; m < 2; ++m) {
        #pragma unroll
        for (int r = 0; r < 4; ++r) {
          const int idx = m * 4 + r;
          float mn = fmaxf(mrow[idx], tmv[m][r]);
          float al = exp2fast(mrow[idx] - mn);
          mrow[idx] = mn;
          lsum[idx] *= al;
          #pragma unroll
          for (int n = 0; n < 4; ++n) acc[m][n][r] *= al;
        }
      }
    }
    #pragma unroll
    for (int m = 0; m < 2; ++m) {
      #pragma unroll
      for (int r = 0; r < 4; ++r) {
        const int idx = m * 4 + r;
        float rs = 0.f;
        #pragma unroll
        for (int n = 0; n < 4; ++n) {
          float p = exp2fast(sacc[m][n][r] - mrow[idx]);
          rs += p;
          int pa = pb + ((m * 2 + (n >> 1)) << 9) + (((n & 1) * 2 + (lrow >> 3)) << 7)
                   + ((lhi * 4 + r) << 3) + (l & 7);
          pa ^= (lrow >> 3) << 3;
          lds[pa] = f2bf(p);
        }
        rs += __shfl_xor(rs, 1);
        rs += __shfl_xor(rs, 2);
        rs += __shfl_xor(rs, 4);
        rs += __shfl_xor(rs, 8);
        lsum[idx] += rs;
      }
    }

    // O += P V
    #pragma unroll
    for (int ks = 0; ks < 2; ++ks) {
      bf16x8 pa_[2];
      #pragma unroll
      for (int m = 0; m < 2; ++m) {
        int ra = pb + ((m * 2 + ks) << 9) + (l << 3);
        ra ^= ((l >> 4) & 1) << 3;
        pa_[m] = *(const bf16x8*)&lds[ra];
      }
      #pragma unroll
      for (int n = 0; n < 4; ++n) {
        bf16x8 vf = *(const bf16x8*)&lds[4096 + (n * 2 + ks) * 512 + l * 8];
        #pragma unroll
        for (int m = 0; m < 2; ++m)
          acc[m][n] = __builtin_amdgcn_mfma_f32_16x16x32_bf16(pa_[m], vf, acc[m][n], 0, 0, 0);
      }
    }
  }

  #pragma unroll
  for (int m = 0; m < 2; ++m) {
    #pragma unroll
    for (int r = 0; r < 4; ++r) {
      float inv = 1.0f / lsum[m * 4 + r];
      int row = bw + m * 16 + lhi * 4 + r;
      #pragma unroll
      for (int n = 0; n < 4; ++n)
        y[(size_t)row * DMODEL + h * 64 + n * 16 + lrow] = acc[m][n][r] * inv;
    }
  }
}

// ---------------------------------------------------------------------------
__device__ __forceinline__ float block_sum256(float v, float* sm)
{
  #pragma unroll
  for (int off = 32; off >= 1; off >>= 1) v += __shfl_xor(v, off);
  int w = threadIdx.x >> 6;
  if ((threadIdx.x & 63) == 0) sm[w] = v;
  __syncthreads();
  v = sm[0] + sm[1] + sm[2] + sm[3];
  __syncthreads();
  return v;
}

// x = layernorm(x + y) * g + b, fused bf16 (hi only) split of the result
__global__ __launch_bounds__(256)
void resid_ln_kernel(float* __restrict__ x, const float* __restrict__ y,
                     const float* __restrict__ g, const float* __restrict__ b,
                     ushort_t* __restrict__ xh)
{
  __shared__ float sm[4];
  int row = blockIdx.x, t = threadIdx.x;
  float4 xv = *(const float4*)(x + (size_t)row * DMODEL + t * 4);
  float4 yv = *(const float4*)(y + (size_t)row * DMODEL + t * 4);
  float a0 = xv.x + yv.x, a1 = xv.y + yv.y, a2 = xv.z + yv.z, a3 = xv.w + yv.w;
  float s = block_sum256(a0 + a1 + a2 + a3, sm);
  float mean = s * (1.0f / DMODEL);
  float d0 = a0 - mean, d1 = a1 - mean, d2 = a2 - mean, d3 = a3 - mean;
  float vs = block_sum256(d0*d0 + d1*d1 + d2*d2 + d3*d3, sm);
  float inv = rsqrtf(vs * (1.0f / DMODEL) + 1e-5f);
  float4 gv = *(const float4*)(g + t * 4);
  float4 bv = *(const float4*)(b + t * 4);
  float o[4];
  o[0] = d0 * inv * gv.x + bv.x;
  o[1] = d1 * inv * gv.y + bv.y;
  o[2] = d2 * inv * gv.z + bv.z;
  o[3] = d3 * inv * gv.w + bv.w;
  *(float4*)(x + (size_t)row * DMODEL + t * 4) = make_float4(o[0], o[1], o[2], o[3]);
  ushort_t hv[4];
  #pragma unroll
  for (int j = 0; j < 4; ++j) hv[j] = f2bf(o[j]);
  *(ushort4*)(xh + (size_t)row * DMODEL + t * 4) = make_ushort4(hv[0], hv[1], hv[2], hv[3]);
}

// ---------------------------------------------------------------------------
// x = layernorm(x + sum_{z<4} parts[z] + bias) * g + b, fused bf16 hi split.
// ---------------------------------------------------------------------------
__global__ __launch_bounds__(256)
void resid_ln_red(float* __restrict__ x, const float* __restrict__ parts,
                  long pstride, const float* __restrict__ bias,
                  const float* __restrict__ g, const float* __restrict__ b,
                  ushort_t* __restrict__ xh)
{
  __shared__ float sm[4];
  int row = blockIdx.x, t = threadIdx.x;
  size_t base = (size_t)row * DMODEL + t * 4;
  float4 xv = *(const float4*)(x + base);
  float4 bb = *(const float4*)(bias + t * 4);
  float a0 = xv.x + bb.x, a1 = xv.y + bb.y, a2 = xv.z + bb.z, a3 = xv.w + bb.w;
  #pragma unroll
  for (int z = 0; z < 4; ++z) {
    float4 pv = *(const float4*)(parts + (size_t)z * pstride + base);
    a0 += pv.x; a1 += pv.y; a2 += pv.z; a3 += pv.w;
  }
  float s = block_sum256(a0 + a1 + a2 + a3, sm);
  float mean = s * (1.0f / DMODEL);
  float d0 = a0 - mean, d1 = a1 - mean, d2 = a2 - mean, d3 = a3 - mean;
  float vs = block_sum256(d0*d0 + d1*d1 + d2*d2 + d3*d3, sm);
  float inv = rsqrtf(vs * (1.0f / DMODEL) + 1e-5f);
  float4 gv = *(const float4*)(g + t * 4);
  float4 bv = *(const float4*)(b + t * 4);
  float o[4];
  o[0] = d0 * inv * gv.x + bv.x;
  o[1] = d1 * inv * gv.y + bv.y;
  o[2] = d2 * inv * gv.z + bv.z;
  o[3] = d3 * inv * gv.w + bv.w;
  *(float4*)(x + base) = make_float4(o[0], o[1], o[2], o[3]);
  ushort_t hv[4];
  #pragma unroll
  for (int j = 0; j < 4; ++j) hv[j] = f2bf(o[j]);
  *(ushort4*)(xh + base) = make_ushort4(hv[0], hv[1], hv[2], hv[3]);
}

// ---------------------------------------------------------------------------
// final scale: out[row] *= 1/sum(row); sum from deterministic partials
// ---------------------------------------------------------------------------
__global__ __launch_bounds__(256)
void scale_softmax(float* __restrict__ out, const float* __restrict__ partials,
                   int ncb)
{
  __shared__ float sm[4];
  int row = blockIdx.x, t = threadIdx.x;
  float s = 0.f;
  for (int cb = t; cb < ncb; cb += 256) s += partials[(size_t)row * NCBP + cb];
  s = block_sum256(s, sm);
  float inv = 1.0f / s;
  float* p = out + (size_t)row * VOCAB;
  int head = (int)((((uintptr_t)16 - ((uintptr_t)p & 15)) & 15) >> 2);
  if (t < head) p[t] *= inv;
  int nvec = (VOCAB - head) >> 2;
  float4* pv = (float4*)(p + head);
  for (int i = t; i < nvec; i += 256) {
    float4 v = pv[i];
    v.x *= inv; v.y *= inv; v.z *= inv; v.w *= inv;
    pv[i] = v;
  }
  int done = head + nvec * 4;
  if (t < VOCAB - done) p[done + t] *= inv;
}

// ---------------------------------------------------------------------------
extern "C" void kernel_launch(void* const* d_in, const int* in_sizes, int n_in,
                              void* d_out, int out_size, void* d_ws, size_t ws_size,
                              hipStream_t stream)
{
  const int*   tokens = (const int*)  d_in[0];
  const float* emb    = (const float*)d_in[1];
  const float* Wq     = (const float*)d_in[2];
  const float* bq     = (const float*)d_in[3];
  const float* Wk     = (const float*)d_in[4];
  const float* bk     = (const float*)d_in[5];
  const float* Wv     = (const float*)d_in[6];
  const float* bv     = (const float*)d_in[7];
  const float* ln1g   = (const float*)d_in[8];
  const float* ln1b   = (const float*)d_in[9];
  const float* W1     = (const float*)d_in[10];
  const float* b1     = (const float*)d_in[11];
  const float* W2     = (const float*)d_in[12];
  const float* b2     = (const float*)d_in[13];
  const float* ln2g   = (const float*)d_in[14];
  const float* ln2b   = (const float*)d_in[15];
  const float* Wout   = (const float*)d_in[16];
  const float* bout   = (const float*)d_in[17];

  // workspace: xh 0-8; logits phase stripH 8-16; partials 24-30.55
  char* wsb = (char*)d_ws;
  ushort_t* xh     = (ushort_t*)(wsb);
  ushort_t* stripH = (ushort_t*)(wsb + ((size_t)8  << 20));
  float*    partials = (float*)(wsb + ((size_t)24 << 20)); // [4096][NCBP] f32

  // scratch in d_out (823 MB; all dead before the logits GEMM writes it)
  char* ob = (char*)d_out;
  float*    x     = (float*)(ob);                          // [S][D] f32 16MB
  float*    yb    = (float*)(ob + ((size_t)16  << 20));    // [S][D] f32 16MB
  ushort_t* qh    = (ushort_t*)(ob + ((size_t)32  << 20)); // [H][S][64] 8MB
  ushort_t* ql    = (ushort_t*)(ob + ((size_t)40  << 20));
  ushort_t* kh    = (ushort_t*)(ob + ((size_t)48  << 20));
  ushort_t* vb16  = (ushort_t*)(ob + ((size_t)56  << 20));
  ushort_t* vt    = (ushort_t*)(ob + ((size_t)64  << 20)); // [H][64][S] 8MB
  ushort_t* h1h   = (ushort_t*)(ob + ((size_t)72  << 20)); // [S][DFF] bf16 32MB
  float*    fparts= (float*)(ob + ((size_t)104 << 20));    // [4][S][D] f32 64MB
  ushort_t* wqkvhA= (ushort_t*)(ob + ((size_t)168 << 20)); // [L][3072][1024] 24MB
  ushort_t* wqkvlA= (ushort_t*)(ob + ((size_t)192 << 20));
  ushort_t* w1hA  = (ushort_t*)(ob + ((size_t)216 << 20)); // [L][4096][1024] 32MB
  ushort_t* w1lA  = (ushort_t*)(ob + ((size_t)248 << 20));
  ushort_t* w2hA  = (ushort_t*)(ob + ((size_t)280 << 20)); // [L][1024][4096] 32MB
  ushort_t* w2lA  = (ushort_t*)(ob + ((size_t)312 << 20));
  float*    bqkvA = (float*)(ob + ((size_t)344 << 20));    // [L][3072] f32
  float*    outf  = (float*)d_out;

  const long WQKV_L = 3072L * 1024;   // shorts per layer
  const long WFF_L  = 4096L * 1024;

  embed_kernel<<<S_LEN, 256, 0, stream>>>(tokens, emb, x, xh);

  // ---- hoisted weight prep (activation-independent) ----
  // Wq/Wk/Wv: [L][H][D][DH] -> per-layer [3072][1024]; z = l*16+h
  transpose_split<<<dim3(16, 1, 64), 256, 0, stream>>>(
      Wq, wqkvhA, wqkvlA,
      (long)DMODEL * DHEAD, (long)DHEAD * DMODEL,
      (long)NHEAD * DMODEL * DHEAD, WQKV_L,
      16, DHEAD, DMODEL, DHEAD);
  transpose_split<<<dim3(16, 1, 64), 256, 0, stream>>>(
      Wk, wqkvhA + 1024 * 1024, wqkvlA + 1024 * 1024,
      (long)DMODEL * DHEAD, (long)DHEAD * DMODEL,
      (long)NHEAD * DMODEL * DHEAD, WQKV_L,
      16, DHEAD, DMODEL, DHEAD);
  transpose_split<<<dim3(16, 1, 64), 256, 0, stream>>>(
      Wv, wqkvhA + 2048 * 1024, wqkvlA + 2048 * 1024,
      (long)DMODEL * DHEAD, (long)DHEAD * DMODEL,
      (long)NHEAD * DMODEL * DHEAD, WQKV_L,
      16, DHEAD, DMODEL, DHEAD);
  // W1: [L][D][DFF] -> [L][4096][1024]; z = layer
  transpose_split<<<dim3(16, 64, 4), 256, 0, stream>>>(
      W1, w1hA, w1lA, 0, 0,
      (long)DMODEL * DFF, WFF_L, 1, DFF, DMODEL, DFF);
  // W2: [L][DFF][D] -> [L][1024][4096]; z = layer
  transpose_split<<<dim3(64, 16, 4), 256, 0, stream>>>(
      W2, w2hA, w2lA, 0, 0,
      (long)DFF * DMODEL, WFF_L, 1, DMODEL, DFF, DMODEL);
  concat3_kernel<<<dim3(4, NLAYER), 256, 0, stream>>>(
      bq, bk, bv, bqkvA, 1024, 1024, 3072);

  for (int l = 0; l < NLAYER; ++l) {
    const ushort_t* wqh = wqkvhA + (long)l * WQKV_L;
    const ushort_t* wql = wqkvlA + (long)l * WQKV_L;
    const ushort_t* w1h = w1hA + (long)l * WFF_L;
    const ushort_t* w1l = w1lA + (long)l * WFF_L;
    const ushort_t* w2h = w2hA + (long)l * WFF_L;
    const ushort_t* w2l = w2lA + (long)l * WFF_L;

    // fused QKV projection: 2-prod, grid 16x12
    gemm8p<2, false><<<dim3(16, 12), 512, 0, stream>>>(
        xh, wqh, wql, bqkvA + (long)l * 3072, nullptr,
        qh, ql, kh, vb16, 1024, 1024, 0, 0);
    transpose_v<<<dim3(64, 16), 256, 0, stream>>>(vb16, vt);

    attn_mfma<<<dim3(32, 16), 256, 0, stream>>>(qh, ql, kh, vt, yb);

    resid_ln_kernel<<<S_LEN, 256, 0, stream>>>(x, yb,
        ln1g + (size_t)l * DMODEL, ln1b + (size_t)l * DMODEL, xh);

    // FFN1: 2-prod, grid 16x16, bf16-hi output
    gemm8p<1, true><<<dim3(16, 16), 512, 0, stream>>>(
        xh, w1h, w1l, b1 + (long)l * DFF, nullptr,
        h1h, nullptr, nullptr, nullptr, 1024, 1024, 4096, 0);
    // FFN2: 2-prod split-K x4 (grid 16x4x4), f32 partials
    gemm8p<0, false><<<dim3(16, 4, 4), 512, 0, stream>>>(
        h1h, w2h, w2l, nullptr, fparts,
        nullptr, nullptr, nullptr, nullptr,
        1024, 4096, 1024, (long)S_LEN * DMODEL);
    resid_ln_red<<<S_LEN, 256, 0, stream>>>(x, fparts, (long)S_LEN * DMODEL,
        b2 + (long)l * DMODEL,
        ln2g + (size_t)l * DMODEL, ln2b + (size_t)l * DMODEL, xh);
  }

  // logits: 4096-col strips, 1-product kernel, exp+partials epilogue
  const int SW = 4096;
  for (int is = 0; is < 12; ++is) {
    int n0 = is * SW;
    transpose_h<<<dim3(16, 64, 1), 256, 0, stream>>>(
        Wout + n0, stripH, VOCAB, DMODEL, SW);
    gemm1p<false><<<dim3(16, 16), 512, 0, stream>>>(
        xh, stripH, bout + n0, outf + n0,
        1024, 1024, VOCAB, SW, partials, is * 16);
  }
  {
    int n0 = 12 * SW;                       // 49152
    int ncols = VOCAB - n0;                 // 1105
    int nt64 = (ncols + 63) / 64;           // 18
    int nb256 = (ncols + 255) / 256;        // 5
    transpose_h<<<dim3(16, nt64, 1), 256, 0, stream>>>(
        Wout + n0, stripH, VOCAB, DMODEL, ncols);
    gemm1p<true><<<dim3(16, nb256), 512, 0, stream>>>(
        xh, stripH, bout + n0, outf + n0,
        1024, 1024, VOCAB, ncols, partials, 12 * 16);
  }
  const int ncb = (VOCAB + 255) / 256;      // 197
  scale_softmax<<<S_LEN, 256, 0, stream>>>(outf, partials, ncb);
}

// Round 10
// 3703.969 us; speedup vs baseline: 4.2411x; 1.0313x over previous
//
#include <hip/hip_runtime.h>
#include <math.h>

#define S_LEN  4096
#define DMODEL 1024
#define NHEAD  16
#define DHEAD  64
#define DFF    4096
#define NLAYER 4
#define VOCAB  50257
#define NCBP   400   // partials row stride (col-blocks of 256, padded)

typedef unsigned short ushort_t;
typedef __attribute__((ext_vector_type(8))) __bf16 bf16x8;
typedef __attribute__((ext_vector_type(4))) float f32x4;

static __device__ __forceinline__ ushort_t f2bf(float f) {
  union { float f; unsigned u; } x; x.f = f;
  unsigned r = x.u + 0x7fffu + ((x.u >> 16) & 1u);
  return (ushort_t)(r >> 16);
}
static __device__ __forceinline__ float bf2f(ushort_t h) {
  union { unsigned u; float f; } x; x.u = ((unsigned)h) << 16;
  return x.f;
}
// 2^x via v_exp_f32 (avoid __exp2f: collides with glibc math.h macros)
static __device__ __forceinline__ float exp2fast(float x) {
  return __builtin_amdgcn_exp2f(x);
}

#define GLOAD_LDS16(gp, lp) \
  __builtin_amdgcn_global_load_lds((const __attribute__((address_space(1))) void*)(gp), \
                                   (__attribute__((address_space(3))) void*)(lp), 16, 0, 0)

// q pre-scale: 1/sqrt(64) * log2(e)  (softmax runs in exp2 domain)
#define QSCALE 0.18033688011112042f

// ---------------------------------------------------------------------------
// embedding + sinusoidal positional encoding, fused bf16 split (hi only)
// ---------------------------------------------------------------------------
__global__ __launch_bounds__(256) void embed_kernel(
    const int* __restrict__ tokens, const float* __restrict__ emb,
    float* __restrict__ x, ushort_t* __restrict__ xh)
{
  int s = blockIdx.x;
  int tok = tokens[s];
  int d0 = threadIdx.x * 4;
  const double lf = 0.01798894603901598653; // log(10000)/512
  float4 ev = *(const float4*)(emb + (size_t)tok * DMODEL + d0);
  float o[4]; float evr[4] = {ev.x, ev.y, ev.z, ev.w};
  #pragma unroll
  for (int j = 0; j < 4; ++j) {
    int d = d0 + j;
    int i = (d < 512) ? d : d - 512;
    double ang = (double)s * exp(-lf * (double)i);
    float pe = (d < 512) ? (float)sin(ang) : (float)cos(ang);
    o[j] = evr[j] + pe;
  }
  *(float4*)(x + (size_t)s * DMODEL + d0) = make_float4(o[0], o[1], o[2], o[3]);
  ushort_t hv[4];
  #pragma unroll
  for (int j = 0; j < 4; ++j) hv[j] = f2bf(o[j]);
  *(ushort4*)(xh + (size_t)s * DMODEL + d0) = make_ushort4(hv[0], hv[1], hv[2], hv[3]);
}

// ---------------------------------------------------------------------------
// transpose + split: in f32 [K][N] (row stride in_rstride) -> out bf16 hi/lo
// [N][Kout] K-contiguous. Two-level z batching: z1 = z % zdiv, z2 = z / zdiv.
// ---------------------------------------------------------------------------
__global__ __launch_bounds__(256)
void transpose_split(const float* __restrict__ in, ushort_t* __restrict__ oh,
                     ushort_t* __restrict__ ol,
                     long in_zstr, long out_zoff, long in_z2str, long out_z2off,
                     int zdiv, int in_rstride, int Kout, int Nvalid)
{
  __shared__ float tile[64][65];
  int z1 = blockIdx.z % zdiv, z2 = blockIdx.z / zdiv;
  long ioff = (long)z1 * in_zstr + (long)z2 * in_z2str;
  long ooff = (long)z1 * out_zoff + (long)z2 * out_z2off;
  const float* inz = in + ioff;
  ushort_t* ohz = oh + ooff;
  ushort_t* olz = ol + ooff;
  int k0 = blockIdx.x * 64, n0 = blockIdx.y * 64;
  int t = threadIdx.x;
  #pragma unroll
  for (int i = 0; i < 4; ++i) {
    int idx = t + i * 256;            // 0..1023
    int kk = idx >> 4, c4 = idx & 15;
    #pragma unroll
    for (int j = 0; j < 4; ++j) {
      int n = n0 + c4 * 4 + j;
      float v = (n < Nvalid) ? inz[(long)(k0 + kk) * in_rstride + n] : 0.f;
      tile[c4 * 4 + j][kk] = v;       // transposed into LDS
    }
  }
  __syncthreads();
  #pragma unroll
  for (int i = 0; i < 4; ++i) {
    int idx = t + i * 256;
    int nn = idx >> 4, k4 = idx & 15;
    ushort_t hv[4], lv[4];
    #pragma unroll
    for (int j = 0; j < 4; ++j) {
      float v = tile[nn][k4 * 4 + j];
      hv[j] = f2bf(v);
      lv[j] = f2bf(v - bf2f(hv[j]));
    }
    long ob = (long)(n0 + nn) * Kout + k0 + k4 * 4;
    *(ushort4*)(ohz + ob) = make_ushort4(hv[0], hv[1], hv[2], hv[3]);
    *(ushort4*)(olz + ob) = make_ushort4(lv[0], lv[1], lv[2], lv[3]);
  }
}

// hi-only variant (for the 1-product logits GEMM)
__global__ __launch_bounds__(256)
void transpose_h(const float* __restrict__ in, ushort_t* __restrict__ oh,
                 int in_rstride, int Kout, int Nvalid)
{
  __shared__ float tile[64][65];
  int k0 = blockIdx.x * 64, n0 = blockIdx.y * 64;
  int t = threadIdx.x;
  #pragma unroll
  for (int i = 0; i < 4; ++i) {
    int idx = t + i * 256;
    int kk = idx >> 4, c4 = idx & 15;
    #pragma unroll
    for (int j = 0; j < 4; ++j) {
      int n = n0 + c4 * 4 + j;
      float v = (n < Nvalid) ? in[(long)(k0 + kk) * in_rstride + n] : 0.f;
      tile[c4 * 4 + j][kk] = v;
    }
  }
  __syncthreads();
  #pragma unroll
  for (int i = 0; i < 4; ++i) {
    int idx = t + i * 256;
    int nn = idx >> 4, k4 = idx & 15;
    ushort_t hv[4];
    #pragma unroll
    for (int j = 0; j < 4; ++j) hv[j] = f2bf(tile[nn][k4 * 4 + j]);
    long ob = (long)(n0 + nn) * Kout + k0 + k4 * 4;
    *(ushort4*)(oh + ob) = make_ushort4(hv[0], hv[1], hv[2], hv[3]);
  }
}

// ---------------------------------------------------------------------------
// concat 3 bias vectors of length n into [3n], batched over layers (y)
// ---------------------------------------------------------------------------
__global__ __launch_bounds__(256)
void concat3_kernel(const float* __restrict__ a, const float* __restrict__ b,
                    const float* __restrict__ c, float* __restrict__ o,
                    int n, long lstrA, long lstrO)
{
  int i = blockIdx.x * 256 + threadIdx.x;
  long l = blockIdx.y;
  if (i < n) {
    o[l * lstrO + i]         = a[l * lstrA + i];
    o[l * lstrO + n + i]     = b[l * lstrA + i];
    o[l * lstrO + 2 * n + i] = c[l * lstrA + i];
  }
}

// ---------------------------------------------------------------------------
// 256x256-tile 8-wave GEMM, counted-vmcnt phase pipeline, 2-product split:
// C = Ah @ (Bh + Bl)^T. Streams Ah|Bh|Bl, double-buffered (96 KB LDS).
// EPI: 0 = raw f32 partial (split-K via blockIdx.z), 1 = bf16 hi C (+bias,
// RELU), 2 = QKV routing (q scaled hi/lo, k hi, v -> transposed [H][64][S]).
// ---------------------------------------------------------------------------
template<int EPI, bool RELU>
__global__ __launch_bounds__(512, 2)
void gemm8p(const ushort_t* __restrict__ Ah,
            const ushort_t* __restrict__ Bh, const ushort_t* __restrict__ Bl,
            const float* __restrict__ bias, float* __restrict__ C,
            ushort_t* __restrict__ O0, ushort_t* __restrict__ O1,
            ushort_t* __restrict__ O2, ushort_t* __restrict__ O4,
            int K, int ldk, long ldc, long czStride)
{
  constexpr int BUFSTR = 3 * 8192;              // Ah | Bh | Bl
  constexpr int OBH = 8192, OBL = 16384;
  __shared__ ushort_t lds[2 * BUFSTR];          // 96 KB

  const int t = threadIdx.x;
  const int l = t & 63;
  const int w = t >> 6;            // 0..7
  const int wr = w >> 2;           // 0..1  (row half)
  const int wc = w & 3;            // 0..3  (col quarter)
  const int lrow = l & 15;
  const int lk = (l >> 4) * 8;
  const int l8 = l * 8;
  const long m0 = (long)blockIdx.x * 256;
  const long n0 = (long)blockIdx.y * 256;
  const long kz = (long)blockIdx.z * K;

  const ushort_t *agp[2], *bgp[2], *blgp[2];
  int dst[2];
  #pragma unroll
  for (int i = 0; i < 2; ++i) {
    int s = i * 8 + w;                       // subtile 0..15
    dst[i] = s * 512 + l8;
    agp[i]  = Ah + (m0 + s * 16 + lrow) * (long)ldk + kz + lk;
    bgp[i]  = Bh + (n0 + s * 16 + lrow) * (long)ldk + kz + lk;
    blgp[i] = Bl + (n0 + s * 16 + lrow) * (long)ldk + kz + lk;
  }

  f32x4 acc[8][4];
  #pragma unroll
  for (int m = 0; m < 8; ++m)
    #pragma unroll
    for (int n = 0; n < 4; ++n) acc[m][n] = (f32x4)0.f;

  // prologue: stage tile 0, canonical per-tile order
  GLOAD_LDS16(agp[0],  &lds[dst[0]]);
  GLOAD_LDS16(agp[1],  &lds[dst[1]]);
  GLOAD_LDS16(bgp[0],  &lds[OBH + dst[0]]);
  GLOAD_LDS16(bgp[1],  &lds[OBH + dst[1]]);
  GLOAD_LDS16(blgp[0], &lds[OBL + dst[0]]);
  GLOAD_LDS16(blgp[1], &lds[OBL + dst[1]]);

  const int nk = K >> 5;
  int cur = 0;
  for (int kt = 0; kt < nk; ++kt) {
    const int knx = (kt + 1 < nk) ? (kt + 1) * 32 : 0;  // last iter: harmless reload
    ushort_t* cb = &lds[cur * BUFSTR];
    ushort_t* nb = &lds[(cur ^ 1) * BUFSTR];
    bf16x8 af[8], bhf[4], blf[4];

    // ---------- P0: needs Ah,Bh of tile kt ----------
    asm volatile("s_waitcnt vmcnt(2)" ::: "memory");
    __builtin_amdgcn_sched_barrier(0);
    __builtin_amdgcn_s_barrier();
    __builtin_amdgcn_sched_barrier(0);
    #pragma unroll
    for (int m = 0; m < 8; ++m)
      af[m] = *(const bf16x8*)&cb[(wr * 8 + m) * 512 + l8];
    #pragma unroll
    for (int n = 0; n < 4; ++n)
      bhf[n] = *(const bf16x8*)&cb[OBH + (wc * 4 + n) * 512 + l8];
    GLOAD_LDS16(agp[0] + knx, &nb[dst[0]]);
    GLOAD_LDS16(agp[1] + knx, &nb[dst[1]]);
    GLOAD_LDS16(bgp[0] + knx, &nb[OBH + dst[0]]);
    __builtin_amdgcn_s_setprio(1);
    #pragma unroll
    for (int m = 0; m < 8; ++m)
      #pragma unroll
      for (int n = 0; n < 4; ++n)
        acc[m][n] = __builtin_amdgcn_mfma_f32_16x16x32_bf16(af[m], bhf[n], acc[m][n], 0, 0, 0);
    __builtin_amdgcn_s_setprio(0);
    __builtin_amdgcn_sched_barrier(0);

    // ---------- P1: needs Bl of tile kt ----------
    asm volatile("s_waitcnt vmcnt(3)" ::: "memory");
    __builtin_amdgcn_sched_barrier(0);
    __builtin_amdgcn_s_barrier();
    __builtin_amdgcn_sched_barrier(0);
    #pragma unroll
    for (int n = 0; n < 4; ++n)
      blf[n] = *(const bf16x8*)&cb[OBL + (wc * 4 + n) * 512 + l8];
    GLOAD_LDS16(bgp[1] + knx,  &nb[OBH + dst[1]]);
    GLOAD_LDS16(blgp[0] + knx, &nb[OBL + dst[0]]);
    GLOAD_LDS16(blgp[1] + knx, &nb[OBL + dst[1]]);
    __builtin_amdgcn_s_setprio(1);
    #pragma unroll
    for (int m = 0; m < 8; ++m)
      #pragma unroll
      for (int n = 0; n < 4; ++n)
        acc[m][n] = __builtin_amdgcn_mfma_f32_16x16x32_bf16(af[m], blf[n], acc[m][n], 0, 0, 0);
    __builtin_amdgcn_s_setprio(0);
    __builtin_amdgcn_sched_barrier(0);
    cur ^= 1;
  }
  asm volatile("s_waitcnt vmcnt(0)" ::: "memory");

  // ---------------- epilogue ----------------
  if constexpr (EPI == 2) {
    #pragma unroll
    for (int n = 0; n < 4; ++n) {
      long col = n0 + wc * 64 + n * 16 + lrow;
      float bv = bias[col];
      #pragma unroll
      for (int m = 0; m < 8; ++m) {
        #pragma unroll
        for (int r = 0; r < 4; ++r) {
          long row = m0 + wr * 128 + m * 16 + (l >> 4) * 4 + r;
          float v = acc[m][n][r] + bv;
          int c = (int)col;
          if (c < 1024) {
            int hh = c >> 6, e = c & 63;
            float qv = v * QSCALE;            // fold 1/sqrt(DH)*log2e
            ushort_t hi = f2bf(qv);
            size_t a = ((size_t)hh * S_LEN + row) * 64 + e;
            O0[a] = hi; O1[a] = f2bf(qv - bf2f(hi));
          } else if (c < 2048) {
            int cc = c - 1024;
            int hh = cc >> 6, e = cc & 63;
            size_t a = ((size_t)hh * S_LEN + row) * 64 + e;
            O2[a] = f2bf(v);
          } else {
            // V: write transposed directly -> vt[h][e][row]
            int cc = c - 2048;
            int hh = cc >> 6, e = cc & 63;
            size_t a = ((size_t)hh * DHEAD + e) * S_LEN + row;
            O4[a] = f2bf(v);
          }
        }
      }
    }
  } else if constexpr (EPI == 1) {
    #pragma unroll
    for (int n = 0; n < 4; ++n) {
      long col = n0 + wc * 64 + n * 16 + lrow;
      float bv = bias[col];
      #pragma unroll
      for (int m = 0; m < 8; ++m) {
        #pragma unroll
        for (int r = 0; r < 4; ++r) {
          long row = m0 + wr * 128 + m * 16 + (l >> 4) * 4 + r;
          float v = acc[m][n][r] + bv;
          if (RELU) v = fmaxf(v, 0.f);
          O0[row * ldc + col] = f2bf(v);
        }
      }
    }
  } else {  // EPI == 0: raw f32 partial (split-K), no bias
    float* Cz = C + (long)blockIdx.z * czStride;
    #pragma unroll
    for (int n = 0; n < 4; ++n) {
      long col = n0 + wc * 64 + n * 16 + lrow;
      #pragma unroll
      for (int m = 0; m < 8; ++m) {
        #pragma unroll
        for (int r = 0; r < 4; ++r) {
          long row = m0 + wr * 128 + m * 16 + (l >> 4) * 4 + r;
          Cz[row * ldc + col] = acc[m][n][r];
        }
      }
    }
  }
}

// ---------------------------------------------------------------------------
// 1-product 256x256 GEMM (logits): C = exp(Ah@Bh^T + bias), per-row partials.
// 2 streams, 2-tile-deep prefetch, vmcnt(4) counted waits, 32 MFMA/K-step.
// ---------------------------------------------------------------------------
template<bool BOUND>
__global__ __launch_bounds__(512, 2)
void gemm1p(const ushort_t* __restrict__ Ah, const ushort_t* __restrict__ Bh,
            const float* __restrict__ bias, float* __restrict__ C,
            int K, int ldk, long ldc, int Nlimit,
            float* __restrict__ Ppart, int cbbase)
{
  constexpr int OB = 8192;
  constexpr int BUFSTR = 16384;
  __shared__ ushort_t lds[2 * BUFSTR];
  __shared__ float psum[1024];

  const int t = threadIdx.x;
  const int l = t & 63;
  const int w = t >> 6;
  const int wr = w >> 2;
  const int wc = w & 3;
  const int lrow = l & 15;
  const int lk = (l >> 4) * 8;
  const int l8 = l * 8;
  const long m0 = (long)blockIdx.x * 256;
  const long n0 = (long)blockIdx.y * 256;

  const ushort_t *agp[2], *bgp[2];
  int dst[2];
  #pragma unroll
  for (int i = 0; i < 2; ++i) {
    int s = i * 8 + w;
    dst[i] = s * 512 + l8;
    agp[i] = Ah + (m0 + s * 16 + lrow) * (long)ldk + lk;
    bgp[i] = Bh + (n0 + s * 16 + lrow) * (long)ldk + lk;
  }

  f32x4 acc[8][4];
  #pragma unroll
  for (int m = 0; m < 8; ++m)
    #pragma unroll
    for (int n = 0; n < 4; ++n) acc[m][n] = (f32x4)0.f;

  // prologue: tiles 0 and 1 (8 loads outstanding)
  GLOAD_LDS16(agp[0], &lds[dst[0]]);
  GLOAD_LDS16(agp[1], &lds[dst[1]]);
  GLOAD_LDS16(bgp[0], &lds[OB + dst[0]]);
  GLOAD_LDS16(bgp[1], &lds[OB + dst[1]]);
  GLOAD_LDS16(agp[0] + 32, &lds[BUFSTR + dst[0]]);
  GLOAD_LDS16(agp[1] + 32, &lds[BUFSTR + dst[1]]);
  GLOAD_LDS16(bgp[0] + 32, &lds[BUFSTR + OB + dst[0]]);
  GLOAD_LDS16(bgp[1] + 32, &lds[BUFSTR + OB + dst[1]]);

  const int nk = K >> 5;
  int cur = 0;
  for (int kt = 0; kt < nk; ++kt) {
    ushort_t* cb = &lds[cur * BUFSTR];
    bf16x8 af[8], bhf[4];

    asm volatile("s_waitcnt vmcnt(4)" ::: "memory");
    __builtin_amdgcn_sched_barrier(0);
    __builtin_amdgcn_s_barrier();
    __builtin_amdgcn_sched_barrier(0);
    #pragma unroll
    for (int m = 0; m < 8; ++m)
      af[m] = *(const bf16x8*)&cb[(wr * 8 + m) * 512 + l8];
    #pragma unroll
    for (int n = 0; n < 4; ++n)
      bhf[n] = *(const bf16x8*)&cb[OB + (wc * 4 + n) * 512 + l8];
    __builtin_amdgcn_sched_barrier(0);
    asm volatile("s_waitcnt lgkmcnt(0)" ::: "memory");
    __builtin_amdgcn_sched_barrier(0);
    __builtin_amdgcn_s_barrier();      // all waves done reading cb
    __builtin_amdgcn_sched_barrier(0);
    const int knx2 = (kt + 2 < nk) ? (kt + 2) * 32 : 0;  // tail: harmless refill
    GLOAD_LDS16(agp[0] + knx2, &cb[dst[0]]);
    GLOAD_LDS16(agp[1] + knx2, &cb[dst[1]]);
    GLOAD_LDS16(bgp[0] + knx2, &cb[OB + dst[0]]);
    GLOAD_LDS16(bgp[1] + knx2, &cb[OB + dst[1]]);
    __builtin_amdgcn_s_setprio(1);
    #pragma unroll
    for (int m = 0; m < 8; ++m)
      #pragma unroll
      for (int n = 0; n < 4; ++n)
        acc[m][n] = __builtin_amdgcn_mfma_f32_16x16x32_bf16(af[m], bhf[n], acc[m][n], 0, 0, 0);
    __builtin_amdgcn_s_setprio(0);
    __builtin_amdgcn_sched_barrier(0);
    cur ^= 1;
  }
  asm volatile("s_waitcnt vmcnt(0)" ::: "memory");

  // epilogue: exp(logit) + deterministic per-row partial sums
  float smr[8][4];
  #pragma unroll
  for (int m = 0; m < 8; ++m)
    #pragma unroll
    for (int r = 0; r < 4; ++r) smr[m][r] = 0.f;
  #pragma unroll
  for (int n = 0; n < 4; ++n) {
    long col = n0 + wc * 64 + n * 16 + lrow;
    bool cok = (!BOUND) || (col < (long)Nlimit);
    float bv = cok ? bias[col] : 0.f;
    #pragma unroll
    for (int m = 0; m < 8; ++m) {
      #pragma unroll
      for (int r = 0; r < 4; ++r) {
        long row = m0 + wr * 128 + m * 16 + (l >> 4) * 4 + r;
        float e = cok ? __expf(acc[m][n][r] + bv) : 0.f;
        if (cok) C[row * ldc + col] = e;
        smr[m][r] += e;
      }
    }
  }
  #pragma unroll
  for (int m = 0; m < 8; ++m) {
    #pragma unroll
    for (int r = 0; r < 4; ++r) {
      float s = smr[m][r];
      s += __shfl_xor(s, 1);
      s += __shfl_xor(s, 2);
      s += __shfl_xor(s, 4);
      s += __shfl_xor(s, 8);
      if (lrow == 0)
        psum[wc * 256 + wr * 128 + m * 16 + (l >> 4) * 4 + r] = s;
    }
  }
  __syncthreads();
  if (t < 256) {
    float s = psum[t] + psum[256 + t] + psum[512 + t] + psum[768 + t];
    Ppart[(m0 + t) * NCBP + cbbase + blockIdx.y] = s;
  }
}

// ---------------------------------------------------------------------------
// MFMA flash attention v3. qh/ql: [H][S][64] bf16 (pre-scaled by QSCALE),
// kh: [H][S][64] bf16, vt: [H][64][S] bf16. y: [S][1024] f32.
// 2-product QK^T; exp2-domain softmax; defer-rescale vote; K/V double-buffer
// with next-tile loads issued a full compute-phase early (1 barrier/tile).
// ---------------------------------------------------------------------------
__global__ __launch_bounds__(256)
void attn_mfma(const ushort_t* __restrict__ qh, const ushort_t* __restrict__ ql,
               const ushort_t* __restrict__ kh, const ushort_t* __restrict__ vt,
               float* __restrict__ y)
{
  __shared__ ushort_t lds[24576];  // buf0 K|V [8192], buf1 K|V [8192], P [4][2048]

  const int t = threadIdx.x, l = t & 63, w = t >> 6;
  const int lrow = l & 15, lhi = l >> 4;
  const int h = blockIdx.y;
  const int bw = blockIdx.x * 128 + w * 32;
  const size_t hS = (size_t)h * S_LEN * DHEAD;
  const size_t hV = (size_t)h * DHEAD * S_LEN;
  const int pb = 16384 + w * 2048;

  bf16x8 qhf[2][2], qlf[2][2];
  #pragma unroll
  for (int m = 0; m < 2; ++m)
    #pragma unroll
    for (int ks = 0; ks < 2; ++ks) {
      size_t a = hS + (size_t)(bw + m * 16 + lrow) * 64 + ks * 32 + lhi * 8;
      qhf[m][ks] = *(const bf16x8*)(qh + a);
      qlf[m][ks] = *(const bf16x8*)(ql + a);
    }

  f32x4 acc[2][4];
  #pragma unroll
  for (int m = 0; m < 2; ++m)
    #pragma unroll
    for (int n = 0; n < 4; ++n) acc[m][n] = (f32x4)0.f;
  float mrow[8], lsum[8];
  #pragma unroll
  for (int i = 0; i < 8; ++i) { mrow[i] = -1e30f; lsum[i] = 0.f; }

  // prologue: stage tile 0 into buf 0
  #pragma unroll
  for (int i = 0; i < 2; ++i) {
    int s = i * 4 + w;
    size_t krow = (size_t)((s >> 1) * 16 + lrow);
    int koff = (s & 1) * 32 + lhi * 8;
    GLOAD_LDS16(kh + hS + krow * 64 + koff, &lds[s * 512 + l * 8]);
    int toff = (s & 1) * 32 + lhi * 8;
    GLOAD_LDS16(vt + hV + krow * S_LEN + toff, &lds[4096 + s * 512 + l * 8]);
  }

  int cur = 0;
  for (int kt = 0; kt < S_LEN; kt += 64) {
    asm volatile("s_waitcnt vmcnt(0)" ::: "memory");
    __builtin_amdgcn_sched_barrier(0);
    __builtin_amdgcn_s_barrier();
    __builtin_amdgcn_sched_barrier(0);
    ushort_t* cb = &lds[cur * 8192];
    // issue next-tile loads into the other buffer (hidden under compute)
    if (kt + 64 < S_LEN) {
      ushort_t* nb = &lds[(cur ^ 1) * 8192];
      int kn = kt + 64;
      #pragma unroll
      for (int i = 0; i < 2; ++i) {
        int s = i * 4 + w;
        size_t krow = (size_t)(kn + (s >> 1) * 16 + lrow);
        int koff = (s & 1) * 32 + lhi * 8;
        GLOAD_LDS16(kh + hS + krow * 64 + koff, &nb[s * 512 + l * 8]);
        size_t erow = (size_t)((s >> 1) * 16 + lrow);
        int toff = kn + (s & 1) * 32 + lhi * 8;
        GLOAD_LDS16(vt + hV + erow * S_LEN + toff, &nb[4096 + s * 512 + l * 8]);
      }
    }

    // scores (exp2 domain), 2-product: (qh + ql) * kh
    f32x4 sacc[2][4];
    #pragma unroll
    for (int m = 0; m < 2; ++m)
      #pragma unroll
      for (int n = 0; n < 4; ++n) sacc[m][n] = (f32x4)0.f;
    #pragma unroll
    for (int ks = 0; ks < 2; ++ks) {
      bf16x8 bh_[4];
      #pragma unroll
      for (int n = 0; n < 4; ++n)
        bh_[n] = *(const bf16x8*)&cb[(n * 2 + ks) * 512 + l * 8];
      #pragma unroll
      for (int m = 0; m < 2; ++m)
        #pragma unroll
        for (int n = 0; n < 4; ++n) {
          sacc[m][n] = __builtin_amdgcn_mfma_f32_16x16x32_bf16(qhf[m][ks], bh_[n], sacc[m][n], 0, 0, 0);
          sacc[m][n] = __builtin_amdgcn_mfma_f32_16x16x32_bf16(qlf[m][ks], bh_[n], sacc[m][n], 0, 0, 0);
        }
    }

    // tile maxes + wave vote (defer rescale when no row's max grew)
    float tmv[2][4];
    bool up = false;
    #pragma unroll
    for (int m = 0; m < 2; ++m) {
      #pragma unroll
      for (int r = 0; r < 4; ++r) {
        float tm = fmaxf(fmaxf(sacc[m][0][r], sacc[m][1][r]),
                         fmaxf(sacc[m][2][r], sacc[m][3][r]));
        tm = fmaxf(tm, __shfl_xor(tm, 1));
        tm = fmaxf(tm, __shfl_xor(tm, 2));
        tm = fmaxf(tm, __shfl_xor(tm, 4));
        tm = fmaxf(tm, __shfl_xor(tm, 8));
        tmv[m][r] = tm;
        up = up || (tm > mrow[m * 4 + r]);
      }
    }
    if (__ballot(up) != 0ULL) {
      #pragma unroll
      for (int m = 0; m < 2; ++m) {
        #pragma unroll
        for (int r = 0; r < 4; ++r) {
          const int idx = m * 4 + r;
          float mn = fmaxf(mrow[idx], tmv[m][r]);
          float al = exp2fast(mrow[idx] - mn);
          mrow[idx] = mn;
          lsum[idx] *= al;
          #pragma unroll
          for (int n = 0; n < 4; ++n) acc[m][n][r] *= al;
        }
      }
    }
    #pragma unroll
    for (int m = 0; m < 2; ++m) {
      #pragma unroll
      for (int r = 0; r < 4; ++r) {
        const int idx = m * 4 + r;
        float rs = 0.f;
        #pragma unroll
        for (int n = 0; n < 4; ++n) {
          float p = exp2fast(sacc[m][n][r] - mrow[idx]);
          rs += p;
          int pa = pb + ((m * 2 + (n >> 1)) << 9) + (((n & 1) * 2 + (lrow >> 3)) << 7)
                   + ((lhi * 4 + r) << 3) + (l & 7);
          pa ^= (lrow >> 3) << 3;
          lds[pa] = f2bf(p);
        }
        rs += __shfl_xor(rs, 1);
        rs += __shfl_xor(rs, 2);
        rs += __shfl_xor(rs, 4);
        rs += __shfl_xor(rs, 8);
        lsum[idx] += rs;
      }
    }

    // O += P V
    #pragma unroll
    for (int ks = 0; ks < 2; ++ks) {
      bf16x8 pa_[2];
      #pragma unroll
      for (int m = 0; m < 2; ++m) {
        int ra = pb + ((m * 2 + ks) << 9) + (l << 3);
        ra ^= ((l >> 4) & 1) << 3;
        pa_[m] = *(const bf16x8*)&lds[ra];
      }
      #pragma unroll
      for (int n = 0; n < 4; ++n) {
        bf16x8 vf = *(const bf16x8*)&cb[4096 + (n * 2 + ks) * 512 + l * 8];
        #pragma unroll
        for (int m = 0; m < 2; ++m)
          acc[m][n] = __builtin_amdgcn_mfma_f32_16x16x32_bf16(pa_[m], vf, acc[m][n], 0, 0, 0);
      }
    }
    cur ^= 1;
  }

  #pragma unroll
  for (int m = 0; m < 2; ++m) {
    #pragma unroll
    for (int r = 0; r < 4; ++r) {
      float inv = 1.0f / lsum[m * 4 + r];
      int row = bw + m * 16 + lhi * 4 + r;
      #pragma unroll
      for (int n = 0; n < 4; ++n)
        y[(size_t)row * DMODEL + h * 64 + n * 16 + lrow] = acc[m][n][r] * inv;
    }
  }
}

// ---------------------------------------------------------------------------
__device__ __forceinline__ float block_sum256(float v, float* sm)
{
  #pragma unroll
  for (int off = 32; off >= 1; off >>= 1) v += __shfl_xor(v, off);
  int w = threadIdx.x >> 6;
  if ((threadIdx.x & 63) == 0) sm[w] = v;
  __syncthreads();
  v = sm[0] + sm[1] + sm[2] + sm[3];
  __syncthreads();
  return v;
}

// x = layernorm(x + y) * g + b, fused bf16 (hi only) split of the result
__global__ __launch_bounds__(256)
void resid_ln_kernel(float* __restrict__ x, const float* __restrict__ y,
                     const float* __restrict__ g, const float* __restrict__ b,
                     ushort_t* __restrict__ xh)
{
  __shared__ float sm[4];
  int row = blockIdx.x, t = threadIdx.x;
  float4 xv = *(const float4*)(x + (size_t)row * DMODEL + t * 4);
  float4 yv = *(const float4*)(y + (size_t)row * DMODEL + t * 4);
  float a0 = xv.x + yv.x, a1 = xv.y + yv.y, a2 = xv.z + yv.z, a3 = xv.w + yv.w;
  float s = block_sum256(a0 + a1 + a2 + a3, sm);
  float mean = s * (1.0f / DMODEL);
  float d0 = a0 - mean, d1 = a1 - mean, d2 = a2 - mean, d3 = a3 - mean;
  float vs = block_sum256(d0*d0 + d1*d1 + d2*d2 + d3*d3, sm);
  float inv = rsqrtf(vs * (1.0f / DMODEL) + 1e-5f);
  float4 gv = *(const float4*)(g + t * 4);
  float4 bv = *(const float4*)(b + t * 4);
  float o[4];
  o[0] = d0 * inv * gv.x + bv.x;
  o[1] = d1 * inv * gv.y + bv.y;
  o[2] = d2 * inv * gv.z + bv.z;
  o[3] = d3 * inv * gv.w + bv.w;
  *(float4*)(x + (size_t)row * DMODEL + t * 4) = make_float4(o[0], o[1], o[2], o[3]);
  ushort_t hv[4];
  #pragma unroll
  for (int j = 0; j < 4; ++j) hv[j] = f2bf(o[j]);
  *(ushort4*)(xh + (size_t)row * DMODEL + t * 4) = make_ushort4(hv[0], hv[1], hv[2], hv[3]);
}

// ---------------------------------------------------------------------------
// x = layernorm(x + sum_{z<4} parts[z] + bias) * g + b, fused bf16 hi split.
// ---------------------------------------------------------------------------
__global__ __launch_bounds__(256)
void resid_ln_red(float* __restrict__ x, const float* __restrict__ parts,
                  long pstride, const float* __restrict__ bias,
                  const float* __restrict__ g, const float* __restrict__ b,
                  ushort_t* __restrict__ xh)
{
  __shared__ float sm[4];
  int row = blockIdx.x, t = threadIdx.x;
  size_t base = (size_t)row * DMODEL + t * 4;
  float4 xv = *(const float4*)(x + base);
  float4 bb = *(const float4*)(bias + t * 4);
  float a0 = xv.x + bb.x, a1 = xv.y + bb.y, a2 = xv.z + bb.z, a3 = xv.w + bb.w;
  #pragma unroll
  for (int z = 0; z < 4; ++z) {
    float4 pv = *(const float4*)(parts + (size_t)z * pstride + base);
    a0 += pv.x; a1 += pv.y; a2 += pv.z; a3 += pv.w;
  }
  float s = block_sum256(a0 + a1 + a2 + a3, sm);
  float mean = s * (1.0f / DMODEL);
  float d0 = a0 - mean, d1 = a1 - mean, d2 = a2 - mean, d3 = a3 - mean;
  float vs = block_sum256(d0*d0 + d1*d1 + d2*d2 + d3*d3, sm);
  float inv = rsqrtf(vs * (1.0f / DMODEL) + 1e-5f);
  float4 gv = *(const float4*)(g + t * 4);
  float4 bv = *(const float4*)(b + t * 4);
  float o[4];
  o[0] = d0 * inv * gv.x + bv.x;
  o[1] = d1 * inv * gv.y + bv.y;
  o[2] = d2 * inv * gv.z + bv.z;
  o[3] = d3 * inv * gv.w + bv.w;
  *(float4*)(x + base) = make_float4(o[0], o[1], o[2], o[3]);
  ushort_t hv[4];
  #pragma unroll
  for (int j = 0; j < 4; ++j) hv[j] = f2bf(o[j]);
  *(ushort4*)(xh + base) = make_ushort4(hv[0], hv[1], hv[2], hv[3]);
}

// ---------------------------------------------------------------------------
// final scale: out[row] *= 1/sum(row); sum from deterministic partials
// ---------------------------------------------------------------------------
__global__ __launch_bounds__(256)
void scale_softmax(float* __restrict__ out, const float* __restrict__ partials,
                   int ncb)
{
  __shared__ float sm[4];
  int row = blockIdx.x, t = threadIdx.x;
  float s = 0.f;
  for (int cb = t; cb < ncb; cb += 256) s += partials[(size_t)row * NCBP + cb];
  s = block_sum256(s, sm);
  float inv = 1.0f / s;
  float* p = out + (size_t)row * VOCAB;
  int head = (int)((((uintptr_t)16 - ((uintptr_t)p & 15)) & 15) >> 2);
  if (t < head) p[t] *= inv;
  int nvec = (VOCAB - head) >> 2;
  float4* pv = (float4*)(p + head);
  for (int i = t; i < nvec; i += 256) {
    float4 v = pv[i];
    v.x *= inv; v.y *= inv; v.z *= inv; v.w *= inv;
    pv[i] = v;
  }
  int done = head + nvec * 4;
  if (t < VOCAB - done) p[done + t] *= inv;
}

// ---------------------------------------------------------------------------
extern "C" void kernel_launch(void* const* d_in, const int* in_sizes, int n_in,
                              void* d_out, int out_size, void* d_ws, size_t ws_size,
                              hipStream_t stream)
{
  const int*   tokens = (const int*)  d_in[0];
  const float* emb    = (const float*)d_in[1];
  const float* Wq     = (const float*)d_in[2];
  const float* bq     = (const float*)d_in[3];
  const float* Wk     = (const float*)d_in[4];
  const float* bk     = (const float*)d_in[5];
  const float* Wv     = (const float*)d_in[6];
  const float* bv     = (const float*)d_in[7];
  const float* ln1g   = (const float*)d_in[8];
  const float* ln1b   = (const float*)d_in[9];
  const float* W1     = (const float*)d_in[10];
  const float* b1     = (const float*)d_in[11];
  const float* W2     = (const float*)d_in[12];
  const float* b2     = (const float*)d_in[13];
  const float* ln2g   = (const float*)d_in[14];
  const float* ln2b   = (const float*)d_in[15];
  const float* Wout   = (const float*)d_in[16];
  const float* bout   = (const float*)d_in[17];

  // workspace: xh 0-8 MB; strip path stripH 8-16; partials 24-30.55;
  // big path (ws >= 137 MB): WoutT at 32 MB (50304x1024 bf16 = 103 MB)
  char* wsb = (char*)d_ws;
  ushort_t* xh     = (ushort_t*)(wsb);
  ushort_t* stripH = (ushort_t*)(wsb + ((size_t)8  << 20));
  float*    partials = (float*)(wsb + ((size_t)24 << 20)); // [4096][NCBP] f32
  ushort_t* woutT  = (ushort_t*)(wsb + ((size_t)32 << 20));
  const bool bigws = ws_size >= ((size_t)137 << 20);

  // scratch in d_out (823 MB; all dead before the logits GEMM writes it)
  char* ob = (char*)d_out;
  float*    x     = (float*)(ob);                          // [S][D] f32 16MB
  float*    yb    = (float*)(ob + ((size_t)16  << 20));    // [S][D] f32 16MB
  ushort_t* qh    = (ushort_t*)(ob + ((size_t)32  << 20)); // [H][S][64] 8MB
  ushort_t* ql    = (ushort_t*)(ob + ((size_t)40  << 20));
  ushort_t* kh    = (ushort_t*)(ob + ((size_t)48  << 20));
  ushort_t* vt    = (ushort_t*)(ob + ((size_t)56  << 20)); // [H][64][S] 8MB
  ushort_t* h1h   = (ushort_t*)(ob + ((size_t)64  << 20)); // [S][DFF] bf16 32MB
  float*    fparts= (float*)(ob + ((size_t)96  << 20));    // [4][S][D] f32 64MB
  ushort_t* wqkvhA= (ushort_t*)(ob + ((size_t)160 << 20)); // [L][3072][1024] 24MB
  ushort_t* wqkvlA= (ushort_t*)(ob + ((size_t)184 << 20));
  ushort_t* w1hA  = (ushort_t*)(ob + ((size_t)208 << 20)); // [L][4096][1024] 32MB
  ushort_t* w1lA  = (ushort_t*)(ob + ((size_t)240 << 20));
  ushort_t* w2hA  = (ushort_t*)(ob + ((size_t)272 << 20)); // [L][1024][4096] 32MB
  ushort_t* w2lA  = (ushort_t*)(ob + ((size_t)304 << 20));
  float*    bqkvA = (float*)(ob + ((size_t)336 << 20));    // [L][3072] f32
  float*    outf  = (float*)d_out;

  const long WQKV_L = 3072L * 1024;   // shorts per layer
  const long WFF_L  = 4096L * 1024;

  embed_kernel<<<S_LEN, 256, 0, stream>>>(tokens, emb, x, xh);

  // ---- hoisted weight prep (activation-independent) ----
  transpose_split<<<dim3(16, 1, 64), 256, 0, stream>>>(
      Wq, wqkvhA, wqkvlA,
      (long)DMODEL * DHEAD, (long)DHEAD * DMODEL,
      (long)NHEAD * DMODEL * DHEAD, WQKV_L,
      16, DHEAD, DMODEL, DHEAD);
  transpose_split<<<dim3(16, 1, 64), 256, 0, stream>>>(
      Wk, wqkvhA + 1024 * 1024, wqkvlA + 1024 * 1024,
      (long)DMODEL * DHEAD, (long)DHEAD * DMODEL,
      (long)NHEAD * DMODEL * DHEAD, WQKV_L,
      16, DHEAD, DMODEL, DHEAD);
  transpose_split<<<dim3(16, 1, 64), 256, 0, stream>>>(
      Wv, wqkvhA + 2048 * 1024, wqkvlA + 2048 * 1024,
      (long)DMODEL * DHEAD, (long)DHEAD * DMODEL,
      (long)NHEAD * DMODEL * DHEAD, WQKV_L,
      16, DHEAD, DMODEL, DHEAD);
  transpose_split<<<dim3(16, 64, 4), 256, 0, stream>>>(
      W1, w1hA, w1lA, 0, 0,
      (long)DMODEL * DFF, WFF_L, 1, DFF, DMODEL, DFF);
  transpose_split<<<dim3(64, 16, 4), 256, 0, stream>>>(
      W2, w2hA, w2lA, 0, 0,
      (long)DFF * DMODEL, WFF_L, 1, DMODEL, DFF, DMODEL);
  concat3_kernel<<<dim3(4, NLAYER), 256, 0, stream>>>(
      bq, bk, bv, bqkvA, 1024, 1024, 3072);

  for (int l = 0; l < NLAYER; ++l) {
    const ushort_t* wqh = wqkvhA + (long)l * WQKV_L;
    const ushort_t* wql = wqkvlA + (long)l * WQKV_L;
    const ushort_t* w1h = w1hA + (long)l * WFF_L;
    const ushort_t* w1l = w1lA + (long)l * WFF_L;
    const ushort_t* w2h = w2hA + (long)l * WFF_L;
    const ushort_t* w2l = w2lA + (long)l * WFF_L;

    // fused QKV projection: 2-prod, grid 16x12; V written transposed
    gemm8p<2, false><<<dim3(16, 12), 512, 0, stream>>>(
        xh, wqh, wql, bqkvA + (long)l * 3072, nullptr,
        qh, ql, kh, vt, 1024, 1024, 0, 0);

    attn_mfma<<<dim3(32, 16), 256, 0, stream>>>(qh, ql, kh, vt, yb);

    resid_ln_kernel<<<S_LEN, 256, 0, stream>>>(x, yb,
        ln1g + (size_t)l * DMODEL, ln1b + (size_t)l * DMODEL, xh);

    // FFN1: 2-prod, grid 16x16, bf16-hi output
    gemm8p<1, true><<<dim3(16, 16), 512, 0, stream>>>(
        xh, w1h, w1l, b1 + (long)l * DFF, nullptr,
        h1h, nullptr, nullptr, nullptr, 1024, 1024, 4096, 0);
    // FFN2: 2-prod split-K x4 (grid 16x4x4), f32 partials
    gemm8p<0, false><<<dim3(16, 4, 4), 512, 0, stream>>>(
        h1h, w2h, w2l, nullptr, fparts,
        nullptr, nullptr, nullptr, nullptr,
        1024, 4096, 1024, (long)S_LEN * DMODEL);
    resid_ln_red<<<S_LEN, 256, 0, stream>>>(x, fparts, (long)S_LEN * DMODEL,
        b2 + (long)l * DMODEL,
        ln2g + (size_t)l * DMODEL, ln2b + (size_t)l * DMODEL, xh);
  }

  if (bigws) {
    // single-shot logits: whole Wout^T (hi) staged in ws, one GEMM
    transpose_h<<<dim3(16, 786, 1), 256, 0, stream>>>(
        Wout, woutT, VOCAB, DMODEL, VOCAB);
    gemm1p<true><<<dim3(16, 197), 512, 0, stream>>>(
        xh, woutT, bout, outf, 1024, 1024, VOCAB, VOCAB, partials, 0);
  } else {
    // fallback: 4096-col strips through 8 MB of ws
    const int SW = 4096;
    for (int is = 0; is < 12; ++is) {
      int n0 = is * SW;
      transpose_h<<<dim3(16, 64, 1), 256, 0, stream>>>(
          Wout + n0, stripH, VOCAB, DMODEL, SW);
      gemm1p<false><<<dim3(16, 16), 512, 0, stream>>>(
          xh, stripH, bout + n0, outf + n0,
          1024, 1024, VOCAB, SW, partials, is * 16);
    }
    int n0 = 12 * SW;                       // 49152
    int ncols = VOCAB - n0;                 // 1105
    int nt64 = (ncols + 63) / 64;           // 18
    int nb256 = (ncols + 255) / 256;        // 5
    transpose_h<<<dim3(16, nt64, 1), 256, 0, stream>>>(
        Wout + n0, stripH, VOCAB, DMODEL, ncols);
    gemm1p<true><<<dim3(16, nb256), 512, 0, stream>>>(
        xh, stripH, bout + n0, outf + n0,
        1024, 1024, VOCAB, ncols, partials, 12 * 16);
  }
  const int ncb = (VOCAB + 255) / 256;      // 197
  scale_softmax<<<S_LEN, 256, 0, stream>>>(outf, partials, ncb);
}

// Round 11
// 3215.837 us; speedup vs baseline: 4.8848x; 1.1518x over previous
//
#include <hip/hip_runtime.h>
#include <math.h>

#define S_LEN  4096
#define DMODEL 1024
#define NHEAD  16
#define DHEAD  64
#define DFF    4096
#define NLAYER 4
#define VOCAB  50257
#define NCBP   400   // partials row stride (col-blocks of 256, padded)

typedef unsigned short ushort_t;
typedef __attribute__((ext_vector_type(8))) __bf16 bf16x8;
typedef __attribute__((ext_vector_type(4))) float f32x4;

static __device__ __forceinline__ ushort_t f2bf(float f) {
  union { float f; unsigned u; } x; x.f = f;
  unsigned r = x.u + 0x7fffu + ((x.u >> 16) & 1u);
  return (ushort_t)(r >> 16);
}
static __device__ __forceinline__ float bf2f(ushort_t h) {
  union { unsigned u; float f; } x; x.u = ((unsigned)h) << 16;
  return x.f;
}
// 2^x via v_exp_f32 (avoid __exp2f: collides with glibc math.h macros)
static __device__ __forceinline__ float exp2fast(float x) {
  return __builtin_amdgcn_exp2f(x);
}

#define GLOAD_LDS16(gp, lp) \
  __builtin_amdgcn_global_load_lds((const __attribute__((address_space(1))) void*)(gp), \
                                   (__attribute__((address_space(3))) void*)(lp), 16, 0, 0)

// q pre-scale: 1/sqrt(64) * log2(e)  (softmax runs in exp2 domain)
#define QSCALE 0.18033688011112042f

// ---------------------------------------------------------------------------
// embedding + sinusoidal positional encoding, fused bf16 split (hi only)
// ---------------------------------------------------------------------------
__global__ __launch_bounds__(256) void embed_kernel(
    const int* __restrict__ tokens, const float* __restrict__ emb,
    float* __restrict__ x, ushort_t* __restrict__ xh)
{
  int s = blockIdx.x;
  int tok = tokens[s];
  int d0 = threadIdx.x * 4;
  const double lf = 0.01798894603901598653; // log(10000)/512
  float4 ev = *(const float4*)(emb + (size_t)tok * DMODEL + d0);
  float o[4]; float evr[4] = {ev.x, ev.y, ev.z, ev.w};
  #pragma unroll
  for (int j = 0; j < 4; ++j) {
    int d = d0 + j;
    int i = (d < 512) ? d : d - 512;
    double ang = (double)s * exp(-lf * (double)i);
    float pe = (d < 512) ? (float)sin(ang) : (float)cos(ang);
    o[j] = evr[j] + pe;
  }
  *(float4*)(x + (size_t)s * DMODEL + d0) = make_float4(o[0], o[1], o[2], o[3]);
  ushort_t hv[4];
  #pragma unroll
  for (int j = 0; j < 4; ++j) hv[j] = f2bf(o[j]);
  *(ushort4*)(xh + (size_t)s * DMODEL + d0) = make_ushort4(hv[0], hv[1], hv[2], hv[3]);
}

// ---------------------------------------------------------------------------
// transpose + split: in f32 [K][N] (row stride in_rstride) -> out bf16 hi/lo
// [N][Kout] K-contiguous. Two-level z batching: z1 = z % zdiv, z2 = z / zdiv.
// ---------------------------------------------------------------------------
__global__ __launch_bounds__(256)
void transpose_split(const float* __restrict__ in, ushort_t* __restrict__ oh,
                     ushort_t* __restrict__ ol,
                     long in_zstr, long out_zoff, long in_z2str, long out_z2off,
                     int zdiv, int in_rstride, int Kout, int Nvalid)
{
  __shared__ float tile[64][65];
  int z1 = blockIdx.z % zdiv, z2 = blockIdx.z / zdiv;
  long ioff = (long)z1 * in_zstr + (long)z2 * in_z2str;
  long ooff = (long)z1 * out_zoff + (long)z2 * out_z2off;
  const float* inz = in + ioff;
  ushort_t* ohz = oh + ooff;
  ushort_t* olz = ol + ooff;
  int k0 = blockIdx.x * 64, n0 = blockIdx.y * 64;
  int t = threadIdx.x;
  #pragma unroll
  for (int i = 0; i < 4; ++i) {
    int idx = t + i * 256;            // 0..1023
    int kk = idx >> 4, c4 = idx & 15;
    #pragma unroll
    for (int j = 0; j < 4; ++j) {
      int n = n0 + c4 * 4 + j;
      float v = (n < Nvalid) ? inz[(long)(k0 + kk) * in_rstride + n] : 0.f;
      tile[c4 * 4 + j][kk] = v;       // transposed into LDS
    }
  }
  __syncthreads();
  #pragma unroll
  for (int i = 0; i < 4; ++i) {
    int idx = t + i * 256;
    int nn = idx >> 4, k4 = idx & 15;
    ushort_t hv[4], lv[4];
    #pragma unroll
    for (int j = 0; j < 4; ++j) {
      float v = tile[nn][k4 * 4 + j];
      hv[j] = f2bf(v);
      lv[j] = f2bf(v - bf2f(hv[j]));
    }
    long ob = (long)(n0 + nn) * Kout + k0 + k4 * 4;
    *(ushort4*)(ohz + ob) = make_ushort4(hv[0], hv[1], hv[2], hv[3]);
    *(ushort4*)(olz + ob) = make_ushort4(lv[0], lv[1], lv[2], lv[3]);
  }
}

// hi-only variant (for the 1-product logits GEMM)
__global__ __launch_bounds__(256)
void transpose_h(const float* __restrict__ in, ushort_t* __restrict__ oh,
                 int in_rstride, int Kout, int Nvalid)
{
  __shared__ float tile[64][65];
  int k0 = blockIdx.x * 64, n0 = blockIdx.y * 64;
  int t = threadIdx.x;
  #pragma unroll
  for (int i = 0; i < 4; ++i) {
    int idx = t + i * 256;
    int kk = idx >> 4, c4 = idx & 15;
    #pragma unroll
    for (int j = 0; j < 4; ++j) {
      int n = n0 + c4 * 4 + j;
      float v = (n < Nvalid) ? in[(long)(k0 + kk) * in_rstride + n] : 0.f;
      tile[c4 * 4 + j][kk] = v;
    }
  }
  __syncthreads();
  #pragma unroll
  for (int i = 0; i < 4; ++i) {
    int idx = t + i * 256;
    int nn = idx >> 4, k4 = idx & 15;
    ushort_t hv[4];
    #pragma unroll
    for (int j = 0; j < 4; ++j) hv[j] = f2bf(tile[nn][k4 * 4 + j]);
    long ob = (long)(n0 + nn) * Kout + k0 + k4 * 4;
    *(ushort4*)(oh + ob) = make_ushort4(hv[0], hv[1], hv[2], hv[3]);
  }
}

// ---------------------------------------------------------------------------
// concat 3 bias vectors of length n into [3n], batched over layers (y)
// ---------------------------------------------------------------------------
__global__ __launch_bounds__(256)
void concat3_kernel(const float* __restrict__ a, const float* __restrict__ b,
                    const float* __restrict__ c, float* __restrict__ o,
                    int n, long lstrA, long lstrO)
{
  int i = blockIdx.x * 256 + threadIdx.x;
  long l = blockIdx.y;
  if (i < n) {
    o[l * lstrO + i]         = a[l * lstrA + i];
    o[l * lstrO + n + i]     = b[l * lstrA + i];
    o[l * lstrO + 2 * n + i] = c[l * lstrA + i];
  }
}

// ---------------------------------------------------------------------------
// 256x256-tile 8-wave GEMM, counted-vmcnt phase pipeline, 2-product split:
// C = Ah @ (Bh + Bl)^T. Streams Ah|Bh|Bl, double-buffered (96 KB LDS).
// EPI: 0 = raw f32 partial (split-K via blockIdx.z), 1 = bf16 hi C (+bias,
// RELU), 2 = QKV routing (q scaled hi/lo, k hi, v -> transposed [H][64][S]).
// ---------------------------------------------------------------------------
template<int EPI, bool RELU>
__global__ __launch_bounds__(512, 2)
void gemm8p(const ushort_t* __restrict__ Ah,
            const ushort_t* __restrict__ Bh, const ushort_t* __restrict__ Bl,
            const float* __restrict__ bias, float* __restrict__ C,
            ushort_t* __restrict__ O0, ushort_t* __restrict__ O1,
            ushort_t* __restrict__ O2, ushort_t* __restrict__ O4,
            int K, int ldk, long ldc, long czStride)
{
  constexpr int BUFSTR = 3 * 8192;              // Ah | Bh | Bl
  constexpr int OBH = 8192, OBL = 16384;
  __shared__ ushort_t lds[2 * BUFSTR];          // 96 KB

  const int t = threadIdx.x;
  const int l = t & 63;
  const int w = t >> 6;            // 0..7
  const int wr = w >> 2;           // 0..1  (row half)
  const int wc = w & 3;            // 0..3  (col quarter)
  const int lrow = l & 15;
  const int lk = (l >> 4) * 8;
  const int l8 = l * 8;
  const long m0 = (long)blockIdx.x * 256;
  const long n0 = (long)blockIdx.y * 256;
  const long kz = (long)blockIdx.z * K;

  const ushort_t *agp[2], *bgp[2], *blgp[2];
  int dst[2];
  #pragma unroll
  for (int i = 0; i < 2; ++i) {
    int s = i * 8 + w;                       // subtile 0..15
    dst[i] = s * 512 + l8;
    agp[i]  = Ah + (m0 + s * 16 + lrow) * (long)ldk + kz + lk;
    bgp[i]  = Bh + (n0 + s * 16 + lrow) * (long)ldk + kz + lk;
    blgp[i] = Bl + (n0 + s * 16 + lrow) * (long)ldk + kz + lk;
  }

  f32x4 acc[8][4];
  #pragma unroll
  for (int m = 0; m < 8; ++m)
    #pragma unroll
    for (int n = 0; n < 4; ++n) acc[m][n] = (f32x4)0.f;

  // prologue: stage tile 0, canonical per-tile order
  GLOAD_LDS16(agp[0],  &lds[dst[0]]);
  GLOAD_LDS16(agp[1],  &lds[dst[1]]);
  GLOAD_LDS16(bgp[0],  &lds[OBH + dst[0]]);
  GLOAD_LDS16(bgp[1],  &lds[OBH + dst[1]]);
  GLOAD_LDS16(blgp[0], &lds[OBL + dst[0]]);
  GLOAD_LDS16(blgp[1], &lds[OBL + dst[1]]);

  const int nk = K >> 5;
  int cur = 0;
  for (int kt = 0; kt < nk; ++kt) {
    const int knx = (kt + 1 < nk) ? (kt + 1) * 32 : 0;  // last iter: harmless reload
    ushort_t* cb = &lds[cur * BUFSTR];
    ushort_t* nb = &lds[(cur ^ 1) * BUFSTR];
    bf16x8 af[8], bhf[4], blf[4];

    // ---------- P0: needs Ah,Bh of tile kt ----------
    asm volatile("s_waitcnt vmcnt(2)" ::: "memory");
    __builtin_amdgcn_sched_barrier(0);
    __builtin_amdgcn_s_barrier();
    __builtin_amdgcn_sched_barrier(0);
    #pragma unroll
    for (int m = 0; m < 8; ++m)
      af[m] = *(const bf16x8*)&cb[(wr * 8 + m) * 512 + l8];
    #pragma unroll
    for (int n = 0; n < 4; ++n)
      bhf[n] = *(const bf16x8*)&cb[OBH + (wc * 4 + n) * 512 + l8];
    GLOAD_LDS16(agp[0] + knx, &nb[dst[0]]);
    GLOAD_LDS16(agp[1] + knx, &nb[dst[1]]);
    GLOAD_LDS16(bgp[0] + knx, &nb[OBH + dst[0]]);
    __builtin_amdgcn_s_setprio(1);
    #pragma unroll
    for (int m = 0; m < 8; ++m)
      #pragma unroll
      for (int n = 0; n < 4; ++n)
        acc[m][n] = __builtin_amdgcn_mfma_f32_16x16x32_bf16(af[m], bhf[n], acc[m][n], 0, 0, 0);
    __builtin_amdgcn_s_setprio(0);
    __builtin_amdgcn_sched_barrier(0);

    // ---------- P1: needs Bl of tile kt ----------
    asm volatile("s_waitcnt vmcnt(3)" ::: "memory");
    __builtin_amdgcn_sched_barrier(0);
    __builtin_amdgcn_s_barrier();
    __builtin_amdgcn_sched_barrier(0);
    #pragma unroll
    for (int n = 0; n < 4; ++n)
      blf[n] = *(const bf16x8*)&cb[OBL + (wc * 4 + n) * 512 + l8];
    GLOAD_LDS16(bgp[1] + knx,  &nb[OBH + dst[1]]);
    GLOAD_LDS16(blgp[0] + knx, &nb[OBL + dst[0]]);
    GLOAD_LDS16(blgp[1] + knx, &nb[OBL + dst[1]]);
    __builtin_amdgcn_s_setprio(1);
    #pragma unroll
    for (int m = 0; m < 8; ++m)
      #pragma unroll
      for (int n = 0; n < 4; ++n)
        acc[m][n] = __builtin_amdgcn_mfma_f32_16x16x32_bf16(af[m], blf[n], acc[m][n], 0, 0, 0);
    __builtin_amdgcn_s_setprio(0);
    __builtin_amdgcn_sched_barrier(0);
    cur ^= 1;
  }
  asm volatile("s_waitcnt vmcnt(0)" ::: "memory");

  // ---------------- epilogue (row-major store order for line combining) ----
  if constexpr (EPI == 2) {
    #pragma unroll
    for (int n = 0; n < 4; ++n) {
      long col = n0 + wc * 64 + n * 16 + lrow;
      float bv = bias[col];
      #pragma unroll
      for (int m = 0; m < 8; ++m) {
        #pragma unroll
        for (int r = 0; r < 4; ++r) {
          long row = m0 + wr * 128 + m * 16 + (l >> 4) * 4 + r;
          float v = acc[m][n][r] + bv;
          int c = (int)col;
          if (c < 1024) {
            int hh = c >> 6, e = c & 63;
            float qv = v * QSCALE;            // fold 1/sqrt(DH)*log2e
            ushort_t hi = f2bf(qv);
            size_t a = ((size_t)hh * S_LEN + row) * 64 + e;
            O0[a] = hi; O1[a] = f2bf(qv - bf2f(hi));
          } else if (c < 2048) {
            int cc = c - 1024;
            int hh = cc >> 6, e = cc & 63;
            size_t a = ((size_t)hh * S_LEN + row) * 64 + e;
            O2[a] = f2bf(v);
          } else {
            // V: write transposed directly -> vt[h][e][row]
            int cc = c - 2048;
            int hh = cc >> 6, e = cc & 63;
            size_t a = ((size_t)hh * DHEAD + e) * S_LEN + row;
            O4[a] = f2bf(v);
          }
        }
      }
    }
  } else if constexpr (EPI == 1) {
    long col4[4]; float bv4[4];
    #pragma unroll
    for (int n = 0; n < 4; ++n) {
      col4[n] = n0 + wc * 64 + n * 16 + lrow;
      bv4[n] = bias[col4[n]];
    }
    #pragma unroll
    for (int m = 0; m < 8; ++m) {
      #pragma unroll
      for (int r = 0; r < 4; ++r) {
        long row = m0 + wr * 128 + m * 16 + (l >> 4) * 4 + r;
        ushort_t* crow = O0 + row * ldc;
        #pragma unroll
        for (int n = 0; n < 4; ++n) {
          float v = acc[m][n][r] + bv4[n];
          if (RELU) v = fmaxf(v, 0.f);
          crow[col4[n]] = f2bf(v);
        }
      }
    }
  } else {  // EPI == 0: raw f32 partial (split-K), no bias
    float* Cz = C + (long)blockIdx.z * czStride;
    long col4[4];
    #pragma unroll
    for (int n = 0; n < 4; ++n) col4[n] = n0 + wc * 64 + n * 16 + lrow;
    #pragma unroll
    for (int m = 0; m < 8; ++m) {
      #pragma unroll
      for (int r = 0; r < 4; ++r) {
        long row = m0 + wr * 128 + m * 16 + (l >> 4) * 4 + r;
        float* crow = Cz + row * ldc;
        #pragma unroll
        for (int n = 0; n < 4; ++n) crow[col4[n]] = acc[m][n][r];
      }
    }
  }
}

// ---------------------------------------------------------------------------
// 1-product 256x256 GEMM (logits): C = exp(Ah@Bh^T + bias), per-row partials.
// 3-buffer rotation, 2-tile-deep prefetch, vmcnt(4) counted wait, ONE barrier
// per K-step; prefetch issued between ds_read and the 32-MFMA cluster.
// ---------------------------------------------------------------------------
template<bool BOUND>
__global__ __launch_bounds__(512, 2)
void gemm1p(const ushort_t* __restrict__ Ah, const ushort_t* __restrict__ Bh,
            const float* __restrict__ bias, float* __restrict__ C,
            int K, int ldk, long ldc, int Nlimit,
            float* __restrict__ Ppart, int cbbase)
{
  constexpr int OB = 8192;
  constexpr int BUFSTR = 16384;       // shorts per buffer (A 16KB | B 16KB)
  __shared__ ushort_t lds[3 * BUFSTR];  // 96 KB, 3-buffer rotation
  __shared__ float psum[1024];

  const int t = threadIdx.x;
  const int l = t & 63;
  const int w = t >> 6;
  const int wr = w >> 2;
  const int wc = w & 3;
  const int lrow = l & 15;
  const int lk = (l >> 4) * 8;
  const int l8 = l * 8;
  const long m0 = (long)blockIdx.x * 256;
  const long n0 = (long)blockIdx.y * 256;

  const ushort_t *agp[2], *bgp[2];
  int dst[2];
  #pragma unroll
  for (int i = 0; i < 2; ++i) {
    int s = i * 8 + w;
    dst[i] = s * 512 + l8;
    agp[i] = Ah + (m0 + s * 16 + lrow) * (long)ldk + lk;
    bgp[i] = Bh + (n0 + s * 16 + lrow) * (long)ldk + lk;
  }

  f32x4 acc[8][4];
  #pragma unroll
  for (int m = 0; m < 8; ++m)
    #pragma unroll
    for (int n = 0; n < 4; ++n) acc[m][n] = (f32x4)0.f;

  // prologue: tile 0 -> buf0, tile 1 -> buf1 (8 loads outstanding)
  GLOAD_LDS16(agp[0], &lds[dst[0]]);
  GLOAD_LDS16(agp[1], &lds[dst[1]]);
  GLOAD_LDS16(bgp[0], &lds[OB + dst[0]]);
  GLOAD_LDS16(bgp[1], &lds[OB + dst[1]]);
  GLOAD_LDS16(agp[0] + 32, &lds[BUFSTR + dst[0]]);
  GLOAD_LDS16(agp[1] + 32, &lds[BUFSTR + dst[1]]);
  GLOAD_LDS16(bgp[0] + 32, &lds[BUFSTR + OB + dst[0]]);
  GLOAD_LDS16(bgp[1] + 32, &lds[BUFSTR + OB + dst[1]]);

  const int nk = K >> 5;
  int cur = 0;
  for (int kt = 0; kt < nk; ++kt) {
    ushort_t* cb = &lds[cur * BUFSTR];
    int nxt = cur + 2; if (nxt >= 3) nxt -= 3;
    ushort_t* nb = &lds[nxt * BUFSTR];
    bf16x8 af[8], bhf[4];

    asm volatile("s_waitcnt vmcnt(4)" ::: "memory");   // tile kt landed
    __builtin_amdgcn_sched_barrier(0);
    __builtin_amdgcn_s_barrier();
    __builtin_amdgcn_sched_barrier(0);
    #pragma unroll
    for (int m = 0; m < 8; ++m)
      af[m] = *(const bf16x8*)&cb[(wr * 8 + m) * 512 + l8];
    #pragma unroll
    for (int n = 0; n < 4; ++n)
      bhf[n] = *(const bf16x8*)&cb[OB + (wc * 4 + n) * 512 + l8];
    const int knx2 = (kt + 2 < nk) ? (kt + 2) * 32 : 0;  // tail: harmless refill
    GLOAD_LDS16(agp[0] + knx2, &nb[dst[0]]);
    GLOAD_LDS16(agp[1] + knx2, &nb[dst[1]]);
    GLOAD_LDS16(bgp[0] + knx2, &nb[OB + dst[0]]);
    GLOAD_LDS16(bgp[1] + knx2, &nb[OB + dst[1]]);
    __builtin_amdgcn_s_setprio(1);
    #pragma unroll
    for (int m = 0; m < 8; ++m)
      #pragma unroll
      for (int n = 0; n < 4; ++n)
        acc[m][n] = __builtin_amdgcn_mfma_f32_16x16x32_bf16(af[m], bhf[n], acc[m][n], 0, 0, 0);
    __builtin_amdgcn_s_setprio(0);
    __builtin_amdgcn_sched_barrier(0);
    cur = (cur == 2) ? 0 : cur + 1;
  }
  asm volatile("s_waitcnt vmcnt(0)" ::: "memory");

  // epilogue: exp(logit), row-major store order + deterministic partial sums
  float smr[8][4];
  #pragma unroll
  for (int m = 0; m < 8; ++m)
    #pragma unroll
    for (int r = 0; r < 4; ++r) smr[m][r] = 0.f;
  long col4[4]; float bv4[4]; bool cok4[4];
  #pragma unroll
  for (int n = 0; n < 4; ++n) {
    col4[n] = n0 + wc * 64 + n * 16 + lrow;
    cok4[n] = (!BOUND) || (col4[n] < (long)Nlimit);
    bv4[n] = cok4[n] ? bias[col4[n]] : 0.f;
  }
  #pragma unroll
  for (int m = 0; m < 8; ++m) {
    #pragma unroll
    for (int r = 0; r < 4; ++r) {
      long row = m0 + wr * 128 + m * 16 + (l >> 4) * 4 + r;
      float* crow = C + row * ldc;
      #pragma unroll
      for (int n = 0; n < 4; ++n) {
        float e = cok4[n] ? __expf(acc[m][n][r] + bv4[n]) : 0.f;
        if (cok4[n]) crow[col4[n]] = e;
        smr[m][r] += e;
      }
    }
  }
  #pragma unroll
  for (int m = 0; m < 8; ++m) {
    #pragma unroll
    for (int r = 0; r < 4; ++r) {
      float s = smr[m][r];
      s += __shfl_xor(s, 1);
      s += __shfl_xor(s, 2);
      s += __shfl_xor(s, 4);
      s += __shfl_xor(s, 8);
      if (lrow == 0)
        psum[wc * 256 + wr * 128 + m * 16 + (l >> 4) * 4 + r] = s;
    }
  }
  __syncthreads();
  if (t < 256) {
    float s = psum[t] + psum[256 + t] + psum[512 + t] + psum[768 + t];
    Ppart[(m0 + t) * NCBP + cbbase + blockIdx.y] = s;
  }
}

// ---------------------------------------------------------------------------
// MFMA flash attention v3. qh/ql: [H][S][64] bf16 (pre-scaled by QSCALE),
// kh: [H][S][64] bf16, vt: [H][64][S] bf16. y: [S][1024] f32.
// 2-product QK^T; exp2-domain softmax; defer-rescale vote; K/V double-buffer
// with next-tile loads issued a full compute-phase early (1 barrier/tile).
// ---------------------------------------------------------------------------
__global__ __launch_bounds__(256)
void attn_mfma(const ushort_t* __restrict__ qh, const ushort_t* __restrict__ ql,
               const ushort_t* __restrict__ kh, const ushort_t* __restrict__ vt,
               float* __restrict__ y)
{
  __shared__ ushort_t lds[24576];  // buf0 K|V [8192], buf1 K|V [8192], P [4][2048]

  const int t = threadIdx.x, l = t & 63, w = t >> 6;
  const int lrow = l & 15, lhi = l >> 4;
  const int h = blockIdx.y;
  const int bw = blockIdx.x * 128 + w * 32;
  const size_t hS = (size_t)h * S_LEN * DHEAD;
  const size_t hV = (size_t)h * DHEAD * S_LEN;
  const int pb = 16384 + w * 2048;

  bf16x8 qhf[2][2], qlf[2][2];
  #pragma unroll
  for (int m = 0; m < 2; ++m)
    #pragma unroll
    for (int ks = 0; ks < 2; ++ks) {
      size_t a = hS + (size_t)(bw + m * 16 + lrow) * 64 + ks * 32 + lhi * 8;
      qhf[m][ks] = *(const bf16x8*)(qh + a);
      qlf[m][ks] = *(const bf16x8*)(ql + a);
    }

  f32x4 acc[2][4];
  #pragma unroll
  for (int m = 0; m < 2; ++m)
    #pragma unroll
    for (int n = 0; n < 4; ++n) acc[m][n] = (f32x4)0.f;
  float mrow[8], lsum[8];
  #pragma unroll
  for (int i = 0; i < 8; ++i) { mrow[i] = -1e30f; lsum[i] = 0.f; }

  // prologue: stage tile 0 into buf 0
  #pragma unroll
  for (int i = 0; i < 2; ++i) {
    int s = i * 4 + w;
    size_t krow = (size_t)((s >> 1) * 16 + lrow);
    int koff = (s & 1) * 32 + lhi * 8;
    GLOAD_LDS16(kh + hS + krow * 64 + koff, &lds[s * 512 + l * 8]);
    int toff = (s & 1) * 32 + lhi * 8;
    GLOAD_LDS16(vt + hV + krow * S_LEN + toff, &lds[4096 + s * 512 + l * 8]);
  }

  int cur = 0;
  for (int kt = 0; kt < S_LEN; kt += 64) {
    asm volatile("s_waitcnt vmcnt(0)" ::: "memory");
    __builtin_amdgcn_sched_barrier(0);
    __builtin_amdgcn_s_barrier();
    __builtin_amdgcn_sched_barrier(0);
    ushort_t* cb = &lds[cur * 8192];
    // issue next-tile loads into the other buffer (hidden under compute)
    if (kt + 64 < S_LEN) {
      ushort_t* nb = &lds[(cur ^ 1) * 8192];
      int kn = kt + 64;
      #pragma unroll
      for (int i = 0; i < 2; ++i) {
        int s = i * 4 + w;
        size_t krow = (size_t)(kn + (s >> 1) * 16 + lrow);
        int koff = (s & 1) * 32 + lhi * 8;
        GLOAD_LDS16(kh + hS + krow * 64 + koff, &nb[s * 512 + l * 8]);
        size_t erow = (size_t)((s >> 1) * 16 + lrow);
        int toff = kn + (s & 1) * 32 + lhi * 8;
        GLOAD_LDS16(vt + hV + erow * S_LEN + toff, &nb[4096 + s * 512 + l * 8]);
      }
    }

    // scores (exp2 domain), 2-product: (qh + ql) * kh
    f32x4 sacc[2][4];
    #pragma unroll
    for (int m = 0; m < 2; ++m)
      #pragma unroll
      for (int n = 0; n < 4; ++n) sacc[m][n] = (f32x4)0.f;
    #pragma unroll
    for (int ks = 0; ks < 2; ++ks) {
      bf16x8 bh_[4];
      #pragma unroll
      for (int n = 0; n < 4; ++n)
        bh_[n] = *(const bf16x8*)&cb[(n * 2 + ks) * 512 + l * 8];
      #pragma unroll
      for (int m = 0; m < 2; ++m)
        #pragma unroll
        for (int n = 0; n < 4; ++n) {
          sacc[m][n] = __builtin_amdgcn_mfma_f32_16x16x32_bf16(qhf[m][ks], bh_[n], sacc[m][n], 0, 0, 0);
          sacc[m][n] = __builtin_amdgcn_mfma_f32_16x16x32_bf16(qlf[m][ks], bh_[n], sacc[m][n], 0, 0, 0);
        }
    }

    // tile maxes + wave vote (defer rescale when no row's max grew)
    float tmv[2][4];
    bool up = false;
    #pragma unroll
    for (int m = 0; m < 2; ++m) {
      #pragma unroll
      for (int r = 0; r < 4; ++r) {
        float tm = fmaxf(fmaxf(sacc[m][0][r], sacc[m][1][r]),
                         fmaxf(sacc[m][2][r], sacc[m][3][r]));
        tm = fmaxf(tm, __shfl_xor(tm, 1));
        tm = fmaxf(tm, __shfl_xor(tm, 2));
        tm = fmaxf(tm, __shfl_xor(tm, 4));
        tm = fmaxf(tm, __shfl_xor(tm, 8));
        tmv[m][r] = tm;
        up = up || (tm > mrow[m * 4 + r]);
      }
    }
    if (__ballot(up) != 0ULL) {
      #pragma unroll
      for (int m = 0; m < 2; ++m) {
        #pragma unroll
        for (int r = 0; r < 4; ++r) {
          const int idx = m * 4 + r;
          float mn = fmaxf(mrow[idx], tmv[m][r]);
          float al = exp2fast(mrow[idx] - mn);
          mrow[idx] = mn;
          lsum[idx] *= al;
          #pragma unroll
          for (int n = 0; n < 4; ++n) acc[m][n][r] *= al;
        }
      }
    }
    #pragma unroll
    for (int m = 0; m < 2; ++m) {
      #pragma unroll
      for (int r = 0; r < 4; ++r) {
        const int idx = m * 4 + r;
        float rs = 0.f;
        #pragma unroll
        for (int n = 0; n < 4; ++n) {
          float p = exp2fast(sacc[m][n][r] - mrow[idx]);
          rs += p;
          int pa = pb + ((m * 2 + (n >> 1)) << 9) + (((n & 1) * 2 + (lrow >> 3)) << 7)
                   + ((lhi * 4 + r) << 3) + (l & 7);
          pa ^= (lrow >> 3) << 3;
          lds[pa] = f2bf(p);
        }
        rs += __shfl_xor(rs, 1);
        rs += __shfl_xor(rs, 2);
        rs += __shfl_xor(rs, 4);
        rs += __shfl_xor(rs, 8);
        lsum[idx] += rs;
      }
    }

    // O += P V
    #pragma unroll
    for (int ks = 0; ks < 2; ++ks) {
      bf16x8 pa_[2];
      #pragma unroll
      for (int m = 0; m < 2; ++m) {
        int ra = pb + ((m * 2 + ks) << 9) + (l << 3);
        ra ^= ((l >> 4) & 1) << 3;
        pa_[m] = *(const bf16x8*)&lds[ra];
      }
      #pragma unroll
      for (int n = 0; n < 4; ++n) {
        bf16x8 vf = *(const bf16x8*)&cb[4096 + (n * 2 + ks) * 512 + l * 8];
        #pragma unroll
        for (int m = 0; m < 2; ++m)
          acc[m][n] = __builtin_amdgcn_mfma_f32_16x16x32_bf16(pa_[m], vf, acc[m][n], 0, 0, 0);
      }
    }
    cur ^= 1;
  }

  #pragma unroll
  for (int m = 0; m < 2; ++m) {
    #pragma unroll
    for (int r = 0; r < 4; ++r) {
      float inv = 1.0f / lsum[m * 4 + r];
      int row = bw + m * 16 + lhi * 4 + r;
      #pragma unroll
      for (int n = 0; n < 4; ++n)
        y[(size_t)row * DMODEL + h * 64 + n * 16 + lrow] = acc[m][n][r] * inv;
    }
  }
}

// ---------------------------------------------------------------------------
__device__ __forceinline__ float block_sum256(float v, float* sm)
{
  #pragma unroll
  for (int off = 32; off >= 1; off >>= 1) v += __shfl_xor(v, off);
  int w = threadIdx.x >> 6;
  if ((threadIdx.x & 63) == 0) sm[w] = v;
  __syncthreads();
  v = sm[0] + sm[1] + sm[2] + sm[3];
  __syncthreads();
  return v;
}

// x = layernorm(x + y) * g + b, fused bf16 (hi only) split of the result
__global__ __launch_bounds__(256)
void resid_ln_kernel(float* __restrict__ x, const float* __restrict__ y,
                     const float* __restrict__ g, const float* __restrict__ b,
                     ushort_t* __restrict__ xh)
{
  __shared__ float sm[4];
  int row = blockIdx.x, t = threadIdx.x;
  float4 xv = *(const float4*)(x + (size_t)row * DMODEL + t * 4);
  float4 yv = *(const float4*)(y + (size_t)row * DMODEL + t * 4);
  float a0 = xv.x + yv.x, a1 = xv.y + yv.y, a2 = xv.z + yv.z, a3 = xv.w + yv.w;
  float s = block_sum256(a0 + a1 + a2 + a3, sm);
  float mean = s * (1.0f / DMODEL);
  float d0 = a0 - mean, d1 = a1 - mean, d2 = a2 - mean, d3 = a3 - mean;
  float vs = block_sum256(d0*d0 + d1*d1 + d2*d2 + d3*d3, sm);
  float inv = rsqrtf(vs * (1.0f / DMODEL) + 1e-5f);
  float4 gv = *(const float4*)(g + t * 4);
  float4 bv = *(const float4*)(b + t * 4);
  float o[4];
  o[0] = d0 * inv * gv.x + bv.x;
  o[1] = d1 * inv * gv.y + bv.y;
  o[2] = d2 * inv * gv.z + bv.z;
  o[3] = d3 * inv * gv.w + bv.w;
  *(float4*)(x + (size_t)row * DMODEL + t * 4) = make_float4(o[0], o[1], o[2], o[3]);
  ushort_t hv[4];
  #pragma unroll
  for (int j = 0; j < 4; ++j) hv[j] = f2bf(o[j]);
  *(ushort4*)(xh + (size_t)row * DMODEL + t * 4) = make_ushort4(hv[0], hv[1], hv[2], hv[3]);
}

// ---------------------------------------------------------------------------
// x = layernorm(x + sum_{z<4} parts[z] + bias) * g + b, fused bf16 hi split.
// ---------------------------------------------------------------------------
__global__ __launch_bounds__(256)
void resid_ln_red(float* __restrict__ x, const float* __restrict__ parts,
                  long pstride, const float* __restrict__ bias,
                  const float* __restrict__ g, const float* __restrict__ b,
                  ushort_t* __restrict__ xh)
{
  __shared__ float sm[4];
  int row = blockIdx.x, t = threadIdx.x;
  size_t base = (size_t)row * DMODEL + t * 4;
  float4 xv = *(const float4*)(x + base);
  float4 bb = *(const float4*)(bias + t * 4);
  float a0 = xv.x + bb.x, a1 = xv.y + bb.y, a2 = xv.z + bb.z, a3 = xv.w + bb.w;
  #pragma unroll
  for (int z = 0; z < 4; ++z) {
    float4 pv = *(const float4*)(parts + (size_t)z * pstride + base);
    a0 += pv.x; a1 += pv.y; a2 += pv.z; a3 += pv.w;
  }
  float s = block_sum256(a0 + a1 + a2 + a3, sm);
  float mean = s * (1.0f / DMODEL);
  float d0 = a0 - mean, d1 = a1 - mean, d2 = a2 - mean, d3 = a3 - mean;
  float vs = block_sum256(d0*d0 + d1*d1 + d2*d2 + d3*d3, sm);
  float inv = rsqrtf(vs * (1.0f / DMODEL) + 1e-5f);
  float4 gv = *(const float4*)(g + t * 4);
  float4 bv = *(const float4*)(b + t * 4);
  float o[4];
  o[0] = d0 * inv * gv.x + bv.x;
  o[1] = d1 * inv * gv.y + bv.y;
  o[2] = d2 * inv * gv.z + bv.z;
  o[3] = d3 * inv * gv.w + bv.w;
  *(float4*)(x + base) = make_float4(o[0], o[1], o[2], o[3]);
  ushort_t hv[4];
  #pragma unroll
  for (int j = 0; j < 4; ++j) hv[j] = f2bf(o[j]);
  *(ushort4*)(xh + base) = make_ushort4(hv[0], hv[1], hv[2], hv[3]);
}

// ---------------------------------------------------------------------------
// final scale: out[row] *= 1/sum(row); sum from deterministic partials
// ---------------------------------------------------------------------------
__global__ __launch_bounds__(256)
void scale_softmax(float* __restrict__ out, const float* __restrict__ partials,
                   int ncb)
{
  __shared__ float sm[4];
  int row = blockIdx.x, t = threadIdx.x;
  float s = 0.f;
  for (int cb = t; cb < ncb; cb += 256) s += partials[(size_t)row * NCBP + cb];
  s = block_sum256(s, sm);
  float inv = 1.0f / s;
  float* p = out + (size_t)row * VOCAB;
  int head = (int)((((uintptr_t)16 - ((uintptr_t)p & 15)) & 15) >> 2);
  if (t < head) p[t] *= inv;
  int nvec = (VOCAB - head) >> 2;
  float4* pv = (float4*)(p + head);
  for (int i = t; i < nvec; i += 256) {
    float4 v = pv[i];
    v.x *= inv; v.y *= inv; v.z *= inv; v.w *= inv;
    pv[i] = v;
  }
  int done = head + nvec * 4;
  if (t < VOCAB - done) p[done + t] *= inv;
}

// ---------------------------------------------------------------------------
extern "C" void kernel_launch(void* const* d_in, const int* in_sizes, int n_in,
                              void* d_out, int out_size, void* d_ws, size_t ws_size,
                              hipStream_t stream)
{
  const int*   tokens = (const int*)  d_in[0];
  const float* emb    = (const float*)d_in[1];
  const float* Wq     = (const float*)d_in[2];
  const float* bq     = (const float*)d_in[3];
  const float* Wk     = (const float*)d_in[4];
  const float* bk     = (const float*)d_in[5];
  const float* Wv     = (const float*)d_in[6];
  const float* bv     = (const float*)d_in[7];
  const float* ln1g   = (const float*)d_in[8];
  const float* ln1b   = (const float*)d_in[9];
  const float* W1     = (const float*)d_in[10];
  const float* b1     = (const float*)d_in[11];
  const float* W2     = (const float*)d_in[12];
  const float* b2     = (const float*)d_in[13];
  const float* ln2g   = (const float*)d_in[14];
  const float* ln2b   = (const float*)d_in[15];
  const float* Wout   = (const float*)d_in[16];
  const float* bout   = (const float*)d_in[17];

  // workspace: xh 0-8 MB; strip path stripH 8-16; partials 24-30.55;
  // big path (ws >= 137 MB): WoutT at 32 MB (50304x1024 bf16 = 103 MB)
  char* wsb = (char*)d_ws;
  ushort_t* xh     = (ushort_t*)(wsb);
  ushort_t* stripH = (ushort_t*)(wsb + ((size_t)8  << 20));
  float*    partials = (float*)(wsb + ((size_t)24 << 20)); // [4096][NCBP] f32
  ushort_t* woutT  = (ushort_t*)(wsb + ((size_t)32 << 20));
  const bool bigws = ws_size >= ((size_t)137 << 20);

  // scratch in d_out (823 MB; all dead before the logits GEMM writes it)
  char* ob = (char*)d_out;
  float*    x     = (float*)(ob);                          // [S][D] f32 16MB
  float*    yb    = (float*)(ob + ((size_t)16  << 20));    // [S][D] f32 16MB
  ushort_t* qh    = (ushort_t*)(ob + ((size_t)32  << 20)); // [H][S][64] 8MB
  ushort_t* ql    = (ushort_t*)(ob + ((size_t)40  << 20));
  ushort_t* kh    = (ushort_t*)(ob + ((size_t)48  << 20));
  ushort_t* vt    = (ushort_t*)(ob + ((size_t)56  << 20)); // [H][64][S] 8MB
  ushort_t* h1h   = (ushort_t*)(ob + ((size_t)64  << 20)); // [S][DFF] bf16 32MB
  float*    fparts= (float*)(ob + ((size_t)96  << 20));    // [4][S][D] f32 64MB
  ushort_t* wqkvhA= (ushort_t*)(ob + ((size_t)160 << 20)); // [L][3072][1024] 24MB
  ushort_t* wqkvlA= (ushort_t*)(ob + ((size_t)184 << 20));
  ushort_t* w1hA  = (ushort_t*)(ob + ((size_t)208 << 20)); // [L][4096][1024] 32MB
  ushort_t* w1lA  = (ushort_t*)(ob + ((size_t)240 << 20));
  ushort_t* w2hA  = (ushort_t*)(ob + ((size_t)272 << 20)); // [L][1024][4096] 32MB
  ushort_t* w2lA  = (ushort_t*)(ob + ((size_t)304 << 20));
  float*    bqkvA = (float*)(ob + ((size_t)336 << 20));    // [L][3072] f32
  float*    outf  = (float*)d_out;

  const long WQKV_L = 3072L * 1024;   // shorts per layer
  const long WFF_L  = 4096L * 1024;

  embed_kernel<<<S_LEN, 256, 0, stream>>>(tokens, emb, x, xh);

  // ---- hoisted weight prep (activation-independent) ----
  transpose_split<<<dim3(16, 1, 64), 256, 0, stream>>>(
      Wq, wqkvhA, wqkvlA,
      (long)DMODEL * DHEAD, (long)DHEAD * DMODEL,
      (long)NHEAD * DMODEL * DHEAD, WQKV_L,
      16, DHEAD, DMODEL, DHEAD);
  transpose_split<<<dim3(16, 1, 64), 256, 0, stream>>>(
      Wk, wqkvhA + 1024 * 1024, wqkvlA + 1024 * 1024,
      (long)DMODEL * DHEAD, (long)DHEAD * DMODEL,
      (long)NHEAD * DMODEL * DHEAD, WQKV_L,
      16, DHEAD, DMODEL, DHEAD);
  transpose_split<<<dim3(16, 1, 64), 256, 0, stream>>>(
      Wv, wqkvhA + 2048 * 1024, wqkvlA + 2048 * 1024,
      (long)DMODEL * DHEAD, (long)DHEAD * DMODEL,
      (long)NHEAD * DMODEL * DHEAD, WQKV_L,
      16, DHEAD, DMODEL, DHEAD);
  transpose_split<<<dim3(16, 64, 4), 256, 0, stream>>>(
      W1, w1hA, w1lA, 0, 0,
      (long)DMODEL * DFF, WFF_L, 1, DFF, DMODEL, DFF);
  transpose_split<<<dim3(64, 16, 4), 256, 0, stream>>>(
      W2, w2hA, w2lA, 0, 0,
      (long)DFF * DMODEL, WFF_L, 1, DMODEL, DFF, DMODEL);
  concat3_kernel<<<dim3(4, NLAYER), 256, 0, stream>>>(
      bq, bk, bv, bqkvA, 1024, 1024, 3072);

  for (int l = 0; l < NLAYER; ++l) {
    const ushort_t* wqh = wqkvhA + (long)l * WQKV_L;
    const ushort_t* wql = wqkvlA + (long)l * WQKV_L;
    const ushort_t* w1h = w1hA + (long)l * WFF_L;
    const ushort_t* w1l = w1lA + (long)l * WFF_L;
    const ushort_t* w2h = w2hA + (long)l * WFF_L;
    const ushort_t* w2l = w2lA + (long)l * WFF_L;

    // fused QKV projection: 2-prod, grid 16x12; V written transposed
    gemm8p<2, false><<<dim3(16, 12), 512, 0, stream>>>(
        xh, wqh, wql, bqkvA + (long)l * 3072, nullptr,
        qh, ql, kh, vt, 1024, 1024, 0, 0);

    attn_mfma<<<dim3(32, 16), 256, 0, stream>>>(qh, ql, kh, vt, yb);

    resid_ln_kernel<<<S_LEN, 256, 0, stream>>>(x, yb,
        ln1g + (size_t)l * DMODEL, ln1b + (size_t)l * DMODEL, xh);

    // FFN1: 2-prod, grid 16x16, bf16-hi output
    gemm8p<1, true><<<dim3(16, 16), 512, 0, stream>>>(
        xh, w1h, w1l, b1 + (long)l * DFF, nullptr,
        h1h, nullptr, nullptr, nullptr, 1024, 1024, 4096, 0);
    // FFN2: 2-prod split-K x4 (grid 16x4x4), f32 partials
    gemm8p<0, false><<<dim3(16, 4, 4), 512, 0, stream>>>(
        h1h, w2h, w2l, nullptr, fparts,
        nullptr, nullptr, nullptr, nullptr,
        1024, 4096, 1024, (long)S_LEN * DMODEL);
    resid_ln_red<<<S_LEN, 256, 0, stream>>>(x, fparts, (long)S_LEN * DMODEL,
        b2 + (long)l * DMODEL,
        ln2g + (size_t)l * DMODEL, ln2b + (size_t)l * DMODEL, xh);
  }

  if (bigws) {
    // single-shot logits: whole Wout^T (hi) staged in ws, one GEMM
    transpose_h<<<dim3(16, 786, 1), 256, 0, stream>>>(
        Wout, woutT, VOCAB, DMODEL, VOCAB);
    gemm1p<true><<<dim3(16, 197), 512, 0, stream>>>(
        xh, woutT, bout, outf, 1024, 1024, VOCAB, VOCAB, partials, 0);
  } else {
    // fallback: 4096-col strips through 8 MB of ws
    const int SW = 4096;
    for (int is = 0; is < 12; ++is) {
      int n0 = is * SW;
      transpose_h<<<dim3(16, 64, 1), 256, 0, stream>>>(
          Wout + n0, stripH, VOCAB, DMODEL, SW);
      gemm1p<false><<<dim3(16, 16), 512, 0, stream>>>(
          xh, stripH, bout + n0, outf + n0,
          1024, 1024, VOCAB, SW, partials, is * 16);
    }
    int n0 = 12 * SW;                       // 49152
    int ncols = VOCAB - n0;                 // 1105
    int nt64 = (ncols + 63) / 64;           // 18
    int nb256 = (ncols + 255) / 256;        // 5
    transpose_h<<<dim3(16, nt64, 1), 256, 0, stream>>>(
        Wout + n0, stripH, VOCAB, DMODEL, ncols);
    gemm1p<true><<<dim3(16, nb256), 512, 0, stream>>>(
        xh, stripH, bout + n0, outf + n0,
        1024, 1024, VOCAB, ncols, partials, 12 * 16);
  }
  const int ncb = (VOCAB + 255) / 256;      // 197
  scale_softmax<<<S_LEN, 256, 0, stream>>>(outf, partials, ncb);
}